// Round 1
// baseline (1029.506 us; speedup 1.0000x reference)
//
#include <hip/hip_runtime.h>
#include <math.h>

#define NN 10000
#define NE 320000

// ---------------- GEMM (f32, A:MxK row-major, B:KxN row-major, C:MxN) --------
#define BM 64
#define BN 64
#define BK 16

__global__ __launch_bounds__(256) void gemm_f32(
    const float* __restrict__ A, const float* __restrict__ B,
    const float* __restrict__ bias, float* __restrict__ C,
    int M, int N, int K) {
  __shared__ float As[BK][BM];
  __shared__ float Bs[BK][BN];
  const int bm = blockIdx.y * BM;
  const int bn = blockIdx.x * BN;
  const int tid = threadIdx.x;
  const int tx = tid & 15, ty = tid >> 4;
  const int arow = tid >> 2, acol = (tid & 3) << 2;
  const int brow = tid >> 4, bcol = (tid & 15) << 2;
  float acc[4][4] = {};
  for (int k0 = 0; k0 < K; k0 += BK) {
    float4 av = make_float4(0.f, 0.f, 0.f, 0.f);
    const int gr = bm + arow;
    if (gr < M) av = *reinterpret_cast<const float4*>(&A[(size_t)gr * K + k0 + acol]);
    As[acol + 0][arow] = av.x;
    As[acol + 1][arow] = av.y;
    As[acol + 2][arow] = av.z;
    As[acol + 3][arow] = av.w;
    *reinterpret_cast<float4*>(&Bs[brow][bcol]) =
        *reinterpret_cast<const float4*>(&B[(size_t)(k0 + brow) * N + bn + bcol]);
    __syncthreads();
#pragma unroll
    for (int k = 0; k < BK; ++k) {
      float4 a = *reinterpret_cast<const float4*>(&As[k][ty << 2]);
      float4 b = *reinterpret_cast<const float4*>(&Bs[k][tx << 2]);
      float ar[4] = {a.x, a.y, a.z, a.w};
      float br[4] = {b.x, b.y, b.z, b.w};
#pragma unroll
      for (int i = 0; i < 4; ++i)
#pragma unroll
        for (int j = 0; j < 4; ++j) acc[i][j] = fmaf(ar[i], br[j], acc[i][j]);
    }
    __syncthreads();
  }
#pragma unroll
  for (int i = 0; i < 4; ++i) {
    const int r = bm + (ty << 2) + i;
    if (r >= M) continue;
#pragma unroll
    for (int j = 0; j < 4; ++j) {
      const int c = bn + (tx << 2) + j;
      float v = acc[i][j];
      if (bias) v += bias[c];
      C[(size_t)r * N + c] = v;
    }
  }
}

// ---------------- CSR build helpers ----------------
__global__ void count_kernel(const int* __restrict__ key, int* __restrict__ cnt, int E) {
  for (int e = blockIdx.x * blockDim.x + threadIdx.x; e < E; e += gridDim.x * blockDim.x)
    atomicAdd(&cnt[key[e]], 1);
}

__global__ __launch_bounds__(1024) void scan_kernel(const int* __restrict__ cnt,
                                                    int* __restrict__ ptr, int n) {
  __shared__ int s[1024];
  const int t = threadIdx.x;
  const int chunk = (n + 1023) >> 10;
  const int start = t * chunk;
  const int end = min(start + chunk, n);
  int sum = 0;
  for (int i = start; i < end; ++i) sum += cnt[i];
  s[t] = sum;
  __syncthreads();
  for (int off = 1; off < 1024; off <<= 1) {
    int v = 0;
    if (t >= off) v = s[t - off];
    __syncthreads();
    s[t] += v;
    __syncthreads();
  }
  int excl = (t == 0) ? 0 : s[t - 1];
  for (int i = start; i < end; ++i) { ptr[i] = excl; excl += cnt[i]; }
  if (t == 1023) ptr[n] = s[1023];
}

__global__ void fill_kernel(const int* __restrict__ key, const int* __restrict__ val,
                            const int* __restrict__ ptr, int* __restrict__ cur,
                            int* __restrict__ out, int E) {
  for (int e = blockIdx.x * blockDim.x + threadIdx.x; e < E; e += gridDim.x * blockDim.x) {
    const int k = key[e];
    const int p = atomicAdd(&cur[k], 1);
    out[ptr[k] + p] = val[e];
  }
}

__global__ void dis_kernel(const int* __restrict__ ptr, float* __restrict__ dis, int n) {
  const int j = blockIdx.x * blockDim.x + threadIdx.x;
  if (j < n) dis[j] = 1.0f / sqrtf((float)(ptr[j + 1] - ptr[j] + 1));
}

// ---------------- GCN aggregation (one wave per destination node) ----------------
template <int C>
__global__ __launch_bounds__(64) void gcn_agg(const float* __restrict__ h,
    const float* __restrict__ dis, const int* __restrict__ ptr,
    const int* __restrict__ ridx, const float* __restrict__ bias,
    float* __restrict__ out) {
  const int j = blockIdx.x;
  const int t = threadIdx.x;
  constexpr int P = C / 256;
  const float dj = dis[j];
  float4 acc[P];
  const float4* hj = reinterpret_cast<const float4*>(h + (size_t)j * C);
  const float wj = dj * dj;
#pragma unroll
  for (int p = 0; p < P; ++p) {
    float4 v = hj[t + (p << 6)];
    acc[p] = make_float4(v.x * wj, v.y * wj, v.z * wj, v.w * wj);
  }
  const int e0 = ptr[j], e1 = ptr[j + 1];
  for (int e = e0; e < e1; ++e) {
    const int r = ridx[e];
    const float w = dis[r] * dj;
    const float4* hr = reinterpret_cast<const float4*>(h + (size_t)r * C);
#pragma unroll
    for (int p = 0; p < P; ++p) {
      float4 v = hr[t + (p << 6)];
      acc[p].x = fmaf(w, v.x, acc[p].x);
      acc[p].y = fmaf(w, v.y, acc[p].y);
      acc[p].z = fmaf(w, v.z, acc[p].z);
      acc[p].w = fmaf(w, v.w, acc[p].w);
    }
  }
  float4* o = reinterpret_cast<float4*>(out + (size_t)j * C);
  const float4* bs = reinterpret_cast<const float4*>(bias);
#pragma unroll
  for (int p = 0; p < P; ++p) {
    float4 bv = bs ? bs[t + (p << 6)] : make_float4(0.f, 0.f, 0.f, 0.f);
    o[t + (p << 6)] = make_float4(acc[p].x + bv.x, acc[p].y + bv.y,
                                  acc[p].z + bv.z, acc[p].w + bv.w);
  }
}

// ---------------- BatchNorm ----------------
template <int C>
__global__ __launch_bounds__(256) void bn_stats(const float* __restrict__ x,
    float* __restrict__ sums, float* __restrict__ sqs, int n) {
  constexpr int P = C / 256;
  float s[P], q[P];
#pragma unroll
  for (int p = 0; p < P; ++p) { s[p] = 0.f; q[p] = 0.f; }
  const int rpb = (n + gridDim.x - 1) / gridDim.x;
  const int r0 = blockIdx.x * rpb;
  const int r1 = min(r0 + rpb, n);
  for (int r = r0; r < r1; ++r) {
#pragma unroll
    for (int p = 0; p < P; ++p) {
      const float v = x[(size_t)r * C + threadIdx.x + (p << 8)];
      s[p] += v;
      q[p] = fmaf(v, v, q[p]);
    }
  }
#pragma unroll
  for (int p = 0; p < P; ++p) {
    atomicAdd(&sums[threadIdx.x + (p << 8)], s[p]);
    atomicAdd(&sqs[threadIdx.x + (p << 8)], q[p]);
  }
}

__global__ void bn_finalize(const float* __restrict__ sums, const float* __restrict__ sqs,
    const float* __restrict__ g, const float* __restrict__ b,
    float* __restrict__ scale, float* __restrict__ shift, int n, int C) {
  const int c = blockIdx.x * blockDim.x + threadIdx.x;
  if (c >= C) return;
  const float m = sums[c] / n;
  const float var = sqs[c] / n - m * m;
  const float sc = g[c] / sqrtf(var + 1e-5f);
  scale[c] = sc;
  shift[c] = b[c] - m * sc;
}

__global__ void bn_apply_prelu(float* __restrict__ x, const float* __restrict__ scale,
    const float* __restrict__ shift, const float* __restrict__ pa, int total, int cmask) {
  const float a = pa[0];
  for (int i = blockIdx.x * blockDim.x + threadIdx.x; i < total; i += gridDim.x * blockDim.x) {
    const int c = i & cmask;
    const float v = fmaf(x[i], scale[c], shift[c]);
    x[i] = v > 0.f ? v : a * v;
  }
}

// ---------------- l2norm over 256-dim rows (one wave per row) ----------------
__global__ __launch_bounds__(64) void l2norm_k(const float* __restrict__ x,
                                               float* __restrict__ y) {
  const int r = blockIdx.x, t = threadIdx.x;
  const float4 v = reinterpret_cast<const float4*>(x + (size_t)r * 256)[t];
  float sq = v.x * v.x + v.y * v.y + v.z * v.z + v.w * v.w;
#pragma unroll
  for (int o = 1; o < 64; o <<= 1) sq += __shfl_xor(sq, o);
  const float inv = 1.0f / sqrtf(sq + 1e-12f);
  reinterpret_cast<float4*>(y + (size_t)r * 256)[t] =
      make_float4(v.x * inv, v.y * inv, v.z * inv, v.w * inv);
}

// ---------------- per-row edge sims + dedup + top-3 ----------------
#define MAXK 512
__global__ __launch_bounds__(256) void topk_kernel(const float* __restrict__ sn,
    const int* __restrict__ ptr, const int* __restrict__ ncol, int* __restrict__ nb) {
  const int i = blockIdx.x;
  __shared__ float4 sni[64];
  __shared__ float vals[MAXK];
  __shared__ int cols[MAXK];
  const int t = threadIdx.x;
  if (t < 64) sni[t] = reinterpret_cast<const float4*>(sn + (size_t)i * 256)[t];
  __syncthreads();
  const int e0 = ptr[i];
  const int k = min(ptr[i + 1] - e0, MAXK);
  const int wave = t >> 6, lane = t & 63;
  for (int e = wave; e < k; e += 4) {
    const int j = ncol[e0 + e];
    const float4 a = sni[lane];
    const float4 b = reinterpret_cast<const float4*>(sn + (size_t)j * 256)[lane];
    float s = a.x * b.x + a.y * b.y + a.z * b.z + a.w * b.w;
#pragma unroll
    for (int o = 1; o < 64; o <<= 1) s += __shfl_xor(s, o);
    if (lane == 0) { vals[e] = s; cols[e] = j; }
  }
  __syncthreads();
  if (t == 0) {
    // merge duplicate (row,col) edges (JAX scatter-add semantics)
    for (int a = 0; a < k; ++a) {
      if (cols[a] < 0) continue;
      for (int b = a + 1; b < k; ++b)
        if (cols[b] == cols[a]) { vals[a] += vals[b]; cols[b] = -1; }
    }
    // top-3 among strictly positive values; ties -> smaller column (JAX order).
    // Non-positive values rank below the ~N zero cells, whose picks have mask=0.
    for (int s = 0; s < 3; ++s) {
      int best = -1; float bv = 0.f; int bc = 0x7fffffff;
      for (int e = 0; e < k; ++e) {
        if (cols[e] < 0) continue;
        const float v = vals[e];
        if (v > 0.f && (v > bv || (v == bv && cols[e] < bc))) {
          best = e; bv = v; bc = cols[e];
        }
      }
      if (best >= 0) { nb[i * 3 + s] = cols[best]; cols[best] = -1; }
      else nb[i * 3 + s] = -1;
    }
  }
}

// ---------------- loss terms ----------------
__global__ __launch_bounds__(256) void loss_terms(const float* __restrict__ pn,
    const float* __restrict__ tgt, const int* __restrict__ nb,
    float* __restrict__ acc, int n) {
  const int t = threadIdx.x, wave = t >> 6, lane = t & 63;
  const int r = blockIdx.x * 4 + wave;
  float vals[7] = {0.f, 0.f, 0.f, 0.f, 0.f, 0.f, 0.f};
  if (r < n) {
    const float4 a = reinterpret_cast<const float4*>(pn + (size_t)r * 256)[lane];
    const float4 b = reinterpret_cast<const float4*>(tgt + (size_t)r * 256)[lane];
    float d = a.x * b.x + a.y * b.y + a.z * b.z + a.w * b.w;
#pragma unroll
    for (int o = 1; o < 64; o <<= 1) d += __shfl_xor(d, o);
    vals[0] = 2.f - 2.f * d;
    for (int s = 0; s < 3; ++s) {
      const int j = nb[r * 3 + s];
      if (j >= 0) {
        const float4 c = reinterpret_cast<const float4*>(tgt + (size_t)j * 256)[lane];
        float e = a.x * c.x + a.y * c.y + a.z * c.z + a.w * c.w;
#pragma unroll
        for (int o = 1; o < 64; o <<= 1) e += __shfl_xor(e, o);
        vals[1 + s] = 2.f - 2.f * e;
        vals[4 + s] = 1.f;
      }
    }
  }
  __shared__ float red[4][7];
  if (lane == 0)
    for (int q = 0; q < 7; ++q) red[wave][q] = vals[q];
  __syncthreads();
  if (t == 0)
    for (int q = 0; q < 7; ++q)
      atomicAdd(&acc[q], red[0][q] + red[1][q] + red[2][q] + red[3][q]);
}

__global__ void finalize_loss(const float* __restrict__ acc, float* __restrict__ out, int n) {
  float loss = acc[0] / n;
  for (int s = 0; s < 3; ++s) loss += acc[1 + s] / fmaxf(acc[4 + s], 1.f);
  out[0] = loss * 0.25f;
}

// ---------------- host ----------------
extern "C" void kernel_launch(void* const* d_in, const int* in_sizes, int n_in,
                              void* d_out, int out_size, void* d_ws, size_t ws_size,
                              hipStream_t stream) {
  const float* x   = (const float*)d_in[0];
  const int*   eidx = (const int*)d_in[1];
  const int*   nidx = (const int*)d_in[2];
  const float* W1  = (const float*)d_in[3];
  const float* b1  = (const float*)d_in[4];
  const float* g1  = (const float*)d_in[5];
  const float* bb1 = (const float*)d_in[6];
  const float* pr1 = (const float*)d_in[7];
  const float* W2  = (const float*)d_in[8];
  const float* b2  = (const float*)d_in[9];
  const float* g2  = (const float*)d_in[10];
  const float* bb2 = (const float*)d_in[11];
  const float* pr2 = (const float*)d_in[12];
  const float* pW1 = (const float*)d_in[13];
  const float* pb1 = (const float*)d_in[14];
  const float* pg  = (const float*)d_in[15];
  const float* pbb = (const float*)d_in[16];
  const float* ppr = (const float*)d_in[17];
  const float* pW2 = (const float*)d_in[18];
  const float* pb2 = (const float*)d_in[19];

  const int* row  = eidx;
  const int* col  = eidx + NE;
  const int* nrow = nidx;
  const int* ncol = nidx + NE;

  float* student = (float*)d_out;              // NN x 256
  float* loss    = student + (size_t)NN * 256; // scalar

  char* ws = (char*)d_ws;
  size_t off = 0;
  auto take = [&](size_t bytes) -> void* {
    void* p = ws + off;
    off += (bytes + 255) & ~(size_t)255;
    return p;
  };
  float* h1    = (float*)take((size_t)NN * 512 * 4);
  float* x2    = (float*)take((size_t)NN * 512 * 4);
  float* h2    = (float*)take((size_t)NN * 256 * 4);
  float* sn    = (float*)take((size_t)NN * 256 * 4);
  float* dis   = (float*)take((size_t)NN * 4);
  int*   cnt   = (int*)take((size_t)NN * 4);
  int*   ptrg  = (int*)take((size_t)(NN + 1) * 4);
  int*   ridx  = (int*)take((size_t)NE * 4);
  int*   ptrn  = (int*)take((size_t)(NN + 1) * 4);
  int*   ncidx = (int*)take((size_t)NE * 4);
  int*   nb    = (int*)take((size_t)NN * 3 * 4);
  float* bnsum = (float*)take(1024 * 4);
  float* bnsq  = bnsum + 512;
  float* scale = (float*)take(512 * 4);
  float* shift = (float*)take(512 * 4);
  float* acc   = (float*)take(64);

  float* ph   = h1;  // predictor hidden reuses h1
  float* pred = h2;  // predictor output reuses h2
  float* pn   = x2;  // l2norm(pred) reuses x2

  // CSR for GCN (grouped by destination col)
  hipMemsetAsync(cnt, 0, NN * 4, stream);
  count_kernel<<<512, 256, 0, stream>>>(col, cnt, NE);
  scan_kernel<<<1, 1024, 0, stream>>>(cnt, ptrg, NN);
  hipMemsetAsync(cnt, 0, NN * 4, stream);
  fill_kernel<<<512, 256, 0, stream>>>(col, row, ptrg, cnt, ridx, NE);
  dis_kernel<<<(NN + 255) / 256, 256, 0, stream>>>(ptrg, dis, NN);

  // CSR for neighbor graph (grouped by nrow)
  hipMemsetAsync(cnt, 0, NN * 4, stream);
  count_kernel<<<512, 256, 0, stream>>>(nrow, cnt, NE);
  scan_kernel<<<1, 1024, 0, stream>>>(cnt, ptrn, NN);
  hipMemsetAsync(cnt, 0, NN * 4, stream);
  fill_kernel<<<512, 256, 0, stream>>>(nrow, ncol, ptrn, cnt, ncidx, NE);

  // ---- encoder layer 1 ----
  { dim3 g(512 / BN, (NN + BM - 1) / BM);
    gemm_f32<<<g, 256, 0, stream>>>(x, W1, nullptr, h1, NN, 512, 512); }
  gcn_agg<512><<<NN, 64, 0, stream>>>(h1, dis, ptrg, ridx, b1, x2);
  hipMemsetAsync(bnsum, 0, 1024 * 4, stream);
  bn_stats<512><<<128, 256, 0, stream>>>(x2, bnsum, bnsq, NN);
  bn_finalize<<<2, 256, 0, stream>>>(bnsum, bnsq, g1, bb1, scale, shift, NN, 512);
  bn_apply_prelu<<<2048, 256, 0, stream>>>(x2, scale, shift, pr1, NN * 512, 511);

  // ---- encoder layer 2 ----
  { dim3 g(256 / BN, (NN + BM - 1) / BM);
    gemm_f32<<<g, 256, 0, stream>>>(x2, W2, nullptr, h2, NN, 256, 512); }
  gcn_agg<256><<<NN, 64, 0, stream>>>(h2, dis, ptrg, ridx, b2, student);
  hipMemsetAsync(bnsum, 0, 1024 * 4, stream);
  bn_stats<256><<<128, 256, 0, stream>>>(student, bnsum, bnsq, NN);
  bn_finalize<<<2, 256, 0, stream>>>(bnsum, bnsq, g2, bb2, scale, shift, NN, 256);
  bn_apply_prelu<<<2048, 256, 0, stream>>>(student, scale, shift, pr2, NN * 256, 255);

  // ---- sn = l2norm(student) ; teacher == student, so tn = tgt = sn ----
  l2norm_k<<<NN, 64, 0, stream>>>(student, sn);

  // ---- predictor ----
  { dim3 g(512 / BN, (NN + BM - 1) / BM);
    gemm_f32<<<g, 256, 0, stream>>>(student, pW1, pb1, ph, NN, 512, 256); }
  hipMemsetAsync(bnsum, 0, 1024 * 4, stream);
  bn_stats<512><<<128, 256, 0, stream>>>(ph, bnsum, bnsq, NN);
  bn_finalize<<<2, 256, 0, stream>>>(bnsum, bnsq, pg, pbb, scale, shift, NN, 512);
  bn_apply_prelu<<<2048, 256, 0, stream>>>(ph, scale, shift, ppr, NN * 512, 511);
  { dim3 g(256 / BN, (NN + BM - 1) / BM);
    gemm_f32<<<g, 256, 0, stream>>>(ph, pW2, pb2, pred, NN, 256, 512); }
  l2norm_k<<<NN, 64, 0, stream>>>(pred, pn);

  // ---- per-row top-3 neighbors ----
  topk_kernel<<<NN, 256, 0, stream>>>(sn, ptrn, ncidx, nb);

  // ---- loss ----
  hipMemsetAsync(acc, 0, 32, stream);
  loss_terms<<<NN / 4, 256, 0, stream>>>(pn, sn, nb, acc, NN);
  finalize_loss<<<1, 1, 0, stream>>>(acc, loss, NN);
}

// Round 2
// 860.259 us; speedup vs baseline: 1.1967x; 1.1967x over previous
//
#include <hip/hip_runtime.h>
#include <math.h>

#define NN 10000
#define NE 320000

// ---------------- GEMM (f32, A:MxK row-major, B:KxN row-major, C:MxN) --------
#define BM 64
#define BN 64
#define BK 16

__global__ __launch_bounds__(256) void gemm_f32(
    const float* __restrict__ A, const float* __restrict__ B,
    const float* __restrict__ bias, float* __restrict__ C,
    int M, int N, int K) {
  __shared__ float As[BK][BM];
  __shared__ float Bs[BK][BN];
  const int bm = blockIdx.y * BM;
  const int bn = blockIdx.x * BN;
  const int tid = threadIdx.x;
  const int tx = tid & 15, ty = tid >> 4;
  const int arow = tid >> 2, acol = (tid & 3) << 2;
  const int brow = tid >> 4, bcol = (tid & 15) << 2;
  float acc[4][4] = {};
  for (int k0 = 0; k0 < K; k0 += BK) {
    float4 av = make_float4(0.f, 0.f, 0.f, 0.f);
    const int gr = bm + arow;
    if (gr < M) av = *reinterpret_cast<const float4*>(&A[(size_t)gr * K + k0 + acol]);
    As[acol + 0][arow] = av.x;
    As[acol + 1][arow] = av.y;
    As[acol + 2][arow] = av.z;
    As[acol + 3][arow] = av.w;
    *reinterpret_cast<float4*>(&Bs[brow][bcol]) =
        *reinterpret_cast<const float4*>(&B[(size_t)(k0 + brow) * N + bn + bcol]);
    __syncthreads();
#pragma unroll
    for (int k = 0; k < BK; ++k) {
      float4 a = *reinterpret_cast<const float4*>(&As[k][ty << 2]);
      float4 b = *reinterpret_cast<const float4*>(&Bs[k][tx << 2]);
      float ar[4] = {a.x, a.y, a.z, a.w};
      float br[4] = {b.x, b.y, b.z, b.w};
#pragma unroll
      for (int i = 0; i < 4; ++i)
#pragma unroll
        for (int j = 0; j < 4; ++j) acc[i][j] = fmaf(ar[i], br[j], acc[i][j]);
    }
    __syncthreads();
  }
#pragma unroll
  for (int i = 0; i < 4; ++i) {
    const int r = bm + (ty << 2) + i;
    if (r >= M) continue;
#pragma unroll
    for (int j = 0; j < 4; ++j) {
      const int c = bn + (tx << 2) + j;
      float v = acc[i][j];
      if (bias) v += bias[c];
      C[(size_t)r * N + c] = v;
    }
  }
}

// ---------------- CSR build helpers ----------------
__global__ void count_kernel(const int* __restrict__ key, int* __restrict__ cnt, int E) {
  for (int e = blockIdx.x * blockDim.x + threadIdx.x; e < E; e += gridDim.x * blockDim.x)
    atomicAdd(&cnt[key[e]], 1);
}

__global__ __launch_bounds__(1024) void scan_kernel(const int* __restrict__ cnt,
                                                    int* __restrict__ ptr, int n) {
  __shared__ int s[1024];
  const int t = threadIdx.x;
  const int chunk = (n + 1023) >> 10;
  const int start = t * chunk;
  const int end = min(start + chunk, n);
  int sum = 0;
  for (int i = start; i < end; ++i) sum += cnt[i];
  s[t] = sum;
  __syncthreads();
  for (int off = 1; off < 1024; off <<= 1) {
    int v = 0;
    if (t >= off) v = s[t - off];
    __syncthreads();
    s[t] += v;
    __syncthreads();
  }
  int excl = (t == 0) ? 0 : s[t - 1];
  for (int i = start; i < end; ++i) { ptr[i] = excl; excl += cnt[i]; }
  if (t == 1023) ptr[n] = s[1023];
}

__global__ void fill_kernel(const int* __restrict__ key, const int* __restrict__ val,
                            const int* __restrict__ ptr, int* __restrict__ cur,
                            int* __restrict__ out, int E) {
  for (int e = blockIdx.x * blockDim.x + threadIdx.x; e < E; e += gridDim.x * blockDim.x) {
    const int k = key[e];
    const int p = atomicAdd(&cur[k], 1);
    out[ptr[k] + p] = val[e];
  }
}

__global__ void dis_kernel(const int* __restrict__ ptr, float* __restrict__ dis, int n) {
  const int j = blockIdx.x * blockDim.x + threadIdx.x;
  if (j < n) dis[j] = 1.0f / sqrtf((float)(ptr[j + 1] - ptr[j] + 1));
}

// ---------------- GCN aggregation (one wave per destination node) ----------------
template <int C>
__global__ __launch_bounds__(64) void gcn_agg(const float* __restrict__ h,
    const float* __restrict__ dis, const int* __restrict__ ptr,
    const int* __restrict__ ridx, const float* __restrict__ bias,
    float* __restrict__ out) {
  const int j = blockIdx.x;
  const int t = threadIdx.x;
  constexpr int P = C / 256;
  const float dj = dis[j];
  float4 acc[P];
  const float4* hj = reinterpret_cast<const float4*>(h + (size_t)j * C);
  const float wj = dj * dj;
#pragma unroll
  for (int p = 0; p < P; ++p) {
    float4 v = hj[t + (p << 6)];
    acc[p] = make_float4(v.x * wj, v.y * wj, v.z * wj, v.w * wj);
  }
  const int e0 = ptr[j], e1 = ptr[j + 1];
  for (int e = e0; e < e1; ++e) {
    const int r = ridx[e];
    const float w = dis[r] * dj;
    const float4* hr = reinterpret_cast<const float4*>(h + (size_t)r * C);
#pragma unroll
    for (int p = 0; p < P; ++p) {
      float4 v = hr[t + (p << 6)];
      acc[p].x = fmaf(w, v.x, acc[p].x);
      acc[p].y = fmaf(w, v.y, acc[p].y);
      acc[p].z = fmaf(w, v.z, acc[p].z);
      acc[p].w = fmaf(w, v.w, acc[p].w);
    }
  }
  float4* o = reinterpret_cast<float4*>(out + (size_t)j * C);
  const float4* bs = reinterpret_cast<const float4*>(bias);
#pragma unroll
  for (int p = 0; p < P; ++p) {
    float4 bv = bs ? bs[t + (p << 6)] : make_float4(0.f, 0.f, 0.f, 0.f);
    o[t + (p << 6)] = make_float4(acc[p].x + bv.x, acc[p].y + bv.y,
                                  acc[p].z + bv.z, acc[p].w + bv.w);
  }
}

// ---------------- BatchNorm ----------------
template <int C>
__global__ __launch_bounds__(256) void bn_stats(const float* __restrict__ x,
    float* __restrict__ sums, float* __restrict__ sqs, int n) {
  constexpr int P = C / 256;
  float s[P], q[P];
#pragma unroll
  for (int p = 0; p < P; ++p) { s[p] = 0.f; q[p] = 0.f; }
  const int rpb = (n + gridDim.x - 1) / gridDim.x;
  const int r0 = blockIdx.x * rpb;
  const int r1 = min(r0 + rpb, n);
  for (int r = r0; r < r1; ++r) {
#pragma unroll
    for (int p = 0; p < P; ++p) {
      const float v = x[(size_t)r * C + threadIdx.x + (p << 8)];
      s[p] += v;
      q[p] = fmaf(v, v, q[p]);
    }
  }
#pragma unroll
  for (int p = 0; p < P; ++p) {
    atomicAdd(&sums[threadIdx.x + (p << 8)], s[p]);
    atomicAdd(&sqs[threadIdx.x + (p << 8)], q[p]);
  }
}

__global__ void bn_finalize(const float* __restrict__ sums, const float* __restrict__ sqs,
    const float* __restrict__ g, const float* __restrict__ b,
    float* __restrict__ scale, float* __restrict__ shift, int n, int C) {
  const int c = blockIdx.x * blockDim.x + threadIdx.x;
  if (c >= C) return;
  const float m = sums[c] / n;
  const float var = sqs[c] / n - m * m;
  const float sc = g[c] / sqrtf(var + 1e-5f);
  scale[c] = sc;
  shift[c] = b[c] - m * sc;
}

__global__ void bn_apply_prelu(float* __restrict__ x, const float* __restrict__ scale,
    const float* __restrict__ shift, const float* __restrict__ pa, int total, int cmask) {
  const float a = pa[0];
  for (int i = blockIdx.x * blockDim.x + threadIdx.x; i < total; i += gridDim.x * blockDim.x) {
    const int c = i & cmask;
    const float v = fmaf(x[i], scale[c], shift[c]);
    x[i] = v > 0.f ? v : a * v;
  }
}

// ---------------- l2norm over 256-dim rows (one wave per row) ----------------
__global__ __launch_bounds__(64) void l2norm_k(const float* __restrict__ x,
                                               float* __restrict__ y) {
  const int r = blockIdx.x, t = threadIdx.x;
  const float4 v = reinterpret_cast<const float4*>(x + (size_t)r * 256)[t];
  float sq = v.x * v.x + v.y * v.y + v.z * v.z + v.w * v.w;
#pragma unroll
  for (int o = 1; o < 64; o <<= 1) sq += __shfl_xor(sq, o);
  const float inv = 1.0f / sqrtf(sq + 1e-12f);
  reinterpret_cast<float4*>(y + (size_t)r * 256)[t] =
      make_float4(v.x * inv, v.y * inv, v.z * inv, v.w * inv);
}

// ---------------- per-row edge sims + dedup + top-3 (one wave per row) -------
#define MAXK 256
__global__ __launch_bounds__(64) void topk_kernel(const float* __restrict__ sn,
    const int* __restrict__ ptr, const int* __restrict__ ncol, int* __restrict__ nb) {
  const int i = blockIdx.x;
  const int lane = threadIdx.x;
  __shared__ float sni[256];
  __shared__ float vals[MAXK];
  __shared__ int   cols[MAXK];
  __shared__ float mvals[MAXK];
  __shared__ int   mcols[MAXK];
  reinterpret_cast<float4*>(sni)[lane] =
      reinterpret_cast<const float4*>(sn + (size_t)i * 256)[lane];
  __syncthreads();
  const int e0 = ptr[i];
  const int k  = min(ptr[i + 1] - e0, MAXK);
  // ---- per-lane 256-dim dot for each edge ----
  for (int e = lane; e < k; e += 64) {
    const int j = ncol[e0 + e];
    const float4* bj = reinterpret_cast<const float4*>(sn + (size_t)j * 256);
    const float4* aj = reinterpret_cast<const float4*>(sni);
    float s = 0.f;
#pragma unroll 8
    for (int q = 0; q < 64; ++q) {
      const float4 b = bj[q];
      const float4 a = aj[q];
      s = fmaf(a.x, b.x, s);
      s = fmaf(a.y, b.y, s);
      s = fmaf(a.z, b.z, s);
      s = fmaf(a.w, b.w, s);
    }
    vals[e] = s;
    cols[e] = j;
  }
  __syncthreads();
  // ---- wave-parallel dedup-merge (JAX scatter-add semantics) ----
  for (int e = lane; e < k; e += 64) {
    const int c = cols[e];
    bool first = true;
    float sum = vals[e];
    for (int q = 0; q < k; ++q) {
      if (q == e) continue;
      if (cols[q] == c) {
        if (q < e) { first = false; break; }  // earlier dup owns the merge
        sum += vals[q];
      }
    }
    mvals[e] = sum;
    mcols[e] = first ? c : -1;
  }
  __syncthreads();
  // ---- top-3 among strictly positive merged values; ties -> smaller col ----
  // Non-positive values rank below the ~N zero cells of S, whose picks have
  // mask=0 (they are non-edges w.p. ~1), so nb=-1 reproduces JAX's result.
  for (int s = 0; s < 3; ++s) {
    unsigned long long best = 0ull;
    for (int e = lane; e < k; e += 64) {
      const int c = mcols[e];
      if (c < 0) continue;
      const float v = mvals[e];
      if (v <= 0.f) continue;
      const unsigned long long key =
          ((unsigned long long)__float_as_uint(v) << 32) |
          (unsigned long long)(0xFFFFFFFFu - (unsigned)c);
      if (key > best) best = key;
    }
#pragma unroll
    for (int off = 1; off < 64; off <<= 1) {
      const unsigned long long o = __shfl_xor(best, off);
      if (o > best) best = o;
    }
    const int wcol = best ? (int)(0xFFFFFFFFu - (unsigned)(best & 0xFFFFFFFFu)) : -1;
    if (lane == 0) nb[i * 3 + s] = wcol;
    if (wcol >= 0)
      for (int e = lane; e < k; e += 64)
        if (mcols[e] == wcol) mcols[e] = -1;  // consume winner
    __syncthreads();
  }
}

// ---------------- loss terms ----------------
__global__ __launch_bounds__(256) void loss_terms(const float* __restrict__ pn,
    const float* __restrict__ tgt, const int* __restrict__ nb,
    float* __restrict__ acc, int n) {
  const int t = threadIdx.x, wave = t >> 6, lane = t & 63;
  const int r = blockIdx.x * 4 + wave;
  float vals[7] = {0.f, 0.f, 0.f, 0.f, 0.f, 0.f, 0.f};
  if (r < n) {
    const float4 a = reinterpret_cast<const float4*>(pn + (size_t)r * 256)[lane];
    const float4 b = reinterpret_cast<const float4*>(tgt + (size_t)r * 256)[lane];
    float d = a.x * b.x + a.y * b.y + a.z * b.z + a.w * b.w;
#pragma unroll
    for (int o = 1; o < 64; o <<= 1) d += __shfl_xor(d, o);
    vals[0] = 2.f - 2.f * d;
    for (int s = 0; s < 3; ++s) {
      const int j = nb[r * 3 + s];
      if (j >= 0) {
        const float4 c = reinterpret_cast<const float4*>(tgt + (size_t)j * 256)[lane];
        float e = a.x * c.x + a.y * c.y + a.z * c.z + a.w * c.w;
#pragma unroll
        for (int o = 1; o < 64; o <<= 1) e += __shfl_xor(e, o);
        vals[1 + s] = 2.f - 2.f * e;
        vals[4 + s] = 1.f;
      }
    }
  }
  __shared__ float red[4][7];
  if (lane == 0)
    for (int q = 0; q < 7; ++q) red[wave][q] = vals[q];
  __syncthreads();
  if (t == 0)
    for (int q = 0; q < 7; ++q)
      atomicAdd(&acc[q], red[0][q] + red[1][q] + red[2][q] + red[3][q]);
}

__global__ void finalize_loss(const float* __restrict__ acc, float* __restrict__ out, int n) {
  float loss = acc[0] / n;
  for (int s = 0; s < 3; ++s) loss += acc[1 + s] / fmaxf(acc[4 + s], 1.f);
  out[0] = loss * 0.25f;
}

// ---------------- host ----------------
extern "C" void kernel_launch(void* const* d_in, const int* in_sizes, int n_in,
                              void* d_out, int out_size, void* d_ws, size_t ws_size,
                              hipStream_t stream) {
  const float* x   = (const float*)d_in[0];
  const int*   eidx = (const int*)d_in[1];
  const int*   nidx = (const int*)d_in[2];
  const float* W1  = (const float*)d_in[3];
  const float* b1  = (const float*)d_in[4];
  const float* g1  = (const float*)d_in[5];
  const float* bb1 = (const float*)d_in[6];
  const float* pr1 = (const float*)d_in[7];
  const float* W2  = (const float*)d_in[8];
  const float* b2  = (const float*)d_in[9];
  const float* g2  = (const float*)d_in[10];
  const float* bb2 = (const float*)d_in[11];
  const float* pr2 = (const float*)d_in[12];
  const float* pW1 = (const float*)d_in[13];
  const float* pb1 = (const float*)d_in[14];
  const float* pg  = (const float*)d_in[15];
  const float* pbb = (const float*)d_in[16];
  const float* ppr = (const float*)d_in[17];
  const float* pW2 = (const float*)d_in[18];
  const float* pb2 = (const float*)d_in[19];

  const int* row  = eidx;
  const int* col  = eidx + NE;
  const int* nrow = nidx;
  const int* ncol = nidx + NE;

  float* student = (float*)d_out;              // NN x 256
  float* loss    = student + (size_t)NN * 256; // scalar

  char* ws = (char*)d_ws;
  size_t off = 0;
  auto take = [&](size_t bytes) -> void* {
    void* p = ws + off;
    off += (bytes + 255) & ~(size_t)255;
    return p;
  };
  float* h1    = (float*)take((size_t)NN * 512 * 4);
  float* x2    = (float*)take((size_t)NN * 512 * 4);
  float* h2    = (float*)take((size_t)NN * 256 * 4);
  float* sn    = (float*)take((size_t)NN * 256 * 4);
  float* dis   = (float*)take((size_t)NN * 4);
  int*   cnt   = (int*)take((size_t)NN * 4);
  int*   ptrg  = (int*)take((size_t)(NN + 1) * 4);
  int*   ridx  = (int*)take((size_t)NE * 4);
  int*   ptrn  = (int*)take((size_t)(NN + 1) * 4);
  int*   ncidx = (int*)take((size_t)NE * 4);
  int*   nb    = (int*)take((size_t)NN * 3 * 4);
  float* bnsum = (float*)take(1024 * 4);
  float* bnsq  = bnsum + 512;
  float* scale = (float*)take(512 * 4);
  float* shift = (float*)take(512 * 4);
  float* acc   = (float*)take(64);

  float* ph   = h1;  // predictor hidden reuses h1
  float* pred = h2;  // predictor output reuses h2
  float* pn   = x2;  // l2norm(pred) reuses x2

  // CSR for GCN (grouped by destination col)
  hipMemsetAsync(cnt, 0, NN * 4, stream);
  count_kernel<<<512, 256, 0, stream>>>(col, cnt, NE);
  scan_kernel<<<1, 1024, 0, stream>>>(cnt, ptrg, NN);
  hipMemsetAsync(cnt, 0, NN * 4, stream);
  fill_kernel<<<512, 256, 0, stream>>>(col, row, ptrg, cnt, ridx, NE);
  dis_kernel<<<(NN + 255) / 256, 256, 0, stream>>>(ptrg, dis, NN);

  // CSR for neighbor graph (grouped by nrow)
  hipMemsetAsync(cnt, 0, NN * 4, stream);
  count_kernel<<<512, 256, 0, stream>>>(nrow, cnt, NE);
  scan_kernel<<<1, 1024, 0, stream>>>(cnt, ptrn, NN);
  hipMemsetAsync(cnt, 0, NN * 4, stream);
  fill_kernel<<<512, 256, 0, stream>>>(nrow, ncol, ptrn, cnt, ncidx, NE);

  // ---- encoder layer 1 ----
  { dim3 g(512 / BN, (NN + BM - 1) / BM);
    gemm_f32<<<g, 256, 0, stream>>>(x, W1, nullptr, h1, NN, 512, 512); }
  gcn_agg<512><<<NN, 64, 0, stream>>>(h1, dis, ptrg, ridx, b1, x2);
  hipMemsetAsync(bnsum, 0, 1024 * 4, stream);
  bn_stats<512><<<128, 256, 0, stream>>>(x2, bnsum, bnsq, NN);
  bn_finalize<<<2, 256, 0, stream>>>(bnsum, bnsq, g1, bb1, scale, shift, NN, 512);
  bn_apply_prelu<<<2048, 256, 0, stream>>>(x2, scale, shift, pr1, NN * 512, 511);

  // ---- encoder layer 2 ----
  { dim3 g(256 / BN, (NN + BM - 1) / BM);
    gemm_f32<<<g, 256, 0, stream>>>(x2, W2, nullptr, h2, NN, 256, 512); }
  gcn_agg<256><<<NN, 64, 0, stream>>>(h2, dis, ptrg, ridx, b2, student);
  hipMemsetAsync(bnsum, 0, 1024 * 4, stream);
  bn_stats<256><<<128, 256, 0, stream>>>(student, bnsum, bnsq, NN);
  bn_finalize<<<2, 256, 0, stream>>>(bnsum, bnsq, g2, bb2, scale, shift, NN, 256);
  bn_apply_prelu<<<2048, 256, 0, stream>>>(student, scale, shift, pr2, NN * 256, 255);

  // ---- sn = l2norm(student) ; teacher == student, so tn = tgt = sn ----
  l2norm_k<<<NN, 64, 0, stream>>>(student, sn);

  // ---- predictor ----
  { dim3 g(512 / BN, (NN + BM - 1) / BM);
    gemm_f32<<<g, 256, 0, stream>>>(student, pW1, pb1, ph, NN, 512, 256); }
  hipMemsetAsync(bnsum, 0, 1024 * 4, stream);
  bn_stats<512><<<128, 256, 0, stream>>>(ph, bnsum, bnsq, NN);
  bn_finalize<<<2, 256, 0, stream>>>(bnsum, bnsq, pg, pbb, scale, shift, NN, 512);
  bn_apply_prelu<<<2048, 256, 0, stream>>>(ph, scale, shift, ppr, NN * 512, 511);
  { dim3 g(256 / BN, (NN + BM - 1) / BM);
    gemm_f32<<<g, 256, 0, stream>>>(ph, pW2, pb2, pred, NN, 256, 512); }
  l2norm_k<<<NN, 64, 0, stream>>>(pred, pn);

  // ---- per-row top-3 neighbors ----
  topk_kernel<<<NN, 64, 0, stream>>>(sn, ptrn, ncidx, nb);

  // ---- loss ----
  hipMemsetAsync(acc, 0, 32, stream);
  loss_terms<<<NN / 4, 256, 0, stream>>>(pn, sn, nb, acc, NN);
  finalize_loss<<<1, 1, 0, stream>>>(acc, loss, NN);
}

// Round 3
// 650.192 us; speedup vs baseline: 1.5834x; 1.3231x over previous
//
#include <hip/hip_runtime.h>
#include <math.h>

#define NN 10000
#define NE 320000

// ---------------- GEMM (f32, A:MxK row-major, B:KxN row-major, C:MxN) --------
#define BM 64
#define BN 64
#define BK 16

__global__ __launch_bounds__(256) void gemm_f32(
    const float* __restrict__ A, const float* __restrict__ B,
    const float* __restrict__ bias, float* __restrict__ C,
    int M, int N, int K) {
  __shared__ float As[BK][BM];
  __shared__ float Bs[BK][BN];
  const int bm = blockIdx.y * BM;
  const int bn = blockIdx.x * BN;
  const int tid = threadIdx.x;
  const int tx = tid & 15, ty = tid >> 4;
  const int arow = tid >> 2, acol = (tid & 3) << 2;
  const int brow = tid >> 4, bcol = (tid & 15) << 2;
  float acc[4][4] = {};
  for (int k0 = 0; k0 < K; k0 += BK) {
    float4 av = make_float4(0.f, 0.f, 0.f, 0.f);
    const int gr = bm + arow;
    if (gr < M) av = *reinterpret_cast<const float4*>(&A[(size_t)gr * K + k0 + acol]);
    As[acol + 0][arow] = av.x;
    As[acol + 1][arow] = av.y;
    As[acol + 2][arow] = av.z;
    As[acol + 3][arow] = av.w;
    *reinterpret_cast<float4*>(&Bs[brow][bcol]) =
        *reinterpret_cast<const float4*>(&B[(size_t)(k0 + brow) * N + bn + bcol]);
    __syncthreads();
#pragma unroll
    for (int k = 0; k < BK; ++k) {
      float4 a = *reinterpret_cast<const float4*>(&As[k][ty << 2]);
      float4 b = *reinterpret_cast<const float4*>(&Bs[k][tx << 2]);
      float ar[4] = {a.x, a.y, a.z, a.w};
      float br[4] = {b.x, b.y, b.z, b.w};
#pragma unroll
      for (int i = 0; i < 4; ++i)
#pragma unroll
        for (int j = 0; j < 4; ++j) acc[i][j] = fmaf(ar[i], br[j], acc[i][j]);
    }
    __syncthreads();
  }
#pragma unroll
  for (int i = 0; i < 4; ++i) {
    const int r = bm + (ty << 2) + i;
    if (r >= M) continue;
#pragma unroll
    for (int j = 0; j < 4; ++j) {
      const int c = bn + (tx << 2) + j;
      float v = acc[i][j];
      if (bias) v += bias[c];
      C[(size_t)r * N + c] = v;
    }
  }
}

// ---------------- CSR build helpers ----------------
__global__ void count_kernel(const int* __restrict__ key, int* __restrict__ cnt, int E) {
  for (int e = blockIdx.x * blockDim.x + threadIdx.x; e < E; e += gridDim.x * blockDim.x)
    atomicAdd(&cnt[key[e]], 1);
}

__global__ __launch_bounds__(1024) void scan_kernel(const int* __restrict__ cnt,
                                                    int* __restrict__ ptr, int n) {
  __shared__ int s[1024];
  const int t = threadIdx.x;
  const int chunk = (n + 1023) >> 10;
  const int start = t * chunk;
  const int end = min(start + chunk, n);
  int sum = 0;
  for (int i = start; i < end; ++i) sum += cnt[i];
  s[t] = sum;
  __syncthreads();
  for (int off = 1; off < 1024; off <<= 1) {
    int v = 0;
    if (t >= off) v = s[t - off];
    __syncthreads();
    s[t] += v;
    __syncthreads();
  }
  int excl = (t == 0) ? 0 : s[t - 1];
  for (int i = start; i < end; ++i) { ptr[i] = excl; excl += cnt[i]; }
  if (t == 1023) ptr[n] = s[1023];
}

__global__ void fill_kernel(const int* __restrict__ key, const int* __restrict__ val,
                            const int* __restrict__ ptr, int* __restrict__ cur,
                            int* __restrict__ out, int E) {
  for (int e = blockIdx.x * blockDim.x + threadIdx.x; e < E; e += gridDim.x * blockDim.x) {
    const int k = key[e];
    const int p = atomicAdd(&cur[k], 1);
    out[ptr[k] + p] = val[e];
  }
}

__global__ void dis_kernel(const int* __restrict__ ptr, float* __restrict__ dis, int n) {
  const int j = blockIdx.x * blockDim.x + threadIdx.x;
  if (j < n) dis[j] = 1.0f / sqrtf((float)(ptr[j + 1] - ptr[j] + 1));
}

// ---------------- GCN aggregation (one wave per destination node) ----------------
template <int C>
__global__ __launch_bounds__(64) void gcn_agg(const float* __restrict__ h,
    const float* __restrict__ dis, const int* __restrict__ ptr,
    const int* __restrict__ ridx, const float* __restrict__ bias,
    float* __restrict__ out) {
  const int j = blockIdx.x;
  const int t = threadIdx.x;
  constexpr int P = C / 256;
  const float dj = dis[j];
  float4 acc[P];
  const float4* hj = reinterpret_cast<const float4*>(h + (size_t)j * C);
  const float wj = dj * dj;
#pragma unroll
  for (int p = 0; p < P; ++p) {
    float4 v = hj[t + (p << 6)];
    acc[p] = make_float4(v.x * wj, v.y * wj, v.z * wj, v.w * wj);
  }
  const int e0 = ptr[j], e1 = ptr[j + 1];
  for (int e = e0; e < e1; ++e) {
    const int r = ridx[e];
    const float w = dis[r] * dj;
    const float4* hr = reinterpret_cast<const float4*>(h + (size_t)r * C);
#pragma unroll
    for (int p = 0; p < P; ++p) {
      float4 v = hr[t + (p << 6)];
      acc[p].x = fmaf(w, v.x, acc[p].x);
      acc[p].y = fmaf(w, v.y, acc[p].y);
      acc[p].z = fmaf(w, v.z, acc[p].z);
      acc[p].w = fmaf(w, v.w, acc[p].w);
    }
  }
  float4* o = reinterpret_cast<float4*>(out + (size_t)j * C);
  const float4* bs = reinterpret_cast<const float4*>(bias);
#pragma unroll
  for (int p = 0; p < P; ++p) {
    float4 bv = bs ? bs[t + (p << 6)] : make_float4(0.f, 0.f, 0.f, 0.f);
    o[t + (p << 6)] = make_float4(acc[p].x + bv.x, acc[p].y + bv.y,
                                  acc[p].z + bv.z, acc[p].w + bv.w);
  }
}

// ---------------- BatchNorm ----------------
template <int C>
__global__ __launch_bounds__(256) void bn_stats(const float* __restrict__ x,
    float* __restrict__ sums, float* __restrict__ sqs, int n) {
  constexpr int P = C / 256;
  float s[P], q[P];
#pragma unroll
  for (int p = 0; p < P; ++p) { s[p] = 0.f; q[p] = 0.f; }
  const int rpb = (n + gridDim.x - 1) / gridDim.x;
  const int r0 = blockIdx.x * rpb;
  const int r1 = min(r0 + rpb, n);
  for (int r = r0; r < r1; ++r) {
#pragma unroll
    for (int p = 0; p < P; ++p) {
      const float v = x[(size_t)r * C + threadIdx.x + (p << 8)];
      s[p] += v;
      q[p] = fmaf(v, v, q[p]);
    }
  }
#pragma unroll
  for (int p = 0; p < P; ++p) {
    atomicAdd(&sums[threadIdx.x + (p << 8)], s[p]);
    atomicAdd(&sqs[threadIdx.x + (p << 8)], q[p]);
  }
}

__global__ void bn_finalize(const float* __restrict__ sums, const float* __restrict__ sqs,
    const float* __restrict__ g, const float* __restrict__ b,
    float* __restrict__ scale, float* __restrict__ shift, int n, int C) {
  const int c = blockIdx.x * blockDim.x + threadIdx.x;
  if (c >= C) return;
  const float m = sums[c] / n;
  const float var = sqs[c] / n - m * m;
  const float sc = g[c] / sqrtf(var + 1e-5f);
  scale[c] = sc;
  shift[c] = b[c] - m * sc;
}

__global__ void bn_apply_prelu(float* __restrict__ x, const float* __restrict__ scale,
    const float* __restrict__ shift, const float* __restrict__ pa, int total, int cmask) {
  const float a = pa[0];
  for (int i = blockIdx.x * blockDim.x + threadIdx.x; i < total; i += gridDim.x * blockDim.x) {
    const int c = i & cmask;
    const float v = fmaf(x[i], scale[c], shift[c]);
    x[i] = v > 0.f ? v : a * v;
  }
}

// ---------------- l2norm over 256-dim rows (one wave per row) ----------------
__global__ __launch_bounds__(64) void l2norm_k(const float* __restrict__ x,
                                               float* __restrict__ y) {
  const int r = blockIdx.x, t = threadIdx.x;
  const float4 v = reinterpret_cast<const float4*>(x + (size_t)r * 256)[t];
  float sq = v.x * v.x + v.y * v.y + v.z * v.z + v.w * v.w;
#pragma unroll
  for (int o = 1; o < 64; o <<= 1) sq += __shfl_xor(sq, o);
  const float inv = 1.0f / sqrtf(sq + 1e-12f);
  reinterpret_cast<float4*>(y + (size_t)r * 256)[t] =
      make_float4(v.x * inv, v.y * inv, v.z * inv, v.w * inv);
}

// ---------------- per-row edge sims + dedup + top-3 (one wave per row) -------
#define MAXK 256
__global__ __launch_bounds__(64) void topk_kernel(const float* __restrict__ sn,
    const int* __restrict__ ptr, const int* __restrict__ ncol, int* __restrict__ nb) {
  const int i = blockIdx.x;
  const int lane = threadIdx.x;
  __shared__ float sni[256];
  __shared__ float vals[MAXK];
  __shared__ int   cols[MAXK];
  __shared__ float mvals[MAXK];
  __shared__ int   mcols[MAXK];
  reinterpret_cast<float4*>(sni)[lane] =
      reinterpret_cast<const float4*>(sn + (size_t)i * 256)[lane];
  __syncthreads();
  const int e0 = ptr[i];
  const int k  = min(ptr[i + 1] - e0, MAXK);
  // ---- per-lane 256-dim dot for each edge ----
  for (int e = lane; e < k; e += 64) {
    const int j = ncol[e0 + e];
    const float4* bj = reinterpret_cast<const float4*>(sn + (size_t)j * 256);
    const float4* aj = reinterpret_cast<const float4*>(sni);
    float s = 0.f;
#pragma unroll 8
    for (int q = 0; q < 64; ++q) {
      const float4 b = bj[q];
      const float4 a = aj[q];
      s = fmaf(a.x, b.x, s);
      s = fmaf(a.y, b.y, s);
      s = fmaf(a.z, b.z, s);
      s = fmaf(a.w, b.w, s);
    }
    vals[e] = s;
    cols[e] = j;
  }
  __syncthreads();
  // ---- wave-parallel dedup-merge (JAX scatter-add semantics) ----
  for (int e = lane; e < k; e += 64) {
    const int c = cols[e];
    bool first = true;
    float sum = vals[e];
    for (int q = 0; q < k; ++q) {
      if (q == e) continue;
      if (cols[q] == c) {
        if (q < e) { first = false; break; }  // earlier dup owns the merge
        sum += vals[q];
      }
    }
    mvals[e] = sum;
    mcols[e] = first ? c : -1;
  }
  __syncthreads();
  // ---- top-3 among strictly positive merged values; ties -> smaller col ----
  // Non-positive values rank below the ~N zero cells of S, whose picks have
  // mask=0 (they are non-edges w.p. ~1), so nb=-1 reproduces JAX's result.
  for (int s = 0; s < 3; ++s) {
    unsigned long long best = 0ull;
    for (int e = lane; e < k; e += 64) {
      const int c = mcols[e];
      if (c < 0) continue;
      const float v = mvals[e];
      if (v <= 0.f) continue;
      const unsigned long long key =
          ((unsigned long long)__float_as_uint(v) << 32) |
          (unsigned long long)(0xFFFFFFFFu - (unsigned)c);
      if (key > best) best = key;
    }
#pragma unroll
    for (int off = 1; off < 64; off <<= 1) {
      const unsigned long long o = __shfl_xor(best, off);
      if (o > best) best = o;
    }
    const int wcol = best ? (int)(0xFFFFFFFFu - (unsigned)(best & 0xFFFFFFFFu)) : -1;
    if (lane == 0) nb[i * 3 + s] = wcol;
    if (wcol >= 0)
      for (int e = lane; e < k; e += 64)
        if (mcols[e] == wcol) mcols[e] = -1;  // consume winner
    __syncthreads();
  }
}

// ---------------- loss terms (no atomics: per-block partials) ----------------
__global__ __launch_bounds__(256) void loss_terms(const float* __restrict__ pn,
    const float* __restrict__ tgt, const int* __restrict__ nb,
    float* __restrict__ part, int n) {
  const int t = threadIdx.x, wave = t >> 6, lane = t & 63;
  const int r = blockIdx.x * 4 + wave;
  float vals[7] = {0.f, 0.f, 0.f, 0.f, 0.f, 0.f, 0.f};
  if (r < n) {
    const float4 a = reinterpret_cast<const float4*>(pn + (size_t)r * 256)[lane];
    const float4 b = reinterpret_cast<const float4*>(tgt + (size_t)r * 256)[lane];
    float d = a.x * b.x + a.y * b.y + a.z * b.z + a.w * b.w;
#pragma unroll
    for (int o = 1; o < 64; o <<= 1) d += __shfl_xor(d, o);
    vals[0] = 2.f - 2.f * d;
    for (int s = 0; s < 3; ++s) {
      const int j = nb[r * 3 + s];
      if (j >= 0) {
        const float4 c = reinterpret_cast<const float4*>(tgt + (size_t)j * 256)[lane];
        float e = a.x * c.x + a.y * c.y + a.z * c.z + a.w * c.w;
#pragma unroll
        for (int o = 1; o < 64; o <<= 1) e += __shfl_xor(e, o);
        vals[1 + s] = 2.f - 2.f * e;
        vals[4 + s] = 1.f;
      }
    }
  }
  __shared__ float red[4][7];
  if (lane == 0)
    for (int q = 0; q < 7; ++q) red[wave][q] = vals[q];
  __syncthreads();
  if (t < 7)  // thread q writes component q: plain store, no contention
    part[(size_t)blockIdx.x * 8 + t] =
        red[0][t] + red[1][t] + red[2][t] + red[3][t];
}

__global__ __launch_bounds__(64) void finalize_loss(const float* __restrict__ part,
    float* __restrict__ out, int nblocks, int n) {
  const int lane = threadIdx.x;
  float comp[7] = {0.f, 0.f, 0.f, 0.f, 0.f, 0.f, 0.f};
  for (int b = lane; b < nblocks; b += 64) {
#pragma unroll
    for (int q = 0; q < 7; ++q) comp[q] += part[(size_t)b * 8 + q];
  }
#pragma unroll
  for (int q = 0; q < 7; ++q) {
#pragma unroll
    for (int o = 1; o < 64; o <<= 1) comp[q] += __shfl_xor(comp[q], o);
  }
  if (lane == 0) {
    float loss = comp[0] / n;
    for (int s = 0; s < 3; ++s) loss += comp[1 + s] / fmaxf(comp[4 + s], 1.f);
    out[0] = loss * 0.25f;
  }
}

// ---------------- host ----------------
extern "C" void kernel_launch(void* const* d_in, const int* in_sizes, int n_in,
                              void* d_out, int out_size, void* d_ws, size_t ws_size,
                              hipStream_t stream) {
  const float* x   = (const float*)d_in[0];
  const int*   eidx = (const int*)d_in[1];
  const int*   nidx = (const int*)d_in[2];
  const float* W1  = (const float*)d_in[3];
  const float* b1  = (const float*)d_in[4];
  const float* g1  = (const float*)d_in[5];
  const float* bb1 = (const float*)d_in[6];
  const float* pr1 = (const float*)d_in[7];
  const float* W2  = (const float*)d_in[8];
  const float* b2  = (const float*)d_in[9];
  const float* g2  = (const float*)d_in[10];
  const float* bb2 = (const float*)d_in[11];
  const float* pr2 = (const float*)d_in[12];
  const float* pW1 = (const float*)d_in[13];
  const float* pb1 = (const float*)d_in[14];
  const float* pg  = (const float*)d_in[15];
  const float* pbb = (const float*)d_in[16];
  const float* ppr = (const float*)d_in[17];
  const float* pW2 = (const float*)d_in[18];
  const float* pb2 = (const float*)d_in[19];

  const int* row  = eidx;
  const int* col  = eidx + NE;
  const int* nrow = nidx;
  const int* ncol = nidx + NE;

  float* student = (float*)d_out;              // NN x 256
  float* loss    = student + (size_t)NN * 256; // scalar

  char* ws = (char*)d_ws;
  size_t off = 0;
  auto take = [&](size_t bytes) -> void* {
    void* p = ws + off;
    off += (bytes + 255) & ~(size_t)255;
    return p;
  };
  const int LOSS_NB = NN / 4;  // 2500 blocks
  float* h1    = (float*)take((size_t)NN * 512 * 4);
  float* x2    = (float*)take((size_t)NN * 512 * 4);
  float* h2    = (float*)take((size_t)NN * 256 * 4);
  float* sn    = (float*)take((size_t)NN * 256 * 4);
  float* dis   = (float*)take((size_t)NN * 4);
  int*   cnt   = (int*)take((size_t)NN * 4);
  int*   ptrg  = (int*)take((size_t)(NN + 1) * 4);
  int*   ridx  = (int*)take((size_t)NE * 4);
  int*   ptrn  = (int*)take((size_t)(NN + 1) * 4);
  int*   ncidx = (int*)take((size_t)NE * 4);
  int*   nb    = (int*)take((size_t)NN * 3 * 4);
  float* bnsum = (float*)take(1024 * 4);
  float* bnsq  = bnsum + 512;
  float* scale = (float*)take(512 * 4);
  float* shift = (float*)take(512 * 4);
  float* part  = (float*)take((size_t)LOSS_NB * 8 * 4);

  float* ph   = h1;  // predictor hidden reuses h1
  float* pred = h2;  // predictor output reuses h2
  float* pn   = x2;  // l2norm(pred) reuses x2

  // CSR for GCN (grouped by destination col)
  hipMemsetAsync(cnt, 0, NN * 4, stream);
  count_kernel<<<512, 256, 0, stream>>>(col, cnt, NE);
  scan_kernel<<<1, 1024, 0, stream>>>(cnt, ptrg, NN);
  hipMemsetAsync(cnt, 0, NN * 4, stream);
  fill_kernel<<<512, 256, 0, stream>>>(col, row, ptrg, cnt, ridx, NE);
  dis_kernel<<<(NN + 255) / 256, 256, 0, stream>>>(ptrg, dis, NN);

  // CSR for neighbor graph (grouped by nrow)
  hipMemsetAsync(cnt, 0, NN * 4, stream);
  count_kernel<<<512, 256, 0, stream>>>(nrow, cnt, NE);
  scan_kernel<<<1, 1024, 0, stream>>>(cnt, ptrn, NN);
  hipMemsetAsync(cnt, 0, NN * 4, stream);
  fill_kernel<<<512, 256, 0, stream>>>(nrow, ncol, ptrn, cnt, ncidx, NE);

  // ---- encoder layer 1 ----
  { dim3 g(512 / BN, (NN + BM - 1) / BM);
    gemm_f32<<<g, 256, 0, stream>>>(x, W1, nullptr, h1, NN, 512, 512); }
  gcn_agg<512><<<NN, 64, 0, stream>>>(h1, dis, ptrg, ridx, b1, x2);
  hipMemsetAsync(bnsum, 0, 1024 * 4, stream);
  bn_stats<512><<<128, 256, 0, stream>>>(x2, bnsum, bnsq, NN);
  bn_finalize<<<2, 256, 0, stream>>>(bnsum, bnsq, g1, bb1, scale, shift, NN, 512);
  bn_apply_prelu<<<2048, 256, 0, stream>>>(x2, scale, shift, pr1, NN * 512, 511);

  // ---- encoder layer 2 ----
  { dim3 g(256 / BN, (NN + BM - 1) / BM);
    gemm_f32<<<g, 256, 0, stream>>>(x2, W2, nullptr, h2, NN, 256, 512); }
  gcn_agg<256><<<NN, 64, 0, stream>>>(h2, dis, ptrg, ridx, b2, student);
  hipMemsetAsync(bnsum, 0, 1024 * 4, stream);
  bn_stats<256><<<128, 256, 0, stream>>>(student, bnsum, bnsq, NN);
  bn_finalize<<<2, 256, 0, stream>>>(bnsum, bnsq, g2, bb2, scale, shift, NN, 256);
  bn_apply_prelu<<<2048, 256, 0, stream>>>(student, scale, shift, pr2, NN * 256, 255);

  // ---- sn = l2norm(student) ; teacher == student, so tn = tgt = sn ----
  l2norm_k<<<NN, 64, 0, stream>>>(student, sn);

  // ---- predictor ----
  { dim3 g(512 / BN, (NN + BM - 1) / BM);
    gemm_f32<<<g, 256, 0, stream>>>(student, pW1, pb1, ph, NN, 512, 256); }
  hipMemsetAsync(bnsum, 0, 1024 * 4, stream);
  bn_stats<512><<<128, 256, 0, stream>>>(ph, bnsum, bnsq, NN);
  bn_finalize<<<2, 256, 0, stream>>>(bnsum, bnsq, pg, pbb, scale, shift, NN, 512);
  bn_apply_prelu<<<2048, 256, 0, stream>>>(ph, scale, shift, ppr, NN * 512, 511);
  { dim3 g(256 / BN, (NN + BM - 1) / BM);
    gemm_f32<<<g, 256, 0, stream>>>(ph, pW2, pb2, pred, NN, 256, 512); }
  l2norm_k<<<NN, 64, 0, stream>>>(pred, pn);

  // ---- per-row top-3 neighbors ----
  topk_kernel<<<NN, 64, 0, stream>>>(sn, ptrn, ncidx, nb);

  // ---- loss ----
  loss_terms<<<LOSS_NB, 256, 0, stream>>>(pn, sn, nb, part, NN);
  finalize_loss<<<1, 64, 0, stream>>>(part, loss, LOSS_NB, NN);
}

// Round 4
// 513.691 us; speedup vs baseline: 2.0041x; 1.2657x over previous
//
#include <hip/hip_runtime.h>
#include <math.h>

#define NN 10000
#define NE 320000

typedef __attribute__((ext_vector_type(8))) short bf16x8;
typedef __attribute__((ext_vector_type(4))) float f32x4;

__device__ inline unsigned short f2bf(float f) {
  unsigned u = __float_as_uint(f);
  unsigned r = (u + 0x7fffu + ((u >> 16) & 1u)) >> 16;
  return (unsigned short)r;
}

// ---------------- converts ----------------
__global__ void f32_to_bf16_k(const float* __restrict__ in,
                              unsigned short* __restrict__ out, int total4) {
  for (int i = blockIdx.x * blockDim.x + threadIdx.x; i < total4;
       i += gridDim.x * blockDim.x) {
    const float4 v = reinterpret_cast<const float4*>(in)[i];
    ushort4 o;
    o.x = f2bf(v.x); o.y = f2bf(v.y); o.z = f2bf(v.z); o.w = f2bf(v.w);
    reinterpret_cast<ushort4*>(out)[i] = o;
  }
}

// Wt[n][k] = bf16(W[k][n]);  W is K x N row-major
__global__ void conv_transpose_bf16(const float* __restrict__ W,
                                    unsigned short* __restrict__ Wt, int K, int N) {
  const int total = K * N;
  for (int i = blockIdx.x * blockDim.x + threadIdx.x; i < total;
       i += gridDim.x * blockDim.x) {
    const int n = i / K, k = i - n * K;
    Wt[i] = f2bf(W[(size_t)k * N + n]);
  }
}

// ---------------- MFMA GEMM: A (MxK bf16 rm) x Bt (NxK bf16) -> C (MxN f32) --
#define GBM 128
#define GBN 64
#define GBK 32
#define SAS 40  // padded LDS row stride (elements): bank stride 20 -> 2-way free

__global__ __launch_bounds__(256) void gemm_bf16(
    const unsigned short* __restrict__ A, const unsigned short* __restrict__ Bt,
    const float* __restrict__ bias, float* __restrict__ C,
    int M, int N, int K) {
  __shared__ unsigned short As[GBM * SAS];
  __shared__ unsigned short Bs[GBN * SAS];
  const int bm = blockIdx.y * GBM;
  const int bn = blockIdx.x * GBN;
  const int tid = threadIdx.x;
  const int wave = tid >> 6, lane = tid & 63;
  const int wm = wave & 1, wn = wave >> 1;  // wave tile 64(M) x 32(N)
  f32x4 acc[4][2] = {};

  const int srow = tid >> 2;            // 0..63
  const int scol = (tid & 3) << 3;      // 0,8,16,24 (bf16 elems)

  for (int k0 = 0; k0 < K; k0 += GBK) {
#pragma unroll
    for (int r = 0; r < 2; ++r) {       // A: 128 rows in 2 rounds
      const int row = srow + (r << 6);
      const int gr = bm + row;
      uint4 v = make_uint4(0u, 0u, 0u, 0u);
      if (gr < M) v = *reinterpret_cast<const uint4*>(&A[(size_t)gr * K + k0 + scol]);
      *reinterpret_cast<uint4*>(&As[row * SAS + scol]) = v;
    }
    {                                   // Bt: 64 rows in 1 round
      const uint4 v = *reinterpret_cast<const uint4*>(
          &Bt[(size_t)(bn + srow) * K + k0 + scol]);
      *reinterpret_cast<uint4*>(&Bs[srow * SAS + scol]) = v;
    }
    __syncthreads();
    const int kofs = (lane >> 4) << 3;  // 0,8,16,24
    const int rl = lane & 15;
    bf16x8 af[4], bf[2];
#pragma unroll
    for (int m = 0; m < 4; ++m)
      af[m] = *reinterpret_cast<const bf16x8*>(
          &As[((wm << 6) + (m << 4) + rl) * SAS + kofs]);
#pragma unroll
    for (int n = 0; n < 2; ++n)
      bf[n] = *reinterpret_cast<const bf16x8*>(
          &Bs[((wn << 5) + (n << 4) + rl) * SAS + kofs]);
#pragma unroll
    for (int m = 0; m < 4; ++m)
#pragma unroll
      for (int n = 0; n < 2; ++n)
        acc[m][n] = __builtin_amdgcn_mfma_f32_16x16x32_bf16(af[m], bf[n], acc[m][n], 0, 0, 0);
    __syncthreads();
  }
  // epilogue: D[row][col], col = lane&15, row = (lane>>4)*4 + reg
  const int crow0 = (lane >> 4) << 2;
  const int ccol = lane & 15;
#pragma unroll
  for (int n = 0; n < 2; ++n) {
    const int col = bn + (wn << 5) + (n << 4) + ccol;
    const float bv = bias ? bias[col] : 0.f;
#pragma unroll
    for (int m = 0; m < 4; ++m) {
#pragma unroll
      for (int r = 0; r < 4; ++r) {
        const int rowg = bm + (wm << 6) + (m << 4) + crow0 + r;
        if (rowg < M) C[(size_t)rowg * N + col] = acc[m][n][r] + bv;
      }
    }
  }
}

// ---------------- CSR build helpers ----------------
__global__ void count_kernel(const int* __restrict__ key, int* __restrict__ cnt, int E) {
  for (int e = blockIdx.x * blockDim.x + threadIdx.x; e < E; e += gridDim.x * blockDim.x)
    atomicAdd(&cnt[key[e]], 1);
}

__global__ __launch_bounds__(1024) void scan_kernel(const int* __restrict__ cnt,
                                                    int* __restrict__ ptr, int n) {
  __shared__ int s[1024];
  const int t = threadIdx.x;
  const int chunk = (n + 1023) >> 10;
  const int start = t * chunk;
  const int end = min(start + chunk, n);
  int sum = 0;
  for (int i = start; i < end; ++i) sum += cnt[i];
  s[t] = sum;
  __syncthreads();
  for (int off = 1; off < 1024; off <<= 1) {
    int v = 0;
    if (t >= off) v = s[t - off];
    __syncthreads();
    s[t] += v;
    __syncthreads();
  }
  int excl = (t == 0) ? 0 : s[t - 1];
  for (int i = start; i < end; ++i) { ptr[i] = excl; excl += cnt[i]; }
  if (t == 1023) ptr[n] = s[1023];
}

__global__ void fill_kernel(const int* __restrict__ key, const int* __restrict__ val,
                            const int* __restrict__ ptr, int* __restrict__ cur,
                            int* __restrict__ out, int E) {
  for (int e = blockIdx.x * blockDim.x + threadIdx.x; e < E; e += gridDim.x * blockDim.x) {
    const int k = key[e];
    const int p = atomicAdd(&cur[k], 1);
    out[ptr[k] + p] = val[e];
  }
}

__global__ void dis_kernel(const int* __restrict__ ptr, float* __restrict__ dis, int n) {
  const int j = blockIdx.x * blockDim.x + threadIdx.x;
  if (j < n) dis[j] = 1.0f / sqrtf((float)(ptr[j + 1] - ptr[j] + 1));
}

// ---------------- GCN aggregation (one wave per destination node) ------------
template <int C>
__global__ __launch_bounds__(64) void gcn_agg(const float* __restrict__ h,
    const float* __restrict__ dis, const int* __restrict__ ptr,
    const int* __restrict__ ridx, const float* __restrict__ bias,
    float* __restrict__ out) {
  const int j = blockIdx.x;
  const int t = threadIdx.x;
  constexpr int P = C / 256;
  const float dj = dis[j];
  float4 acc[P];
  const float4* hj = reinterpret_cast<const float4*>(h + (size_t)j * C);
  const float wj = dj * dj;
#pragma unroll
  for (int p = 0; p < P; ++p) {
    float4 v = hj[t + (p << 6)];
    acc[p] = make_float4(v.x * wj, v.y * wj, v.z * wj, v.w * wj);
  }
  const int e0 = ptr[j], e1 = ptr[j + 1];
  for (int e = e0; e < e1; ++e) {
    const int r = ridx[e];
    const float w = dis[r] * dj;
    const float4* hr = reinterpret_cast<const float4*>(h + (size_t)r * C);
#pragma unroll
    for (int p = 0; p < P; ++p) {
      float4 v = hr[t + (p << 6)];
      acc[p].x = fmaf(w, v.x, acc[p].x);
      acc[p].y = fmaf(w, v.y, acc[p].y);
      acc[p].z = fmaf(w, v.z, acc[p].z);
      acc[p].w = fmaf(w, v.w, acc[p].w);
    }
  }
  float4* o = reinterpret_cast<float4*>(out + (size_t)j * C);
  const float4* bs = reinterpret_cast<const float4*>(bias);
#pragma unroll
  for (int p = 0; p < P; ++p) {
    float4 bv = bs ? bs[t + (p << 6)] : make_float4(0.f, 0.f, 0.f, 0.f);
    o[t + (p << 6)] = make_float4(acc[p].x + bv.x, acc[p].y + bv.y,
                                  acc[p].z + bv.z, acc[p].w + bv.w);
  }
}

// ---------------- BatchNorm ----------------
template <int C>
__global__ __launch_bounds__(256) void bn_stats(const float* __restrict__ x,
    float* __restrict__ sums, float* __restrict__ sqs, int n) {
  constexpr int P = C / 256;
  float s[P], q[P];
#pragma unroll
  for (int p = 0; p < P; ++p) { s[p] = 0.f; q[p] = 0.f; }
  const int rpb = (n + gridDim.x - 1) / gridDim.x;
  const int r0 = blockIdx.x * rpb;
  const int r1 = min(r0 + rpb, n);
  for (int r = r0; r < r1; ++r) {
#pragma unroll
    for (int p = 0; p < P; ++p) {
      const float v = x[(size_t)r * C + threadIdx.x + (p << 8)];
      s[p] += v;
      q[p] = fmaf(v, v, q[p]);
    }
  }
#pragma unroll
  for (int p = 0; p < P; ++p) {
    atomicAdd(&sums[threadIdx.x + (p << 8)], s[p]);
    atomicAdd(&sqs[threadIdx.x + (p << 8)], q[p]);
  }
}

__global__ void bn_finalize(const float* __restrict__ sums, const float* __restrict__ sqs,
    const float* __restrict__ g, const float* __restrict__ b,
    float* __restrict__ scale, float* __restrict__ shift, int n, int C) {
  const int c = blockIdx.x * blockDim.x + threadIdx.x;
  if (c >= C) return;
  const float m = sums[c] / n;
  const float var = sqs[c] / n - m * m;
  const float sc = g[c] / sqrtf(var + 1e-5f);
  scale[c] = sc;
  shift[c] = b[c] - m * sc;
}

// BN+PReLU; always writes bf16 copy, optionally f32 (in-place allowed)
template <bool WRITE_F32>
__global__ void bn_apply_prelu(const float* __restrict__ in, float* __restrict__ outf,
    unsigned short* __restrict__ outb, const float* __restrict__ scale,
    const float* __restrict__ shift, const float* __restrict__ pa,
    int total4, int cmask) {
  const float a = pa[0];
  for (int i = blockIdx.x * blockDim.x + threadIdx.x; i < total4;
       i += gridDim.x * blockDim.x) {
    float4 v = reinterpret_cast<const float4*>(in)[i];
    const int c0 = (i << 2) & cmask;
    float r[4] = {v.x, v.y, v.z, v.w};
    ushort4 o;
    unsigned short* op = reinterpret_cast<unsigned short*>(&o);
#pragma unroll
    for (int j = 0; j < 4; ++j) {
      float t = fmaf(r[j], scale[c0 + j], shift[c0 + j]);
      t = t > 0.f ? t : a * t;
      r[j] = t;
      op[j] = f2bf(t);
    }
    if (WRITE_F32)
      reinterpret_cast<float4*>(outf)[i] = make_float4(r[0], r[1], r[2], r[3]);
    reinterpret_cast<ushort4*>(outb)[i] = o;
  }
}

// ---------------- l2norm over 256-dim rows (one wave per row) ----------------
__global__ __launch_bounds__(64) void l2norm_k(const float* __restrict__ x,
                                               float* __restrict__ y) {
  const int r = blockIdx.x, t = threadIdx.x;
  const float4 v = reinterpret_cast<const float4*>(x + (size_t)r * 256)[t];
  float sq = v.x * v.x + v.y * v.y + v.z * v.z + v.w * v.w;
#pragma unroll
  for (int o = 1; o < 64; o <<= 1) sq += __shfl_xor(sq, o);
  const float inv = 1.0f / sqrtf(sq + 1e-12f);
  reinterpret_cast<float4*>(y + (size_t)r * 256)[t] =
      make_float4(v.x * inv, v.y * inv, v.z * inv, v.w * inv);
}

// ---------------- per-row edge sims + dedup + top-3 (one wave per row) -------
#define MAXK 256
__global__ __launch_bounds__(64) void topk_kernel(const float* __restrict__ sn,
    const int* __restrict__ ptr, const int* __restrict__ ncol, int* __restrict__ nb) {
  const int i = blockIdx.x;
  const int lane = threadIdx.x;
  __shared__ float sni[256];
  __shared__ float vals[MAXK];
  __shared__ int   cols[MAXK];
  __shared__ float mvals[MAXK];
  __shared__ int   mcols[MAXK];
  reinterpret_cast<float4*>(sni)[lane] =
      reinterpret_cast<const float4*>(sn + (size_t)i * 256)[lane];
  __syncthreads();
  const int e0 = ptr[i];
  const int k  = min(ptr[i + 1] - e0, MAXK);
  for (int e = lane; e < k; e += 64) {
    const int j = ncol[e0 + e];
    const float4* bj = reinterpret_cast<const float4*>(sn + (size_t)j * 256);
    const float4* aj = reinterpret_cast<const float4*>(sni);
    float s = 0.f;
#pragma unroll 8
    for (int q = 0; q < 64; ++q) {
      const float4 b = bj[q];
      const float4 a = aj[q];
      s = fmaf(a.x, b.x, s);
      s = fmaf(a.y, b.y, s);
      s = fmaf(a.z, b.z, s);
      s = fmaf(a.w, b.w, s);
    }
    vals[e] = s;
    cols[e] = j;
  }
  __syncthreads();
  for (int e = lane; e < k; e += 64) {
    const int c = cols[e];
    bool first = true;
    float sum = vals[e];
    for (int q = 0; q < k; ++q) {
      if (q == e) continue;
      if (cols[q] == c) {
        if (q < e) { first = false; break; }
        sum += vals[q];
      }
    }
    mvals[e] = sum;
    mcols[e] = first ? c : -1;
  }
  __syncthreads();
  for (int s = 0; s < 3; ++s) {
    unsigned long long best = 0ull;
    for (int e = lane; e < k; e += 64) {
      const int c = mcols[e];
      if (c < 0) continue;
      const float v = mvals[e];
      if (v <= 0.f) continue;
      const unsigned long long key =
          ((unsigned long long)__float_as_uint(v) << 32) |
          (unsigned long long)(0xFFFFFFFFu - (unsigned)c);
      if (key > best) best = key;
    }
#pragma unroll
    for (int off = 1; off < 64; off <<= 1) {
      const unsigned long long o = __shfl_xor(best, off);
      if (o > best) best = o;
    }
    const int wcol = best ? (int)(0xFFFFFFFFu - (unsigned)(best & 0xFFFFFFFFu)) : -1;
    if (lane == 0) nb[i * 3 + s] = wcol;
    if (wcol >= 0)
      for (int e = lane; e < k; e += 64)
        if (mcols[e] == wcol) mcols[e] = -1;
    __syncthreads();
  }
}

// ---------------- loss terms (no atomics: per-block partials) ----------------
__global__ __launch_bounds__(256) void loss_terms(const float* __restrict__ pn,
    const float* __restrict__ tgt, const int* __restrict__ nb,
    float* __restrict__ part, int n) {
  const int t = threadIdx.x, wave = t >> 6, lane = t & 63;
  const int r = blockIdx.x * 4 + wave;
  float vals[7] = {0.f, 0.f, 0.f, 0.f, 0.f, 0.f, 0.f};
  if (r < n) {
    const float4 a = reinterpret_cast<const float4*>(pn + (size_t)r * 256)[lane];
    const float4 b = reinterpret_cast<const float4*>(tgt + (size_t)r * 256)[lane];
    float d = a.x * b.x + a.y * b.y + a.z * b.z + a.w * b.w;
#pragma unroll
    for (int o = 1; o < 64; o <<= 1) d += __shfl_xor(d, o);
    vals[0] = 2.f - 2.f * d;
    for (int s = 0; s < 3; ++s) {
      const int j = nb[r * 3 + s];
      if (j >= 0) {
        const float4 c = reinterpret_cast<const float4*>(tgt + (size_t)j * 256)[lane];
        float e = a.x * c.x + a.y * c.y + a.z * c.z + a.w * c.w;
#pragma unroll
        for (int o = 1; o < 64; o <<= 1) e += __shfl_xor(e, o);
        vals[1 + s] = 2.f - 2.f * e;
        vals[4 + s] = 1.f;
      }
    }
  }
  __shared__ float red[4][7];
  if (lane == 0)
    for (int q = 0; q < 7; ++q) red[wave][q] = vals[q];
  __syncthreads();
  if (t < 7)
    part[(size_t)blockIdx.x * 8 + t] =
        red[0][t] + red[1][t] + red[2][t] + red[3][t];
}

__global__ __launch_bounds__(64) void finalize_loss(const float* __restrict__ part,
    float* __restrict__ out, int nblocks, int n) {
  const int lane = threadIdx.x;
  float comp[7] = {0.f, 0.f, 0.f, 0.f, 0.f, 0.f, 0.f};
  for (int b = lane; b < nblocks; b += 64) {
#pragma unroll
    for (int q = 0; q < 7; ++q) comp[q] += part[(size_t)b * 8 + q];
  }
#pragma unroll
  for (int q = 0; q < 7; ++q) {
#pragma unroll
    for (int o = 1; o < 64; o <<= 1) comp[q] += __shfl_xor(comp[q], o);
  }
  if (lane == 0) {
    float loss = comp[0] / n;
    for (int s = 0; s < 3; ++s) loss += comp[1 + s] / fmaxf(comp[4 + s], 1.f);
    out[0] = loss * 0.25f;
  }
}

// ---------------- host ----------------
extern "C" void kernel_launch(void* const* d_in, const int* in_sizes, int n_in,
                              void* d_out, int out_size, void* d_ws, size_t ws_size,
                              hipStream_t stream) {
  const float* x   = (const float*)d_in[0];
  const int*   eidx = (const int*)d_in[1];
  const int*   nidx = (const int*)d_in[2];
  const float* W1  = (const float*)d_in[3];
  const float* b1  = (const float*)d_in[4];
  const float* g1  = (const float*)d_in[5];
  const float* bb1 = (const float*)d_in[6];
  const float* pr1 = (const float*)d_in[7];
  const float* W2  = (const float*)d_in[8];
  const float* b2  = (const float*)d_in[9];
  const float* g2  = (const float*)d_in[10];
  const float* bb2 = (const float*)d_in[11];
  const float* pr2 = (const float*)d_in[12];
  const float* pW1 = (const float*)d_in[13];
  const float* pb1 = (const float*)d_in[14];
  const float* pg  = (const float*)d_in[15];
  const float* pbb = (const float*)d_in[16];
  const float* ppr = (const float*)d_in[17];
  const float* pW2 = (const float*)d_in[18];
  const float* pb2 = (const float*)d_in[19];

  const int* row  = eidx;
  const int* col  = eidx + NE;
  const int* nrow = nidx;
  const int* ncol = nidx + NE;

  float* student = (float*)d_out;              // NN x 256
  float* loss    = student + (size_t)NN * 256; // scalar

  char* ws = (char*)d_ws;
  size_t off = 0;
  auto take = [&](size_t bytes) -> void* {
    void* p = ws + off;
    off += (bytes + 255) & ~(size_t)255;
    return p;
  };
  const int LOSS_NB = NN / 4;
  float* h1    = (float*)take((size_t)NN * 512 * 4);
  float* x2    = (float*)take((size_t)NN * 512 * 4);
  float* h2    = (float*)take((size_t)NN * 256 * 4);
  float* sn    = (float*)take((size_t)NN * 256 * 4);
  float* dis   = (float*)take((size_t)NN * 4);
  int*   cnt   = (int*)take((size_t)NN * 4);
  int*   ptrg  = (int*)take((size_t)(NN + 1) * 4);
  int*   ridx  = (int*)take((size_t)NE * 4);
  int*   ptrn  = (int*)take((size_t)(NN + 1) * 4);
  int*   ncidx = (int*)take((size_t)NE * 4);
  int*   nb    = (int*)take((size_t)NN * 3 * 4);
  float* bnsum = (float*)take(1024 * 4);
  float* bnsq  = bnsum + 512;
  float* scale = (float*)take(512 * 4);
  float* shift = (float*)take(512 * 4);
  float* part  = (float*)take((size_t)LOSS_NB * 8 * 4);
  // bf16 buffers
  unsigned short* xb   = (unsigned short*)take((size_t)NN * 512 * 2);
  unsigned short* x2b  = (unsigned short*)take((size_t)NN * 512 * 2);
  unsigned short* stb  = (unsigned short*)take((size_t)NN * 256 * 2);
  unsigned short* phb  = (unsigned short*)take((size_t)NN * 512 * 2);
  unsigned short* W1t  = (unsigned short*)take((size_t)512 * 512 * 2);
  unsigned short* W2t  = (unsigned short*)take((size_t)512 * 256 * 2);
  unsigned short* pW1t = (unsigned short*)take((size_t)256 * 512 * 2);
  unsigned short* pW2t = (unsigned short*)take((size_t)512 * 256 * 2);

  float* ph   = h1;  // predictor hidden reuses h1
  float* pred = h2;  // predictor output reuses h2
  float* pn   = x2;  // l2norm(pred) reuses x2

  const int MB = (NN + GBM - 1) / GBM;  // 79

  // ---- input/weight converts ----
  f32_to_bf16_k<<<1024, 256, 0, stream>>>(x, xb, NN * 512 / 4);
  conv_transpose_bf16<<<512, 256, 0, stream>>>(W1, W1t, 512, 512);
  conv_transpose_bf16<<<256, 256, 0, stream>>>(W2, W2t, 512, 256);
  conv_transpose_bf16<<<256, 256, 0, stream>>>(pW1, pW1t, 256, 512);
  conv_transpose_bf16<<<256, 256, 0, stream>>>(pW2, pW2t, 512, 256);

  // CSR for GCN (grouped by destination col)
  hipMemsetAsync(cnt, 0, NN * 4, stream);
  count_kernel<<<512, 256, 0, stream>>>(col, cnt, NE);
  scan_kernel<<<1, 1024, 0, stream>>>(cnt, ptrg, NN);
  hipMemsetAsync(cnt, 0, NN * 4, stream);
  fill_kernel<<<512, 256, 0, stream>>>(col, row, ptrg, cnt, ridx, NE);
  dis_kernel<<<(NN + 255) / 256, 256, 0, stream>>>(ptrg, dis, NN);

  // CSR for neighbor graph (grouped by nrow)
  hipMemsetAsync(cnt, 0, NN * 4, stream);
  count_kernel<<<512, 256, 0, stream>>>(nrow, cnt, NE);
  scan_kernel<<<1, 1024, 0, stream>>>(cnt, ptrn, NN);
  hipMemsetAsync(cnt, 0, NN * 4, stream);
  fill_kernel<<<512, 256, 0, stream>>>(nrow, ncol, ptrn, cnt, ncidx, NE);

  // ---- encoder layer 1 ----
  { dim3 g(512 / GBN, MB);
    gemm_bf16<<<g, 256, 0, stream>>>(xb, W1t, nullptr, h1, NN, 512, 512); }
  gcn_agg<512><<<NN, 64, 0, stream>>>(h1, dis, ptrg, ridx, b1, x2);
  hipMemsetAsync(bnsum, 0, 1024 * 4, stream);
  bn_stats<512><<<128, 256, 0, stream>>>(x2, bnsum, bnsq, NN);
  bn_finalize<<<2, 256, 0, stream>>>(bnsum, bnsq, g1, bb1, scale, shift, NN, 512);
  bn_apply_prelu<false><<<2048, 256, 0, stream>>>(x2, nullptr, x2b, scale, shift,
                                                  pr1, NN * 512 / 4, 511);

  // ---- encoder layer 2 ----
  { dim3 g(256 / GBN, MB);
    gemm_bf16<<<g, 256, 0, stream>>>(x2b, W2t, nullptr, h2, NN, 256, 512); }
  gcn_agg<256><<<NN, 64, 0, stream>>>(h2, dis, ptrg, ridx, b2, student);
  hipMemsetAsync(bnsum, 0, 1024 * 4, stream);
  bn_stats<256><<<128, 256, 0, stream>>>(student, bnsum, bnsq, NN);
  bn_finalize<<<2, 256, 0, stream>>>(bnsum, bnsq, g2, bb2, scale, shift, NN, 256);
  bn_apply_prelu<true><<<2048, 256, 0, stream>>>(student, student, stb, scale, shift,
                                                 pr2, NN * 256 / 4, 255);

  // ---- sn = l2norm(student) ; teacher == student, so tn = tgt = sn ----
  l2norm_k<<<NN, 64, 0, stream>>>(student, sn);

  // ---- predictor ----
  { dim3 g(512 / GBN, MB);
    gemm_bf16<<<g, 256, 0, stream>>>(stb, pW1t, pb1, ph, NN, 512, 256); }
  hipMemsetAsync(bnsum, 0, 1024 * 4, stream);
  bn_stats<512><<<128, 256, 0, stream>>>(ph, bnsum, bnsq, NN);
  bn_finalize<<<2, 256, 0, stream>>>(bnsum, bnsq, pg, pbb, scale, shift, NN, 512);
  bn_apply_prelu<false><<<2048, 256, 0, stream>>>(ph, nullptr, phb, scale, shift,
                                                  ppr, NN * 512 / 4, 511);
  { dim3 g(256 / GBN, MB);
    gemm_bf16<<<g, 256, 0, stream>>>(phb, pW2t, pb2, pred, NN, 256, 512); }
  l2norm_k<<<NN, 64, 0, stream>>>(pred, pn);

  // ---- per-row top-3 neighbors ----
  topk_kernel<<<NN, 64, 0, stream>>>(sn, ptrn, ncidx, nb);

  // ---- loss ----
  loss_terms<<<LOSS_NB, 256, 0, stream>>>(pn, sn, nb, part, NN);
  finalize_loss<<<1, 64, 0, stream>>>(part, loss, LOSS_NB, NN);
}

// Round 5
// 463.434 us; speedup vs baseline: 2.2215x; 1.1084x over previous
//
#include <hip/hip_runtime.h>
#include <math.h>

#define NN 10000
#define NE 320000

typedef __attribute__((ext_vector_type(8))) short bf16x8;
typedef __attribute__((ext_vector_type(4))) float f32x4;

__device__ inline unsigned short f2bf(float f) {
  unsigned u = __float_as_uint(f);
  unsigned r = (u + 0x7fffu + ((u >> 16) & 1u)) >> 16;
  return (unsigned short)r;
}
__device__ inline float bflo(unsigned u) { return __uint_as_float(u << 16); }
__device__ inline float bfhi(unsigned u) { return __uint_as_float(u & 0xffff0000u); }

// ---------------- converts ----------------
__global__ void f32_to_bf16_k(const float* __restrict__ in,
                              unsigned short* __restrict__ out, int total4) {
  for (int i = blockIdx.x * blockDim.x + threadIdx.x; i < total4;
       i += gridDim.x * blockDim.x) {
    const float4 v = reinterpret_cast<const float4*>(in)[i];
    ushort4 o;
    o.x = f2bf(v.x); o.y = f2bf(v.y); o.z = f2bf(v.z); o.w = f2bf(v.w);
    reinterpret_cast<ushort4*>(out)[i] = o;
  }
}

// Wt[n][k] = bf16(W[k][n]);  W is K x N row-major
__global__ void conv_transpose_bf16(const float* __restrict__ W,
                                    unsigned short* __restrict__ Wt, int K, int N) {
  const int total = K * N;
  for (int i = blockIdx.x * blockDim.x + threadIdx.x; i < total;
       i += gridDim.x * blockDim.x) {
    const int n = i / K, k = i - n * K;
    Wt[i] = f2bf(W[(size_t)k * N + n]);
  }
}

// ---------------- MFMA GEMM: A (MxK bf16 rm) x Bt (NxK bf16) -> C (MxN) -----
// BF16OUT: writes bf16 C scaled per-row by rowscale (for GCN staging).
// else:    writes f32 C (+bias).
#define GBM 128
#define GBN 64
#define GBK 32
#define SAS 40  // padded LDS row stride (elements): bank stride 20 -> 2-way free

template <bool BF16OUT>
__global__ __launch_bounds__(256) void gemm_bf16(
    const unsigned short* __restrict__ A, const unsigned short* __restrict__ Bt,
    const float* __restrict__ bias, const float* __restrict__ rowscale,
    float* __restrict__ Cf, unsigned short* __restrict__ Cb,
    int M, int N, int K) {
  __shared__ unsigned short As[GBM * SAS];
  __shared__ unsigned short Bs[GBN * SAS];
  const int bm = blockIdx.y * GBM;
  const int bn = blockIdx.x * GBN;
  const int tid = threadIdx.x;
  const int wave = tid >> 6, lane = tid & 63;
  const int wm = wave & 1, wn = wave >> 1;  // wave tile 64(M) x 32(N)
  f32x4 acc[4][2] = {};

  const int srow = tid >> 2;            // 0..63
  const int scol = (tid & 3) << 3;      // 0,8,16,24 (bf16 elems)

  for (int k0 = 0; k0 < K; k0 += GBK) {
#pragma unroll
    for (int r = 0; r < 2; ++r) {       // A: 128 rows in 2 rounds
      const int row = srow + (r << 6);
      const int gr = bm + row;
      uint4 v = make_uint4(0u, 0u, 0u, 0u);
      if (gr < M) v = *reinterpret_cast<const uint4*>(&A[(size_t)gr * K + k0 + scol]);
      *reinterpret_cast<uint4*>(&As[row * SAS + scol]) = v;
    }
    {                                   // Bt: 64 rows in 1 round
      const uint4 v = *reinterpret_cast<const uint4*>(
          &Bt[(size_t)(bn + srow) * K + k0 + scol]);
      *reinterpret_cast<uint4*>(&Bs[srow * SAS + scol]) = v;
    }
    __syncthreads();
    const int kofs = (lane >> 4) << 3;  // 0,8,16,24
    const int rl = lane & 15;
    bf16x8 af[4], bfr[2];
#pragma unroll
    for (int m = 0; m < 4; ++m)
      af[m] = *reinterpret_cast<const bf16x8*>(
          &As[((wm << 6) + (m << 4) + rl) * SAS + kofs]);
#pragma unroll
    for (int n = 0; n < 2; ++n)
      bfr[n] = *reinterpret_cast<const bf16x8*>(
          &Bs[((wn << 5) + (n << 4) + rl) * SAS + kofs]);
#pragma unroll
    for (int m = 0; m < 4; ++m)
#pragma unroll
      for (int n = 0; n < 2; ++n)
        acc[m][n] = __builtin_amdgcn_mfma_f32_16x16x32_bf16(af[m], bfr[n], acc[m][n], 0, 0, 0);
    __syncthreads();
  }
  // epilogue: D[row][col], col = lane&15, row = (lane>>4)*4 + reg
  const int crow0 = (lane >> 4) << 2;
  const int ccol = lane & 15;
#pragma unroll
  for (int n = 0; n < 2; ++n) {
    const int col = bn + (wn << 5) + (n << 4) + ccol;
    const float bv = (!BF16OUT && bias) ? bias[col] : 0.f;
#pragma unroll
    for (int m = 0; m < 4; ++m) {
#pragma unroll
      for (int r = 0; r < 4; ++r) {
        const int rowg = bm + (wm << 6) + (m << 4) + crow0 + r;
        if (rowg < M) {
          if (BF16OUT)
            Cb[(size_t)rowg * N + col] = f2bf(acc[m][n][r] * rowscale[rowg]);
          else
            Cf[(size_t)rowg * N + col] = acc[m][n][r] + bv;
        }
      }
    }
  }
}

// ---------------- CSR build helpers ----------------
__global__ void count_kernel(const int* __restrict__ key, int* __restrict__ cnt, int E) {
  for (int e = blockIdx.x * blockDim.x + threadIdx.x; e < E; e += gridDim.x * blockDim.x)
    atomicAdd(&cnt[key[e]], 1);
}

__global__ __launch_bounds__(1024) void scan_kernel(const int* __restrict__ cnt,
                                                    int* __restrict__ ptr, int n) {
  __shared__ int s[1024];
  const int t = threadIdx.x;
  const int chunk = (n + 1023) >> 10;
  const int start = t * chunk;
  const int end = min(start + chunk, n);
  int sum = 0;
  for (int i = start; i < end; ++i) sum += cnt[i];
  s[t] = sum;
  __syncthreads();
  for (int off = 1; off < 1024; off <<= 1) {
    int v = 0;
    if (t >= off) v = s[t - off];
    __syncthreads();
    s[t] += v;
    __syncthreads();
  }
  int excl = (t == 0) ? 0 : s[t - 1];
  for (int i = start; i < end; ++i) { ptr[i] = excl; excl += cnt[i]; }
  if (t == 1023) ptr[n] = s[1023];
}

__global__ void fill_kernel(const int* __restrict__ key, const int* __restrict__ val,
                            const int* __restrict__ ptr, int* __restrict__ cur,
                            int* __restrict__ out, int E) {
  for (int e = blockIdx.x * blockDim.x + threadIdx.x; e < E; e += gridDim.x * blockDim.x) {
    const int k = key[e];
    const int p = atomicAdd(&cur[k], 1);
    out[ptr[k] + p] = val[e];
  }
}

__global__ void dis_kernel(const int* __restrict__ ptr, float* __restrict__ dis, int n) {
  const int j = blockIdx.x * blockDim.x + threadIdx.x;
  if (j < n) dis[j] = 1.0f / sqrtf((float)(ptr[j + 1] - ptr[j] + 1));
}

// ------- GCN aggregation over pre-scaled bf16 rows (one wave per node) -------
// hs[r][c] = dis[r] * h[r][c] (bf16).  out[j] = dis[j]*(hs[j] + sum_e hs[r_e]) + bias
template <int C>
__global__ __launch_bounds__(64) void gcn_agg_b(const unsigned short* __restrict__ hs,
    const float* __restrict__ dis, const int* __restrict__ ptr,
    const int* __restrict__ ridx, const float* __restrict__ bias,
    float* __restrict__ out) {
  constexpr int P = C / 64;   // bf16 elems per lane (8 or 4)
  constexpr int U = P / 2;    // dwords per lane (4 or 2)
  const int j = blockIdx.x;
  const int t = threadIdx.x;
  float acc[P];
  {
    const unsigned short* hj = hs + (size_t)j * C + t * P;
    if constexpr (U == 4) {
      const uint4 v = *reinterpret_cast<const uint4*>(hj);
      acc[0] = bflo(v.x); acc[1] = bfhi(v.x);
      acc[2] = bflo(v.y); acc[3] = bfhi(v.y);
      acc[4] = bflo(v.z); acc[5] = bfhi(v.z);
      acc[6] = bflo(v.w); acc[7] = bfhi(v.w);
    } else {
      const uint2 v = *reinterpret_cast<const uint2*>(hj);
      acc[0] = bflo(v.x); acc[1] = bfhi(v.x);
      acc[2] = bflo(v.y); acc[3] = bfhi(v.y);
    }
  }
  const int e0 = ptr[j], e1 = ptr[j + 1];
  for (int e = e0; e < e1; ++e) {
    const int r = ridx[e];
    const unsigned short* hr = hs + (size_t)r * C + t * P;
    if constexpr (U == 4) {
      const uint4 v = *reinterpret_cast<const uint4*>(hr);
      acc[0] += bflo(v.x); acc[1] += bfhi(v.x);
      acc[2] += bflo(v.y); acc[3] += bfhi(v.y);
      acc[4] += bflo(v.z); acc[5] += bfhi(v.z);
      acc[6] += bflo(v.w); acc[7] += bfhi(v.w);
    } else {
      const uint2 v = *reinterpret_cast<const uint2*>(hr);
      acc[0] += bflo(v.x); acc[1] += bfhi(v.x);
      acc[2] += bflo(v.y); acc[3] += bfhi(v.y);
    }
  }
  const float dj = dis[j];
  float* o = out + (size_t)j * C + t * P;
  const float* bs = bias + t * P;
#pragma unroll
  for (int u = 0; u < U; u += 2) {
    float4 w;
    w.x = fmaf(dj, acc[2 * u + 0], bs[2 * u + 0]);
    w.y = fmaf(dj, acc[2 * u + 1], bs[2 * u + 1]);
    w.z = fmaf(dj, acc[2 * u + 2], bs[2 * u + 2]);
    w.w = fmaf(dj, acc[2 * u + 3], bs[2 * u + 3]);
    *reinterpret_cast<float4*>(o + 2 * u) = w;
  }
}

// ---------------- BatchNorm ----------------
template <int C>
__global__ __launch_bounds__(256) void bn_stats(const float* __restrict__ x,
    float* __restrict__ sums, float* __restrict__ sqs, int n) {
  constexpr int P = C / 256;
  float s[P], q[P];
#pragma unroll
  for (int p = 0; p < P; ++p) { s[p] = 0.f; q[p] = 0.f; }
  const int rpb = (n + gridDim.x - 1) / gridDim.x;
  const int r0 = blockIdx.x * rpb;
  const int r1 = min(r0 + rpb, n);
  for (int r = r0; r < r1; ++r) {
#pragma unroll
    for (int p = 0; p < P; ++p) {
      const float v = x[(size_t)r * C + threadIdx.x + (p << 8)];
      s[p] += v;
      q[p] = fmaf(v, v, q[p]);
    }
  }
#pragma unroll
  for (int p = 0; p < P; ++p) {
    atomicAdd(&sums[threadIdx.x + (p << 8)], s[p]);
    atomicAdd(&sqs[threadIdx.x + (p << 8)], q[p]);
  }
}

__global__ void bn_finalize(const float* __restrict__ sums, const float* __restrict__ sqs,
    const float* __restrict__ g, const float* __restrict__ b,
    float* __restrict__ scale, float* __restrict__ shift, int n, int C) {
  const int c = blockIdx.x * blockDim.x + threadIdx.x;
  if (c >= C) return;
  const float m = sums[c] / n;
  const float var = sqs[c] / n - m * m;
  const float sc = g[c] / sqrtf(var + 1e-5f);
  scale[c] = sc;
  shift[c] = b[c] - m * sc;
}

// BN+PReLU; always writes bf16 copy, optionally f32 (in-place allowed)
template <bool WRITE_F32>
__global__ void bn_apply_prelu(const float* __restrict__ in, float* __restrict__ outf,
    unsigned short* __restrict__ outb, const float* __restrict__ scale,
    const float* __restrict__ shift, const float* __restrict__ pa,
    int total4, int cmask) {
  const float a = pa[0];
  for (int i = blockIdx.x * blockDim.x + threadIdx.x; i < total4;
       i += gridDim.x * blockDim.x) {
    float4 v = reinterpret_cast<const float4*>(in)[i];
    const int c0 = (i << 2) & cmask;
    float r[4] = {v.x, v.y, v.z, v.w};
    ushort4 o;
    unsigned short* op = reinterpret_cast<unsigned short*>(&o);
#pragma unroll
    for (int j = 0; j < 4; ++j) {
      float t = fmaf(r[j], scale[c0 + j], shift[c0 + j]);
      t = t > 0.f ? t : a * t;
      r[j] = t;
      op[j] = f2bf(t);
    }
    if (WRITE_F32)
      reinterpret_cast<float4*>(outf)[i] = make_float4(r[0], r[1], r[2], r[3]);
    reinterpret_cast<ushort4*>(outb)[i] = o;
  }
}

// ---------------- l2norm over 256-dim rows (one wave per row) ----------------
__global__ __launch_bounds__(64) void l2norm_k(const float* __restrict__ x,
                                               float* __restrict__ y) {
  const int r = blockIdx.x, t = threadIdx.x;
  const float4 v = reinterpret_cast<const float4*>(x + (size_t)r * 256)[t];
  float sq = v.x * v.x + v.y * v.y + v.z * v.z + v.w * v.w;
#pragma unroll
  for (int o = 1; o < 64; o <<= 1) sq += __shfl_xor(sq, o);
  const float inv = 1.0f / sqrtf(sq + 1e-12f);
  reinterpret_cast<float4*>(y + (size_t)r * 256)[t] =
      make_float4(v.x * inv, v.y * inv, v.z * inv, v.w * inv);
}

// ---------------- per-row edge sims + dedup + top-3 (one wave per row) -------
#define MAXK 256
__global__ __launch_bounds__(64) void topk_kernel(const float* __restrict__ sn,
    const int* __restrict__ ptr, const int* __restrict__ ncol, int* __restrict__ nb) {
  const int i = blockIdx.x;
  const int lane = threadIdx.x;
  __shared__ float sni[256];
  __shared__ float vals[MAXK];
  __shared__ int   cols[MAXK];
  __shared__ float mvals[MAXK];
  __shared__ int   mcols[MAXK];
  reinterpret_cast<float4*>(sni)[lane] =
      reinterpret_cast<const float4*>(sn + (size_t)i * 256)[lane];
  __syncthreads();
  const int e0 = ptr[i];
  const int k  = min(ptr[i + 1] - e0, MAXK);
  for (int e = lane; e < k; e += 64) {
    const int j = ncol[e0 + e];
    const float4* bj = reinterpret_cast<const float4*>(sn + (size_t)j * 256);
    const float4* aj = reinterpret_cast<const float4*>(sni);
    float s = 0.f;
#pragma unroll 8
    for (int q = 0; q < 64; ++q) {
      const float4 b = bj[q];
      const float4 a = aj[q];
      s = fmaf(a.x, b.x, s);
      s = fmaf(a.y, b.y, s);
      s = fmaf(a.z, b.z, s);
      s = fmaf(a.w, b.w, s);
    }
    vals[e] = s;
    cols[e] = j;
  }
  __syncthreads();
  for (int e = lane; e < k; e += 64) {
    const int c = cols[e];
    bool first = true;
    float sum = vals[e];
    for (int q = 0; q < k; ++q) {
      if (q == e) continue;
      if (cols[q] == c) {
        if (q < e) { first = false; break; }
        sum += vals[q];
      }
    }
    mvals[e] = sum;
    mcols[e] = first ? c : -1;
  }
  __syncthreads();
  for (int s = 0; s < 3; ++s) {
    unsigned long long best = 0ull;
    for (int e = lane; e < k; e += 64) {
      const int c = mcols[e];
      if (c < 0) continue;
      const float v = mvals[e];
      if (v <= 0.f) continue;
      const unsigned long long key =
          ((unsigned long long)__float_as_uint(v) << 32) |
          (unsigned long long)(0xFFFFFFFFu - (unsigned)c);
      if (key > best) best = key;
    }
#pragma unroll
    for (int off = 1; off < 64; off <<= 1) {
      const unsigned long long o = __shfl_xor(best, off);
      if (o > best) best = o;
    }
    const int wcol = best ? (int)(0xFFFFFFFFu - (unsigned)(best & 0xFFFFFFFFu)) : -1;
    if (lane == 0) nb[i * 3 + s] = wcol;
    if (wcol >= 0)
      for (int e = lane; e < k; e += 64)
        if (mcols[e] == wcol) mcols[e] = -1;
    __syncthreads();
  }
}

// ---------------- loss terms (no atomics: per-block partials) ----------------
__global__ __launch_bounds__(256) void loss_terms(const float* __restrict__ pn,
    const float* __restrict__ tgt, const int* __restrict__ nb,
    float* __restrict__ part, int n) {
  const int t = threadIdx.x, wave = t >> 6, lane = t & 63;
  const int r = blockIdx.x * 4 + wave;
  float vals[7] = {0.f, 0.f, 0.f, 0.f, 0.f, 0.f, 0.f};
  if (r < n) {
    const float4 a = reinterpret_cast<const float4*>(pn + (size_t)r * 256)[lane];
    const float4 b = reinterpret_cast<const float4*>(tgt + (size_t)r * 256)[lane];
    float d = a.x * b.x + a.y * b.y + a.z * b.z + a.w * b.w;
#pragma unroll
    for (int o = 1; o < 64; o <<= 1) d += __shfl_xor(d, o);
    vals[0] = 2.f - 2.f * d;
    for (int s = 0; s < 3; ++s) {
      const int j = nb[r * 3 + s];
      if (j >= 0) {
        const float4 c = reinterpret_cast<const float4*>(tgt + (size_t)j * 256)[lane];
        float e = a.x * c.x + a.y * c.y + a.z * c.z + a.w * c.w;
#pragma unroll
        for (int o = 1; o < 64; o <<= 1) e += __shfl_xor(e, o);
        vals[1 + s] = 2.f - 2.f * e;
        vals[4 + s] = 1.f;
      }
    }
  }
  __shared__ float red[4][7];
  if (lane == 0)
    for (int q = 0; q < 7; ++q) red[wave][q] = vals[q];
  __syncthreads();
  if (t < 7)
    part[(size_t)blockIdx.x * 8 + t] =
        red[0][t] + red[1][t] + red[2][t] + red[3][t];
}

__global__ __launch_bounds__(64) void finalize_loss(const float* __restrict__ part,
    float* __restrict__ out, int nblocks, int n) {
  const int lane = threadIdx.x;
  float comp[7] = {0.f, 0.f, 0.f, 0.f, 0.f, 0.f, 0.f};
  for (int b = lane; b < nblocks; b += 64) {
#pragma unroll
    for (int q = 0; q < 7; ++q) comp[q] += part[(size_t)b * 8 + q];
  }
#pragma unroll
  for (int q = 0; q < 7; ++q) {
#pragma unroll
    for (int o = 1; o < 64; o <<= 1) comp[q] += __shfl_xor(comp[q], o);
  }
  if (lane == 0) {
    float loss = comp[0] / n;
    for (int s = 0; s < 3; ++s) loss += comp[1 + s] / fmaxf(comp[4 + s], 1.f);
    out[0] = loss * 0.25f;
  }
}

// ---------------- host ----------------
extern "C" void kernel_launch(void* const* d_in, const int* in_sizes, int n_in,
                              void* d_out, int out_size, void* d_ws, size_t ws_size,
                              hipStream_t stream) {
  const float* x   = (const float*)d_in[0];
  const int*   eidx = (const int*)d_in[1];
  const int*   nidx = (const int*)d_in[2];
  const float* W1  = (const float*)d_in[3];
  const float* b1  = (const float*)d_in[4];
  const float* g1  = (const float*)d_in[5];
  const float* bb1 = (const float*)d_in[6];
  const float* pr1 = (const float*)d_in[7];
  const float* W2  = (const float*)d_in[8];
  const float* b2  = (const float*)d_in[9];
  const float* g2  = (const float*)d_in[10];
  const float* bb2 = (const float*)d_in[11];
  const float* pr2 = (const float*)d_in[12];
  const float* pW1 = (const float*)d_in[13];
  const float* pb1 = (const float*)d_in[14];
  const float* pg  = (const float*)d_in[15];
  const float* pbb = (const float*)d_in[16];
  const float* ppr = (const float*)d_in[17];
  const float* pW2 = (const float*)d_in[18];
  const float* pb2 = (const float*)d_in[19];

  const int* row  = eidx;
  const int* col  = eidx + NE;
  const int* nrow = nidx;
  const int* ncol = nidx + NE;

  float* student = (float*)d_out;              // NN x 256
  float* loss    = student + (size_t)NN * 256; // scalar

  char* ws = (char*)d_ws;
  size_t off = 0;
  auto take = [&](size_t bytes) -> void* {
    void* p = ws + off;
    off += (bytes + 255) & ~(size_t)255;
    return p;
  };
  const int LOSS_NB = NN / 4;
  float* h1    = (float*)take((size_t)NN * 512 * 4);
  float* x2    = (float*)take((size_t)NN * 512 * 4);
  float* h2    = (float*)take((size_t)NN * 256 * 4);
  float* sn    = (float*)take((size_t)NN * 256 * 4);
  float* dis   = (float*)take((size_t)NN * 4);
  int*   cnt   = (int*)take((size_t)NN * 4);
  int*   ptrg  = (int*)take((size_t)(NN + 1) * 4);
  int*   ridx  = (int*)take((size_t)NE * 4);
  int*   ptrn  = (int*)take((size_t)(NN + 1) * 4);
  int*   ncidx = (int*)take((size_t)NE * 4);
  int*   nb    = (int*)take((size_t)NN * 3 * 4);
  float* bnsum = (float*)take(1024 * 4);
  float* bnsq  = bnsum + 512;
  float* scale = (float*)take(512 * 4);
  float* shift = (float*)take(512 * 4);
  float* part  = (float*)take((size_t)LOSS_NB * 8 * 4);
  // bf16 buffers
  unsigned short* xb   = (unsigned short*)take((size_t)NN * 512 * 2);
  unsigned short* x2b  = (unsigned short*)take((size_t)NN * 512 * 2);
  unsigned short* stb  = (unsigned short*)take((size_t)NN * 256 * 2);
  unsigned short* phb  = (unsigned short*)take((size_t)NN * 512 * 2);
  unsigned short* h1b  = (unsigned short*)take((size_t)NN * 512 * 2);
  unsigned short* h2b  = (unsigned short*)take((size_t)NN * 256 * 2);
  unsigned short* W1t  = (unsigned short*)take((size_t)512 * 512 * 2);
  unsigned short* W2t  = (unsigned short*)take((size_t)512 * 256 * 2);
  unsigned short* pW1t = (unsigned short*)take((size_t)256 * 512 * 2);
  unsigned short* pW2t = (unsigned short*)take((size_t)512 * 256 * 2);

  float* ph   = h1;  // predictor hidden reuses h1
  float* pred = h2;  // predictor output reuses h2
  float* pn   = x2;  // l2norm(pred) reuses x2

  const int MB = (NN + GBM - 1) / GBM;  // 79

  // ---- input/weight converts ----
  f32_to_bf16_k<<<1024, 256, 0, stream>>>(x, xb, NN * 512 / 4);
  conv_transpose_bf16<<<512, 256, 0, stream>>>(W1, W1t, 512, 512);
  conv_transpose_bf16<<<256, 256, 0, stream>>>(W2, W2t, 512, 256);
  conv_transpose_bf16<<<256, 256, 0, stream>>>(pW1, pW1t, 256, 512);
  conv_transpose_bf16<<<256, 256, 0, stream>>>(pW2, pW2t, 512, 256);

  // CSR for GCN (grouped by destination col)
  hipMemsetAsync(cnt, 0, NN * 4, stream);
  count_kernel<<<512, 256, 0, stream>>>(col, cnt, NE);
  scan_kernel<<<1, 1024, 0, stream>>>(cnt, ptrg, NN);
  hipMemsetAsync(cnt, 0, NN * 4, stream);
  fill_kernel<<<512, 256, 0, stream>>>(col, row, ptrg, cnt, ridx, NE);
  dis_kernel<<<(NN + 255) / 256, 256, 0, stream>>>(ptrg, dis, NN);

  // CSR for neighbor graph (grouped by nrow)
  hipMemsetAsync(cnt, 0, NN * 4, stream);
  count_kernel<<<512, 256, 0, stream>>>(nrow, cnt, NE);
  scan_kernel<<<1, 1024, 0, stream>>>(cnt, ptrn, NN);
  hipMemsetAsync(cnt, 0, NN * 4, stream);
  fill_kernel<<<512, 256, 0, stream>>>(nrow, ncol, ptrn, cnt, ncidx, NE);

  // ---- encoder layer 1 ----
  { dim3 g(512 / GBN, MB);
    gemm_bf16<true><<<g, 256, 0, stream>>>(xb, W1t, nullptr, dis, nullptr, h1b,
                                           NN, 512, 512); }
  gcn_agg_b<512><<<NN, 64, 0, stream>>>(h1b, dis, ptrg, ridx, b1, x2);
  hipMemsetAsync(bnsum, 0, 1024 * 4, stream);
  bn_stats<512><<<128, 256, 0, stream>>>(x2, bnsum, bnsq, NN);
  bn_finalize<<<2, 256, 0, stream>>>(bnsum, bnsq, g1, bb1, scale, shift, NN, 512);
  bn_apply_prelu<false><<<2048, 256, 0, stream>>>(x2, nullptr, x2b, scale, shift,
                                                  pr1, NN * 512 / 4, 511);

  // ---- encoder layer 2 ----
  { dim3 g(256 / GBN, MB);
    gemm_bf16<true><<<g, 256, 0, stream>>>(x2b, W2t, nullptr, dis, nullptr, h2b,
                                           NN, 256, 512); }
  gcn_agg_b<256><<<NN, 64, 0, stream>>>(h2b, dis, ptrg, ridx, b2, student);
  hipMemsetAsync(bnsum, 0, 1024 * 4, stream);
  bn_stats<256><<<128, 256, 0, stream>>>(student, bnsum, bnsq, NN);
  bn_finalize<<<2, 256, 0, stream>>>(bnsum, bnsq, g2, bb2, scale, shift, NN, 256);
  bn_apply_prelu<true><<<2048, 256, 0, stream>>>(student, student, stb, scale, shift,
                                                 pr2, NN * 256 / 4, 255);

  // ---- sn = l2norm(student) ; teacher == student, so tn = tgt = sn ----
  l2norm_k<<<NN, 64, 0, stream>>>(student, sn);

  // ---- predictor ----
  { dim3 g(512 / GBN, MB);
    gemm_bf16<false><<<g, 256, 0, stream>>>(stb, pW1t, pb1, nullptr, ph, nullptr,
                                            NN, 512, 256); }
  hipMemsetAsync(bnsum, 0, 1024 * 4, stream);
  bn_stats<512><<<128, 256, 0, stream>>>(ph, bnsum, bnsq, NN);
  bn_finalize<<<2, 256, 0, stream>>>(bnsum, bnsq, pg, pbb, scale, shift, NN, 512);
  bn_apply_prelu<false><<<2048, 256, 0, stream>>>(ph, nullptr, phb, scale, shift,
                                                  ppr, NN * 512 / 4, 511);
  { dim3 g(256 / GBN, MB);
    gemm_bf16<false><<<g, 256, 0, stream>>>(phb, pW2t, pb2, nullptr, pred, nullptr,
                                            NN, 256, 512); }
  l2norm_k<<<NN, 64, 0, stream>>>(pred, pn);

  // ---- per-row top-3 neighbors ----
  topk_kernel<<<NN, 64, 0, stream>>>(sn, ptrn, ncidx, nb);

  // ---- loss ----
  loss_terms<<<LOSS_NB, 256, 0, stream>>>(pn, sn, nb, part, NN);
  finalize_loss<<<1, 64, 0, stream>>>(part, loss, LOSS_NB, NN);
}

// Round 6
// 444.815 us; speedup vs baseline: 2.3145x; 1.0419x over previous
//
#include <hip/hip_runtime.h>
#include <math.h>

#define NN 10000
#define NE 320000

typedef __attribute__((ext_vector_type(8))) short bf16x8;
typedef __attribute__((ext_vector_type(4))) float f32x4;

__device__ inline unsigned short f2bf(float f) {
  unsigned u = __float_as_uint(f);
  unsigned r = (u + 0x7fffu + ((u >> 16) & 1u)) >> 16;
  return (unsigned short)r;
}
__device__ inline float bflo(unsigned u) { return __uint_as_float(u << 16); }
__device__ inline float bfhi(unsigned u) { return __uint_as_float(u & 0xffff0000u); }

// ---------------- converts ----------------
__global__ void f32_to_bf16_k(const float* __restrict__ in,
                              unsigned short* __restrict__ out, int total4) {
  for (int i = blockIdx.x * blockDim.x + threadIdx.x; i < total4;
       i += gridDim.x * blockDim.x) {
    const float4 v = reinterpret_cast<const float4*>(in)[i];
    ushort4 o;
    o.x = f2bf(v.x); o.y = f2bf(v.y); o.z = f2bf(v.z); o.w = f2bf(v.w);
    reinterpret_cast<ushort4*>(out)[i] = o;
  }
}

// Wt[n][k] = bf16(W[k][n]);  W is K x N row-major
__global__ void conv_transpose_bf16(const float* __restrict__ W,
                                    unsigned short* __restrict__ Wt, int K, int N) {
  const int total = K * N;
  for (int i = blockIdx.x * blockDim.x + threadIdx.x; i < total;
       i += gridDim.x * blockDim.x) {
    const int n = i / K, k = i - n * K;
    Wt[i] = f2bf(W[(size_t)k * N + n]);
  }
}

// ---------------- MFMA GEMM: A (MxK bf16 rm) x Bt (NxK bf16) -> C (MxN) -----
// BF16OUT: writes bf16 C scaled per-row by rowscale (for GCN staging).
// else:    writes f32 C (+bias).
#define GBM 128
#define GBN 64
#define GBK 32
#define SAS 40  // padded LDS row stride (elements): bank stride 20 -> 2-way free

template <bool BF16OUT>
__global__ __launch_bounds__(256) void gemm_bf16(
    const unsigned short* __restrict__ A, const unsigned short* __restrict__ Bt,
    const float* __restrict__ bias, const float* __restrict__ rowscale,
    float* __restrict__ Cf, unsigned short* __restrict__ Cb,
    int M, int N, int K) {
  __shared__ unsigned short As[GBM * SAS];
  __shared__ unsigned short Bs[GBN * SAS];
  const int bm = blockIdx.y * GBM;
  const int bn = blockIdx.x * GBN;
  const int tid = threadIdx.x;
  const int wave = tid >> 6, lane = tid & 63;
  const int wm = wave & 1, wn = wave >> 1;  // wave tile 64(M) x 32(N)
  f32x4 acc[4][2] = {};

  const int srow = tid >> 2;            // 0..63
  const int scol = (tid & 3) << 3;      // 0,8,16,24 (bf16 elems)

  for (int k0 = 0; k0 < K; k0 += GBK) {
#pragma unroll
    for (int r = 0; r < 2; ++r) {       // A: 128 rows in 2 rounds
      const int row = srow + (r << 6);
      const int gr = bm + row;
      uint4 v = make_uint4(0u, 0u, 0u, 0u);
      if (gr < M) v = *reinterpret_cast<const uint4*>(&A[(size_t)gr * K + k0 + scol]);
      *reinterpret_cast<uint4*>(&As[row * SAS + scol]) = v;
    }
    {                                   // Bt: 64 rows in 1 round
      const uint4 v = *reinterpret_cast<const uint4*>(
          &Bt[(size_t)(bn + srow) * K + k0 + scol]);
      *reinterpret_cast<uint4*>(&Bs[srow * SAS + scol]) = v;
    }
    __syncthreads();
    const int kofs = (lane >> 4) << 3;  // 0,8,16,24
    const int rl = lane & 15;
    bf16x8 af[4], bfr[2];
#pragma unroll
    for (int m = 0; m < 4; ++m)
      af[m] = *reinterpret_cast<const bf16x8*>(
          &As[((wm << 6) + (m << 4) + rl) * SAS + kofs]);
#pragma unroll
    for (int n = 0; n < 2; ++n)
      bfr[n] = *reinterpret_cast<const bf16x8*>(
          &Bs[((wn << 5) + (n << 4) + rl) * SAS + kofs]);
#pragma unroll
    for (int m = 0; m < 4; ++m)
#pragma unroll
      for (int n = 0; n < 2; ++n)
        acc[m][n] = __builtin_amdgcn_mfma_f32_16x16x32_bf16(af[m], bfr[n], acc[m][n], 0, 0, 0);
    __syncthreads();
  }
  // epilogue: D[row][col], col = lane&15, row = (lane>>4)*4 + reg
  const int crow0 = (lane >> 4) << 2;
  const int ccol = lane & 15;
#pragma unroll
  for (int n = 0; n < 2; ++n) {
    const int col = bn + (wn << 5) + (n << 4) + ccol;
    const float bv = (!BF16OUT && bias) ? bias[col] : 0.f;
#pragma unroll
    for (int m = 0; m < 4; ++m) {
#pragma unroll
      for (int r = 0; r < 4; ++r) {
        const int rowg = bm + (wm << 6) + (m << 4) + crow0 + r;
        if (rowg < M) {
          if (BF16OUT)
            Cb[(size_t)rowg * N + col] = f2bf(acc[m][n][r] * rowscale[rowg]);
          else
            Cf[(size_t)rowg * N + col] = acc[m][n][r] + bv;
        }
      }
    }
  }
}

// ---------------- CSR build helpers ----------------
__global__ void count_kernel(const int* __restrict__ key, int* __restrict__ cnt, int E) {
  for (int e = blockIdx.x * blockDim.x + threadIdx.x; e < E; e += gridDim.x * blockDim.x)
    atomicAdd(&cnt[key[e]], 1);
}

__global__ __launch_bounds__(1024) void scan_kernel(const int* __restrict__ cnt,
                                                    int* __restrict__ ptr, int n) {
  __shared__ int s[1024];
  const int t = threadIdx.x;
  const int chunk = (n + 1023) >> 10;
  const int start = t * chunk;
  const int end = min(start + chunk, n);
  int sum = 0;
  for (int i = start; i < end; ++i) sum += cnt[i];
  s[t] = sum;
  __syncthreads();
  for (int off = 1; off < 1024; off <<= 1) {
    int v = 0;
    if (t >= off) v = s[t - off];
    __syncthreads();
    s[t] += v;
    __syncthreads();
  }
  int excl = (t == 0) ? 0 : s[t - 1];
  for (int i = start; i < end; ++i) { ptr[i] = excl; excl += cnt[i]; }
  if (t == 1023) ptr[n] = s[1023];
}

__global__ void fill_kernel(const int* __restrict__ key, const int* __restrict__ val,
                            const int* __restrict__ ptr, int* __restrict__ cur,
                            int* __restrict__ out, int E) {
  for (int e = blockIdx.x * blockDim.x + threadIdx.x; e < E; e += gridDim.x * blockDim.x) {
    const int k = key[e];
    const int p = atomicAdd(&cur[k], 1);
    out[ptr[k] + p] = val[e];
  }
}

__global__ void dis_kernel(const int* __restrict__ ptr, float* __restrict__ dis, int n) {
  const int j = blockIdx.x * blockDim.x + threadIdx.x;
  if (j < n) dis[j] = 1.0f / sqrtf((float)(ptr[j + 1] - ptr[j] + 1));
}

// ------- GCN aggregation over pre-scaled bf16 rows (one wave per node) -------
// hs[r][c] = dis[r] * h[r][c] (bf16).  out[j] = dis[j]*(hs[j] + sum_e hs[r_e]) + bias
template <int C>
__global__ __launch_bounds__(64) void gcn_agg_b(const unsigned short* __restrict__ hs,
    const float* __restrict__ dis, const int* __restrict__ ptr,
    const int* __restrict__ ridx, const float* __restrict__ bias,
    float* __restrict__ out) {
  constexpr int P = C / 64;   // bf16 elems per lane (8 or 4)
  constexpr int U = P / 2;    // dwords per lane (4 or 2)
  const int j = blockIdx.x;
  const int t = threadIdx.x;
  float acc[P];
  {
    const unsigned short* hj = hs + (size_t)j * C + t * P;
    if constexpr (U == 4) {
      const uint4 v = *reinterpret_cast<const uint4*>(hj);
      acc[0] = bflo(v.x); acc[1] = bfhi(v.x);
      acc[2] = bflo(v.y); acc[3] = bfhi(v.y);
      acc[4] = bflo(v.z); acc[5] = bfhi(v.z);
      acc[6] = bflo(v.w); acc[7] = bfhi(v.w);
    } else {
      const uint2 v = *reinterpret_cast<const uint2*>(hj);
      acc[0] = bflo(v.x); acc[1] = bfhi(v.x);
      acc[2] = bflo(v.y); acc[3] = bfhi(v.y);
    }
  }
  const int e0 = ptr[j], e1 = ptr[j + 1];
  for (int e = e0; e < e1; ++e) {
    const int r = ridx[e];
    const unsigned short* hr = hs + (size_t)r * C + t * P;
    if constexpr (U == 4) {
      const uint4 v = *reinterpret_cast<const uint4*>(hr);
      acc[0] += bflo(v.x); acc[1] += bfhi(v.x);
      acc[2] += bflo(v.y); acc[3] += bfhi(v.y);
      acc[4] += bflo(v.z); acc[5] += bfhi(v.z);
      acc[6] += bflo(v.w); acc[7] += bfhi(v.w);
    } else {
      const uint2 v = *reinterpret_cast<const uint2*>(hr);
      acc[0] += bflo(v.x); acc[1] += bfhi(v.x);
      acc[2] += bflo(v.y); acc[3] += bfhi(v.y);
    }
  }
  const float dj = dis[j];
  float* o = out + (size_t)j * C + t * P;
  const float* bs = bias + t * P;
#pragma unroll
  for (int u = 0; u < U; u += 2) {
    float4 w;
    w.x = fmaf(dj, acc[2 * u + 0], bs[2 * u + 0]);
    w.y = fmaf(dj, acc[2 * u + 1], bs[2 * u + 1]);
    w.z = fmaf(dj, acc[2 * u + 2], bs[2 * u + 2]);
    w.w = fmaf(dj, acc[2 * u + 3], bs[2 * u + 3]);
    *reinterpret_cast<float4*>(o + 2 * u) = w;
  }
}

// ---------------- BatchNorm ----------------
template <int C>
__global__ __launch_bounds__(256) void bn_stats(const float* __restrict__ x,
    float* __restrict__ sums, float* __restrict__ sqs, int n) {
  constexpr int P = C / 256;
  float s[P], q[P];
#pragma unroll
  for (int p = 0; p < P; ++p) { s[p] = 0.f; q[p] = 0.f; }
  const int rpb = (n + gridDim.x - 1) / gridDim.x;
  const int r0 = blockIdx.x * rpb;
  const int r1 = min(r0 + rpb, n);
  for (int r = r0; r < r1; ++r) {
#pragma unroll
    for (int p = 0; p < P; ++p) {
      const float v = x[(size_t)r * C + threadIdx.x + (p << 8)];
      s[p] += v;
      q[p] = fmaf(v, v, q[p]);
    }
  }
#pragma unroll
  for (int p = 0; p < P; ++p) {
    atomicAdd(&sums[threadIdx.x + (p << 8)], s[p]);
    atomicAdd(&sqs[threadIdx.x + (p << 8)], q[p]);
  }
}

__global__ void bn_finalize(const float* __restrict__ sums, const float* __restrict__ sqs,
    const float* __restrict__ g, const float* __restrict__ b,
    float* __restrict__ scale, float* __restrict__ shift, int n, int C) {
  const int c = blockIdx.x * blockDim.x + threadIdx.x;
  if (c >= C) return;
  const float m = sums[c] / n;
  const float var = sqs[c] / n - m * m;
  const float sc = g[c] / sqrtf(var + 1e-5f);
  scale[c] = sc;
  shift[c] = b[c] - m * sc;
}

// BN+PReLU; always writes bf16 copy, optionally f32 (in-place allowed)
template <bool WRITE_F32>
__global__ void bn_apply_prelu(const float* __restrict__ in, float* __restrict__ outf,
    unsigned short* __restrict__ outb, const float* __restrict__ scale,
    const float* __restrict__ shift, const float* __restrict__ pa,
    int total4, int cmask) {
  const float a = pa[0];
  for (int i = blockIdx.x * blockDim.x + threadIdx.x; i < total4;
       i += gridDim.x * blockDim.x) {
    float4 v = reinterpret_cast<const float4*>(in)[i];
    const int c0 = (i << 2) & cmask;
    float r[4] = {v.x, v.y, v.z, v.w};
    ushort4 o;
    unsigned short* op = reinterpret_cast<unsigned short*>(&o);
#pragma unroll
    for (int j = 0; j < 4; ++j) {
      float t = fmaf(r[j], scale[c0 + j], shift[c0 + j]);
      t = t > 0.f ? t : a * t;
      r[j] = t;
      op[j] = f2bf(t);
    }
    if (WRITE_F32)
      reinterpret_cast<float4*>(outf)[i] = make_float4(r[0], r[1], r[2], r[3]);
    reinterpret_cast<ushort4*>(outb)[i] = o;
  }
}

// ------- l2norm over 256-dim rows (one wave per row); optional bf16 copy -----
template <bool WRITE_BF16>
__global__ __launch_bounds__(64) void l2norm_k(const float* __restrict__ x,
                                               float* __restrict__ y,
                                               unsigned short* __restrict__ yb) {
  const int r = blockIdx.x, t = threadIdx.x;
  const float4 v = reinterpret_cast<const float4*>(x + (size_t)r * 256)[t];
  float sq = v.x * v.x + v.y * v.y + v.z * v.z + v.w * v.w;
#pragma unroll
  for (int o = 1; o < 64; o <<= 1) sq += __shfl_xor(sq, o);
  const float inv = 1.0f / sqrtf(sq + 1e-12f);
  const float4 w = make_float4(v.x * inv, v.y * inv, v.z * inv, v.w * inv);
  reinterpret_cast<float4*>(y + (size_t)r * 256)[t] = w;
  if (WRITE_BF16) {
    ushort4 o;
    o.x = f2bf(w.x); o.y = f2bf(w.y); o.z = f2bf(w.z); o.w = f2bf(w.w);
    reinterpret_cast<ushort4*>(yb + (size_t)r * 256)[t] = o;
  }
}

// ------ per-row edge sims (bf16 gathers) + dedup + top-3 (one wave/row) ------
#define MAXK 256
__global__ __launch_bounds__(64) void topk_kernel(const unsigned short* __restrict__ snb,
    const int* __restrict__ ptr, const int* __restrict__ ncol, int* __restrict__ nb) {
  const int i = blockIdx.x;
  const int lane = threadIdx.x;
  __shared__ unsigned short sni[256];
  __shared__ float vals[MAXK];
  __shared__ int   cols[MAXK];
  __shared__ float mvals[MAXK];
  __shared__ int   mcols[MAXK];
  reinterpret_cast<uint2*>(sni)[lane] =
      reinterpret_cast<const uint2*>(snb + (size_t)i * 256)[lane];
  __syncthreads();
  const int e0 = ptr[i];
  const int k  = min(ptr[i + 1] - e0, MAXK);
  // ---- per-lane 256-dim bf16 dot for each edge (f32 accumulate) ----
  for (int e = lane; e < k; e += 64) {
    const int j = ncol[e0 + e];
    const uint4* bj = reinterpret_cast<const uint4*>(snb + (size_t)j * 256);
    const uint4* aj = reinterpret_cast<const uint4*>(sni);
    float s = 0.f;
#pragma unroll 8
    for (int q = 0; q < 32; ++q) {
      const uint4 b = bj[q];
      const uint4 a = aj[q];
      s = fmaf(bflo(a.x), bflo(b.x), s);
      s = fmaf(bfhi(a.x), bfhi(b.x), s);
      s = fmaf(bflo(a.y), bflo(b.y), s);
      s = fmaf(bfhi(a.y), bfhi(b.y), s);
      s = fmaf(bflo(a.z), bflo(b.z), s);
      s = fmaf(bfhi(a.z), bfhi(b.z), s);
      s = fmaf(bflo(a.w), bflo(b.w), s);
      s = fmaf(bfhi(a.w), bfhi(b.w), s);
    }
    vals[e] = s;
    cols[e] = j;
  }
  __syncthreads();
  // ---- wave-parallel dedup-merge (JAX scatter-add semantics) ----
  for (int e = lane; e < k; e += 64) {
    const int c = cols[e];
    bool first = true;
    float sum = vals[e];
    for (int q = 0; q < k; ++q) {
      if (q == e) continue;
      if (cols[q] == c) {
        if (q < e) { first = false; break; }
        sum += vals[q];
      }
    }
    mvals[e] = sum;
    mcols[e] = first ? c : -1;
  }
  __syncthreads();
  // ---- top-3 among strictly positive merged values; ties -> smaller col ----
  for (int s = 0; s < 3; ++s) {
    unsigned long long best = 0ull;
    for (int e = lane; e < k; e += 64) {
      const int c = mcols[e];
      if (c < 0) continue;
      const float v = mvals[e];
      if (v <= 0.f) continue;
      const unsigned long long key =
          ((unsigned long long)__float_as_uint(v) << 32) |
          (unsigned long long)(0xFFFFFFFFu - (unsigned)c);
      if (key > best) best = key;
    }
#pragma unroll
    for (int off = 1; off < 64; off <<= 1) {
      const unsigned long long o = __shfl_xor(best, off);
      if (o > best) best = o;
    }
    const int wcol = best ? (int)(0xFFFFFFFFu - (unsigned)(best & 0xFFFFFFFFu)) : -1;
    if (lane == 0) nb[i * 3 + s] = wcol;
    if (wcol >= 0)
      for (int e = lane; e < k; e += 64)
        if (mcols[e] == wcol) mcols[e] = -1;
    __syncthreads();
  }
}

// ---------------- loss terms (no atomics: per-block partials) ----------------
__global__ __launch_bounds__(256) void loss_terms(const float* __restrict__ pn,
    const float* __restrict__ tgt, const int* __restrict__ nb,
    float* __restrict__ part, int n) {
  const int t = threadIdx.x, wave = t >> 6, lane = t & 63;
  const int r = blockIdx.x * 4 + wave;
  float vals[7] = {0.f, 0.f, 0.f, 0.f, 0.f, 0.f, 0.f};
  if (r < n) {
    const float4 a = reinterpret_cast<const float4*>(pn + (size_t)r * 256)[lane];
    const float4 b = reinterpret_cast<const float4*>(tgt + (size_t)r * 256)[lane];
    float d = a.x * b.x + a.y * b.y + a.z * b.z + a.w * b.w;
#pragma unroll
    for (int o = 1; o < 64; o <<= 1) d += __shfl_xor(d, o);
    vals[0] = 2.f - 2.f * d;
    for (int s = 0; s < 3; ++s) {
      const int j = nb[r * 3 + s];
      if (j >= 0) {
        const float4 c = reinterpret_cast<const float4*>(tgt + (size_t)j * 256)[lane];
        float e = a.x * c.x + a.y * c.y + a.z * c.z + a.w * c.w;
#pragma unroll
        for (int o = 1; o < 64; o <<= 1) e += __shfl_xor(e, o);
        vals[1 + s] = 2.f - 2.f * e;
        vals[4 + s] = 1.f;
      }
    }
  }
  __shared__ float red[4][7];
  if (lane == 0)
    for (int q = 0; q < 7; ++q) red[wave][q] = vals[q];
  __syncthreads();
  if (t < 7)
    part[(size_t)blockIdx.x * 8 + t] =
        red[0][t] + red[1][t] + red[2][t] + red[3][t];
}

__global__ __launch_bounds__(64) void finalize_loss(const float* __restrict__ part,
    float* __restrict__ out, int nblocks, int n) {
  const int lane = threadIdx.x;
  float comp[7] = {0.f, 0.f, 0.f, 0.f, 0.f, 0.f, 0.f};
  for (int b = lane; b < nblocks; b += 64) {
#pragma unroll
    for (int q = 0; q < 7; ++q) comp[q] += part[(size_t)b * 8 + q];
  }
#pragma unroll
  for (int q = 0; q < 7; ++q) {
#pragma unroll
    for (int o = 1; o < 64; o <<= 1) comp[q] += __shfl_xor(comp[q], o);
  }
  if (lane == 0) {
    float loss = comp[0] / n;
    for (int s = 0; s < 3; ++s) loss += comp[1 + s] / fmaxf(comp[4 + s], 1.f);
    out[0] = loss * 0.25f;
  }
}

// ---------------- host ----------------
extern "C" void kernel_launch(void* const* d_in, const int* in_sizes, int n_in,
                              void* d_out, int out_size, void* d_ws, size_t ws_size,
                              hipStream_t stream) {
  const float* x   = (const float*)d_in[0];
  const int*   eidx = (const int*)d_in[1];
  const int*   nidx = (const int*)d_in[2];
  const float* W1  = (const float*)d_in[3];
  const float* b1  = (const float*)d_in[4];
  const float* g1  = (const float*)d_in[5];
  const float* bb1 = (const float*)d_in[6];
  const float* pr1 = (const float*)d_in[7];
  const float* W2  = (const float*)d_in[8];
  const float* b2  = (const float*)d_in[9];
  const float* g2  = (const float*)d_in[10];
  const float* bb2 = (const float*)d_in[11];
  const float* pr2 = (const float*)d_in[12];
  const float* pW1 = (const float*)d_in[13];
  const float* pb1 = (const float*)d_in[14];
  const float* pg  = (const float*)d_in[15];
  const float* pbb = (const float*)d_in[16];
  const float* ppr = (const float*)d_in[17];
  const float* pW2 = (const float*)d_in[18];
  const float* pb2 = (const float*)d_in[19];

  const int* row  = eidx;
  const int* col  = eidx + NE;
  const int* nrow = nidx;
  const int* ncol = nidx + NE;

  float* student = (float*)d_out;              // NN x 256
  float* loss    = student + (size_t)NN * 256; // scalar

  char* ws = (char*)d_ws;
  size_t off = 0;
  auto take = [&](size_t bytes) -> void* {
    void* p = ws + off;
    off += (bytes + 255) & ~(size_t)255;
    return p;
  };
  const int LOSS_NB = NN / 4;
  float* h1    = (float*)take((size_t)NN * 512 * 4);
  float* x2    = (float*)take((size_t)NN * 512 * 4);
  float* h2    = (float*)take((size_t)NN * 256 * 4);
  float* sn    = (float*)take((size_t)NN * 256 * 4);
  float* dis   = (float*)take((size_t)NN * 4);
  int*   cnt   = (int*)take((size_t)NN * 4);
  int*   ptrg  = (int*)take((size_t)(NN + 1) * 4);
  int*   ridx  = (int*)take((size_t)NE * 4);
  int*   ptrn  = (int*)take((size_t)(NN + 1) * 4);
  int*   ncidx = (int*)take((size_t)NE * 4);
  int*   nb    = (int*)take((size_t)NN * 3 * 4);
  float* bnsum = (float*)take(1024 * 4);
  float* bnsq  = bnsum + 512;
  float* scale = (float*)take(512 * 4);
  float* shift = (float*)take(512 * 4);
  float* part  = (float*)take((size_t)LOSS_NB * 8 * 4);
  // bf16 buffers
  unsigned short* xb   = (unsigned short*)take((size_t)NN * 512 * 2);
  unsigned short* x2b  = (unsigned short*)take((size_t)NN * 512 * 2);
  unsigned short* stb  = (unsigned short*)take((size_t)NN * 256 * 2);
  unsigned short* phb  = (unsigned short*)take((size_t)NN * 512 * 2);
  unsigned short* h1b  = (unsigned short*)take((size_t)NN * 512 * 2);
  unsigned short* h2b  = (unsigned short*)take((size_t)NN * 256 * 2);
  unsigned short* snb  = (unsigned short*)take((size_t)NN * 256 * 2);
  unsigned short* W1t  = (unsigned short*)take((size_t)512 * 512 * 2);
  unsigned short* W2t  = (unsigned short*)take((size_t)512 * 256 * 2);
  unsigned short* pW1t = (unsigned short*)take((size_t)256 * 512 * 2);
  unsigned short* pW2t = (unsigned short*)take((size_t)512 * 256 * 2);

  float* ph   = h1;  // predictor hidden reuses h1
  float* pred = h2;  // predictor output reuses h2
  float* pn   = x2;  // l2norm(pred) reuses x2

  const int MB = (NN + GBM - 1) / GBM;  // 79

  // ---- input/weight converts ----
  f32_to_bf16_k<<<1024, 256, 0, stream>>>(x, xb, NN * 512 / 4);
  conv_transpose_bf16<<<512, 256, 0, stream>>>(W1, W1t, 512, 512);
  conv_transpose_bf16<<<256, 256, 0, stream>>>(W2, W2t, 512, 256);
  conv_transpose_bf16<<<256, 256, 0, stream>>>(pW1, pW1t, 256, 512);
  conv_transpose_bf16<<<256, 256, 0, stream>>>(pW2, pW2t, 512, 256);

  // CSR for GCN (grouped by destination col)
  hipMemsetAsync(cnt, 0, NN * 4, stream);
  count_kernel<<<512, 256, 0, stream>>>(col, cnt, NE);
  scan_kernel<<<1, 1024, 0, stream>>>(cnt, ptrg, NN);
  hipMemsetAsync(cnt, 0, NN * 4, stream);
  fill_kernel<<<512, 256, 0, stream>>>(col, row, ptrg, cnt, ridx, NE);
  dis_kernel<<<(NN + 255) / 256, 256, 0, stream>>>(ptrg, dis, NN);

  // CSR for neighbor graph (grouped by nrow)
  hipMemsetAsync(cnt, 0, NN * 4, stream);
  count_kernel<<<512, 256, 0, stream>>>(nrow, cnt, NE);
  scan_kernel<<<1, 1024, 0, stream>>>(cnt, ptrn, NN);
  hipMemsetAsync(cnt, 0, NN * 4, stream);
  fill_kernel<<<512, 256, 0, stream>>>(nrow, ncol, ptrn, cnt, ncidx, NE);

  // ---- encoder layer 1 ----
  { dim3 g(512 / GBN, MB);
    gemm_bf16<true><<<g, 256, 0, stream>>>(xb, W1t, nullptr, dis, nullptr, h1b,
                                           NN, 512, 512); }
  gcn_agg_b<512><<<NN, 64, 0, stream>>>(h1b, dis, ptrg, ridx, b1, x2);
  hipMemsetAsync(bnsum, 0, 1024 * 4, stream);
  bn_stats<512><<<128, 256, 0, stream>>>(x2, bnsum, bnsq, NN);
  bn_finalize<<<2, 256, 0, stream>>>(bnsum, bnsq, g1, bb1, scale, shift, NN, 512);
  bn_apply_prelu<false><<<2048, 256, 0, stream>>>(x2, nullptr, x2b, scale, shift,
                                                  pr1, NN * 512 / 4, 511);

  // ---- encoder layer 2 ----
  { dim3 g(256 / GBN, MB);
    gemm_bf16<true><<<g, 256, 0, stream>>>(x2b, W2t, nullptr, dis, nullptr, h2b,
                                           NN, 256, 512); }
  gcn_agg_b<256><<<NN, 64, 0, stream>>>(h2b, dis, ptrg, ridx, b2, student);
  hipMemsetAsync(bnsum, 0, 1024 * 4, stream);
  bn_stats<256><<<128, 256, 0, stream>>>(student, bnsum, bnsq, NN);
  bn_finalize<<<2, 256, 0, stream>>>(bnsum, bnsq, g2, bb2, scale, shift, NN, 256);
  bn_apply_prelu<true><<<2048, 256, 0, stream>>>(student, student, stb, scale, shift,
                                                 pr2, NN * 256 / 4, 255);

  // ---- sn = l2norm(student) (f32 + bf16); teacher == student => tgt = sn ----
  l2norm_k<true><<<NN, 64, 0, stream>>>(student, sn, snb);

  // ---- predictor ----
  { dim3 g(512 / GBN, MB);
    gemm_bf16<false><<<g, 256, 0, stream>>>(stb, pW1t, pb1, nullptr, ph, nullptr,
                                            NN, 512, 256); }
  hipMemsetAsync(bnsum, 0, 1024 * 4, stream);
  bn_stats<512><<<128, 256, 0, stream>>>(ph, bnsum, bnsq, NN);
  bn_finalize<<<2, 256, 0, stream>>>(bnsum, bnsq, pg, pbb, scale, shift, NN, 512);
  bn_apply_prelu<false><<<2048, 256, 0, stream>>>(ph, nullptr, phb, scale, shift,
                                                  ppr, NN * 512 / 4, 511);
  { dim3 g(256 / GBN, MB);
    gemm_bf16<false><<<g, 256, 0, stream>>>(phb, pW2t, pb2, nullptr, pred, nullptr,
                                            NN, 256, 512); }
  l2norm_k<false><<<NN, 64, 0, stream>>>(pred, pn, nullptr);

  // ---- per-row top-3 neighbors (bf16 gathers) ----
  topk_kernel<<<NN, 64, 0, stream>>>(snb, ptrn, ncidx, nb);

  // ---- loss ----
  loss_terms<<<LOSS_NB, 256, 0, stream>>>(pn, sn, nb, part, NN);
  finalize_loss<<<1, 64, 0, stream>>>(part, loss, LOSS_NB, NN);
}

// Round 7
// 396.321 us; speedup vs baseline: 2.5977x; 1.1224x over previous
//
#include <hip/hip_runtime.h>
#include <math.h>

#define NN 10000
#define NE 320000

typedef __attribute__((ext_vector_type(8))) short bf16x8;
typedef __attribute__((ext_vector_type(4))) float f32x4;

__device__ inline unsigned short f2bf(float f) {
  unsigned u = __float_as_uint(f);
  unsigned r = (u + 0x7fffu + ((u >> 16) & 1u)) >> 16;
  return (unsigned short)r;
}
__device__ inline float bflo(unsigned u) { return __uint_as_float(u << 16); }
__device__ inline float bfhi(unsigned u) { return __uint_as_float(u & 0xffff0000u); }

// ------------- prep: x->bf16 (vec4) + 4 weight transposes, one kernel -------
#define X4 (NN * 512 / 4)            // 1,280,000 float4 ids
#define W1N (512 * 512)
#define W2N (512 * 256)
#define P1N (256 * 512)
#define P2N (512 * 256)
#define S1 X4
#define S2 (S1 + W1N)
#define S3 (S2 + W2N)
#define S4 (S3 + P1N)
#define PREP_TOT (S4 + P2N)

__global__ void prep_kernel(const float* __restrict__ x, unsigned short* __restrict__ xb,
    const float* __restrict__ W1, unsigned short* __restrict__ W1t,
    const float* __restrict__ W2, unsigned short* __restrict__ W2t,
    const float* __restrict__ pW1, unsigned short* __restrict__ pW1t,
    const float* __restrict__ pW2, unsigned short* __restrict__ pW2t) {
  for (int i = blockIdx.x * blockDim.x + threadIdx.x; i < PREP_TOT;
       i += gridDim.x * blockDim.x) {
    if (i < X4) {
      const float4 v = reinterpret_cast<const float4*>(x)[i];
      ushort4 o;
      o.x = f2bf(v.x); o.y = f2bf(v.y); o.z = f2bf(v.z); o.w = f2bf(v.w);
      reinterpret_cast<ushort4*>(xb)[i] = o;
    } else if (i < S2) {
      const int j = i - S1, n = j >> 9, k = j & 511;   // N=512,K=512
      W1t[j] = f2bf(W1[(size_t)k * 512 + n]);
    } else if (i < S3) {
      const int j = i - S2, n = j >> 9, k = j & 511;   // N=256,K=512
      W2t[j] = f2bf(W2[(size_t)k * 256 + n]);
    } else if (i < S4) {
      const int j = i - S3, n = j >> 8, k = j & 255;   // N=512,K=256
      pW1t[j] = f2bf(pW1[(size_t)k * 512 + n]);
    } else {
      const int j = i - S4, n = j >> 9, k = j & 511;   // N=256,K=512
      pW2t[j] = f2bf(pW2[(size_t)k * 256 + n]);
    }
  }
}

// ---------------- MFMA GEMM: A (MxK bf16 rm) x Bt (NxK bf16) -> C (MxN) -----
#define GBM 128
#define GBN 64
#define GBK 32
#define SAS 40

template <bool BF16OUT>
__global__ __launch_bounds__(256) void gemm_bf16(
    const unsigned short* __restrict__ A, const unsigned short* __restrict__ Bt,
    const float* __restrict__ bias, const float* __restrict__ rowscale,
    float* __restrict__ Cf, unsigned short* __restrict__ Cb,
    int M, int N, int K) {
  __shared__ unsigned short As[GBM * SAS];
  __shared__ unsigned short Bs[GBN * SAS];
  const int bm = blockIdx.y * GBM;
  const int bn = blockIdx.x * GBN;
  const int tid = threadIdx.x;
  const int wave = tid >> 6, lane = tid & 63;
  const int wm = wave & 1, wn = wave >> 1;
  f32x4 acc[4][2] = {};

  const int srow = tid >> 2;
  const int scol = (tid & 3) << 3;

  for (int k0 = 0; k0 < K; k0 += GBK) {
#pragma unroll
    for (int r = 0; r < 2; ++r) {
      const int row = srow + (r << 6);
      const int gr = bm + row;
      uint4 v = make_uint4(0u, 0u, 0u, 0u);
      if (gr < M) v = *reinterpret_cast<const uint4*>(&A[(size_t)gr * K + k0 + scol]);
      *reinterpret_cast<uint4*>(&As[row * SAS + scol]) = v;
    }
    {
      const uint4 v = *reinterpret_cast<const uint4*>(
          &Bt[(size_t)(bn + srow) * K + k0 + scol]);
      *reinterpret_cast<uint4*>(&Bs[srow * SAS + scol]) = v;
    }
    __syncthreads();
    const int kofs = (lane >> 4) << 3;
    const int rl = lane & 15;
    bf16x8 af[4], bfr[2];
#pragma unroll
    for (int m = 0; m < 4; ++m)
      af[m] = *reinterpret_cast<const bf16x8*>(
          &As[((wm << 6) + (m << 4) + rl) * SAS + kofs]);
#pragma unroll
    for (int n = 0; n < 2; ++n)
      bfr[n] = *reinterpret_cast<const bf16x8*>(
          &Bs[((wn << 5) + (n << 4) + rl) * SAS + kofs]);
#pragma unroll
    for (int m = 0; m < 4; ++m)
#pragma unroll
      for (int n = 0; n < 2; ++n)
        acc[m][n] = __builtin_amdgcn_mfma_f32_16x16x32_bf16(af[m], bfr[n], acc[m][n], 0, 0, 0);
    __syncthreads();
  }
  const int crow0 = (lane >> 4) << 2;
  const int ccol = lane & 15;
#pragma unroll
  for (int n = 0; n < 2; ++n) {
    const int col = bn + (wn << 5) + (n << 4) + ccol;
    const float bv = (!BF16OUT && bias) ? bias[col] : 0.f;
#pragma unroll
    for (int m = 0; m < 4; ++m) {
#pragma unroll
      for (int r = 0; r < 4; ++r) {
        const int rowg = bm + (wm << 6) + (m << 4) + crow0 + r;
        if (rowg < M) {
          if (BF16OUT)
            Cb[(size_t)rowg * N + col] = f2bf(acc[m][n][r] * rowscale[rowg]);
          else
            Cf[(size_t)rowg * N + col] = acc[m][n][r] + bv;
        }
      }
    }
  }
}

// ---------------- CSR build (both graphs fused) ----------------
__global__ void count_both(const int* __restrict__ col, const int* __restrict__ nrow,
                           int* __restrict__ cnt1, int* __restrict__ cnt2) {
  for (int e = blockIdx.x * blockDim.x + threadIdx.x; e < NE; e += gridDim.x * blockDim.x) {
    atomicAdd(&cnt1[col[e]], 1);
    atomicAdd(&cnt2[nrow[e]], 1);
  }
}

// block 0: cnt1 -> ptrg (+ dis); block 1: cnt2 -> ptrn
__global__ __launch_bounds__(1024) void scan2_kernel(
    const int* __restrict__ cnt1, int* __restrict__ ptrg, float* __restrict__ dis,
    const int* __restrict__ cnt2, int* __restrict__ ptrn, int n) {
  const int* cnt = (blockIdx.x == 0) ? cnt1 : cnt2;
  int* ptr = (blockIdx.x == 0) ? ptrg : ptrn;
  __shared__ int s[1024];
  const int t = threadIdx.x;
  const int chunk = (n + 1023) >> 10;
  const int start = t * chunk;
  const int end = min(start + chunk, n);
  int sum = 0;
  for (int i = start; i < end; ++i) sum += cnt[i];
  s[t] = sum;
  __syncthreads();
  for (int off = 1; off < 1024; off <<= 1) {
    int v = 0;
    if (t >= off) v = s[t - off];
    __syncthreads();
    s[t] += v;
    __syncthreads();
  }
  int excl = (t == 0) ? 0 : s[t - 1];
  for (int i = start; i < end; ++i) { ptr[i] = excl; excl += cnt[i]; }
  if (t == 1023) ptr[n] = s[1023];
  if (blockIdx.x == 0)
    for (int i = start; i < end; ++i)
      dis[i] = 1.0f / sqrtf((float)(cnt[i] + 1));
}

__global__ void fill_both(const int* __restrict__ col, const int* __restrict__ row,
                          const int* __restrict__ ptrg, int* __restrict__ cur1,
                          int* __restrict__ ridx,
                          const int* __restrict__ nrow, const int* __restrict__ ncol,
                          const int* __restrict__ ptrn, int* __restrict__ cur2,
                          int* __restrict__ ncidx) {
  for (int e = blockIdx.x * blockDim.x + threadIdx.x; e < NE; e += gridDim.x * blockDim.x) {
    const int k1 = col[e];
    const int p1 = atomicAdd(&cur1[k1], 1);
    ridx[ptrg[k1] + p1] = row[e];
    const int k2 = nrow[e];
    const int p2 = atomicAdd(&cur2[k2], 1);
    ncidx[ptrn[k2] + p2] = ncol[e];
  }
}

// ------- GCN aggregation over pre-scaled bf16 rows (one wave per node) -------
template <int C>
__global__ __launch_bounds__(64) void gcn_agg_b(const unsigned short* __restrict__ hs,
    const float* __restrict__ dis, const int* __restrict__ ptr,
    const int* __restrict__ ridx, const float* __restrict__ bias,
    float* __restrict__ out) {
  constexpr int P = C / 64;
  constexpr int U = P / 2;
  const int j = blockIdx.x;
  const int t = threadIdx.x;
  float acc[P];
  {
    const unsigned short* hj = hs + (size_t)j * C + t * P;
    if constexpr (U == 4) {
      const uint4 v = *reinterpret_cast<const uint4*>(hj);
      acc[0] = bflo(v.x); acc[1] = bfhi(v.x);
      acc[2] = bflo(v.y); acc[3] = bfhi(v.y);
      acc[4] = bflo(v.z); acc[5] = bfhi(v.z);
      acc[6] = bflo(v.w); acc[7] = bfhi(v.w);
    } else {
      const uint2 v = *reinterpret_cast<const uint2*>(hj);
      acc[0] = bflo(v.x); acc[1] = bfhi(v.x);
      acc[2] = bflo(v.y); acc[3] = bfhi(v.y);
    }
  }
  const int e0 = ptr[j], e1 = ptr[j + 1];
  for (int e = e0; e < e1; ++e) {
    const int r = ridx[e];
    const unsigned short* hr = hs + (size_t)r * C + t * P;
    if constexpr (U == 4) {
      const uint4 v = *reinterpret_cast<const uint4*>(hr);
      acc[0] += bflo(v.x); acc[1] += bfhi(v.x);
      acc[2] += bflo(v.y); acc[3] += bfhi(v.y);
      acc[4] += bflo(v.z); acc[5] += bfhi(v.z);
      acc[6] += bflo(v.w); acc[7] += bfhi(v.w);
    } else {
      const uint2 v = *reinterpret_cast<const uint2*>(hr);
      acc[0] += bflo(v.x); acc[1] += bfhi(v.x);
      acc[2] += bflo(v.y); acc[3] += bfhi(v.y);
    }
  }
  const float dj = dis[j];
  float* o = out + (size_t)j * C + t * P;
  const float* bs = bias + t * P;
#pragma unroll
  for (int u = 0; u < U; u += 2) {
    float4 w;
    w.x = fmaf(dj, acc[2 * u + 0], bs[2 * u + 0]);
    w.y = fmaf(dj, acc[2 * u + 1], bs[2 * u + 1]);
    w.z = fmaf(dj, acc[2 * u + 2], bs[2 * u + 2]);
    w.w = fmaf(dj, acc[2 * u + 3], bs[2 * u + 3]);
    *reinterpret_cast<float4*>(o + 2 * u) = w;
  }
}

// ---------------- BatchNorm stats (atomic partials; no finalize kernel) ------
template <int C>
__global__ __launch_bounds__(256) void bn_stats(const float* __restrict__ x,
    float* __restrict__ sums, float* __restrict__ sqs, int n) {
  constexpr int P = C / 256;
  float s[P], q[P];
#pragma unroll
  for (int p = 0; p < P; ++p) { s[p] = 0.f; q[p] = 0.f; }
  const int rpb = (n + gridDim.x - 1) / gridDim.x;
  const int r0 = blockIdx.x * rpb;
  const int r1 = min(r0 + rpb, n);
  for (int r = r0; r < r1; ++r) {
#pragma unroll
    for (int p = 0; p < P; ++p) {
      const float v = x[(size_t)r * C + threadIdx.x + (p << 8)];
      s[p] += v;
      q[p] = fmaf(v, v, q[p]);
    }
  }
#pragma unroll
  for (int p = 0; p < P; ++p) {
    atomicAdd(&sums[threadIdx.x + (p << 8)], s[p]);
    atomicAdd(&sqs[threadIdx.x + (p << 8)], q[p]);
  }
}

__device__ inline void bn_coeff(const float* sums, const float* sqs,
                                const float* g, const float* b, int c,
                                float inv_n, float& sc, float& sh) {
  const float m = sums[c] * inv_n;
  const float var = sqs[c] * inv_n - m * m;
  sc = g[c] / sqrtf(var + 1e-5f);
  sh = b[c] - m * sc;
}

// BN(inline-finalize)+PReLU -> bf16 out only
__global__ void bn_apply_prelu(const float* __restrict__ in,
    unsigned short* __restrict__ outb, const float* __restrict__ sums,
    const float* __restrict__ sqs, const float* __restrict__ g,
    const float* __restrict__ b, const float* __restrict__ pa,
    float inv_n, int total4, int cmask) {
  const float a = pa[0];
  for (int i = blockIdx.x * blockDim.x + threadIdx.x; i < total4;
       i += gridDim.x * blockDim.x) {
    float4 v = reinterpret_cast<const float4*>(in)[i];
    const int c0 = (i << 2) & cmask;
    float r[4] = {v.x, v.y, v.z, v.w};
    ushort4 o;
    unsigned short* op = reinterpret_cast<unsigned short*>(&o);
#pragma unroll
    for (int j = 0; j < 4; ++j) {
      float sc, sh;
      bn_coeff(sums, sqs, g, b, c0 + j, inv_n, sc, sh);
      float t = fmaf(r[j], sc, sh);
      t = t > 0.f ? t : a * t;
      op[j] = f2bf(t);
    }
    reinterpret_cast<ushort4*>(outb)[i] = o;
  }
}

// --- fused layer-2 tail: BN(inline)+PReLU -> student(f32) + stb + snb -------
__global__ __launch_bounds__(64) void bn_l2_student(float* __restrict__ student,
    unsigned short* __restrict__ stb, unsigned short* __restrict__ snb,
    const float* __restrict__ sums, const float* __restrict__ sqs,
    const float* __restrict__ g, const float* __restrict__ b,
    const float* __restrict__ pa, float inv_n) {
  const int r = blockIdx.x, t = threadIdx.x;
  const float a = pa[0];
  const float4 v = reinterpret_cast<const float4*>(student + (size_t)r * 256)[t];
  float w[4] = {v.x, v.y, v.z, v.w};
  const int c0 = t << 2;
#pragma unroll
  for (int j = 0; j < 4; ++j) {
    float sc, sh;
    bn_coeff(sums, sqs, g, b, c0 + j, inv_n, sc, sh);
    float u = fmaf(w[j], sc, sh);
    w[j] = u > 0.f ? u : a * u;
  }
  reinterpret_cast<float4*>(student + (size_t)r * 256)[t] =
      make_float4(w[0], w[1], w[2], w[3]);
  ushort4 ob;
  ob.x = f2bf(w[0]); ob.y = f2bf(w[1]); ob.z = f2bf(w[2]); ob.w = f2bf(w[3]);
  reinterpret_cast<ushort4*>(stb + (size_t)r * 256)[t] = ob;
  float sq = w[0] * w[0] + w[1] * w[1] + w[2] * w[2] + w[3] * w[3];
#pragma unroll
  for (int o = 1; o < 64; o <<= 1) sq += __shfl_xor(sq, o);
  const float inv = 1.0f / sqrtf(sq + 1e-12f);
  ushort4 on;
  on.x = f2bf(w[0] * inv); on.y = f2bf(w[1] * inv);
  on.z = f2bf(w[2] * inv); on.w = f2bf(w[3] * inv);
  reinterpret_cast<ushort4*>(snb + (size_t)r * 256)[t] = on;
}

// ------ per-row edge sims (bf16 gathers) + dedup + top-3 (one wave/row) ------
#define MAXK 256
__global__ __launch_bounds__(64) void topk_kernel(const unsigned short* __restrict__ snb,
    const int* __restrict__ ptr, const int* __restrict__ ncol, int* __restrict__ nb) {
  const int i = blockIdx.x;
  const int lane = threadIdx.x;
  __shared__ unsigned short sni[256];
  __shared__ float vals[MAXK];
  __shared__ int   cols[MAXK];
  __shared__ float mvals[MAXK];
  __shared__ int   mcols[MAXK];
  reinterpret_cast<uint2*>(sni)[lane] =
      reinterpret_cast<const uint2*>(snb + (size_t)i * 256)[lane];
  __syncthreads();
  const int e0 = ptr[i];
  const int k  = min(ptr[i + 1] - e0, MAXK);
  for (int e = lane; e < k; e += 64) {
    const int j = ncol[e0 + e];
    const uint4* bj = reinterpret_cast<const uint4*>(snb + (size_t)j * 256);
    const uint4* aj = reinterpret_cast<const uint4*>(sni);
    float s = 0.f;
#pragma unroll 8
    for (int q = 0; q < 32; ++q) {
      const uint4 b = bj[q];
      const uint4 a = aj[q];
      s = fmaf(bflo(a.x), bflo(b.x), s);
      s = fmaf(bfhi(a.x), bfhi(b.x), s);
      s = fmaf(bflo(a.y), bflo(b.y), s);
      s = fmaf(bfhi(a.y), bfhi(b.y), s);
      s = fmaf(bflo(a.z), bflo(b.z), s);
      s = fmaf(bfhi(a.z), bfhi(b.z), s);
      s = fmaf(bflo(a.w), bflo(b.w), s);
      s = fmaf(bfhi(a.w), bfhi(b.w), s);
    }
    vals[e] = s;
    cols[e] = j;
  }
  __syncthreads();
  for (int e = lane; e < k; e += 64) {
    const int c = cols[e];
    bool first = true;
    float sum = vals[e];
    for (int q = 0; q < k; ++q) {
      if (q == e) continue;
      if (cols[q] == c) {
        if (q < e) { first = false; break; }
        sum += vals[q];
      }
    }
    mvals[e] = sum;
    mcols[e] = first ? c : -1;
  }
  __syncthreads();
  for (int s = 0; s < 3; ++s) {
    unsigned long long best = 0ull;
    for (int e = lane; e < k; e += 64) {
      const int c = mcols[e];
      if (c < 0) continue;
      const float v = mvals[e];
      if (v <= 0.f) continue;
      const unsigned long long key =
          ((unsigned long long)__float_as_uint(v) << 32) |
          (unsigned long long)(0xFFFFFFFFu - (unsigned)c);
      if (key > best) best = key;
    }
#pragma unroll
    for (int off = 1; off < 64; off <<= 1) {
      const unsigned long long o = __shfl_xor(best, off);
      if (o > best) best = o;
    }
    const int wcol = best ? (int)(0xFFFFFFFFu - (unsigned)(best & 0xFFFFFFFFu)) : -1;
    if (lane == 0) nb[i * 3 + s] = wcol;
    if (wcol >= 0)
      for (int e = lane; e < k; e += 64)
        if (mcols[e] == wcol) mcols[e] = -1;
    __syncthreads();
  }
}

// ------ loss terms: inline pn=l2norm(pred), bf16 snb gathers, partials ------
__global__ __launch_bounds__(256) void loss_terms(const float* __restrict__ pred,
    const unsigned short* __restrict__ snb, const int* __restrict__ nb,
    float* __restrict__ part, int n) {
  const int t = threadIdx.x, wave = t >> 6, lane = t & 63;
  const int r = blockIdx.x * 4 + wave;
  float vals[7] = {0.f, 0.f, 0.f, 0.f, 0.f, 0.f, 0.f};
  if (r < n) {
    const float4 p = reinterpret_cast<const float4*>(pred + (size_t)r * 256)[lane];
    float sq = p.x * p.x + p.y * p.y + p.z * p.z + p.w * p.w;
#pragma unroll
    for (int o = 1; o < 64; o <<= 1) sq += __shfl_xor(sq, o);
    const float inv = 1.0f / sqrtf(sq + 1e-12f);
    const float a0 = p.x * inv, a1 = p.y * inv, a2 = p.z * inv, a3 = p.w * inv;
    {
      const uint2 bv = reinterpret_cast<const uint2*>(snb + (size_t)r * 256)[lane];
      float d = a0 * bflo(bv.x) + a1 * bfhi(bv.x) + a2 * bflo(bv.y) + a3 * bfhi(bv.y);
#pragma unroll
      for (int o = 1; o < 64; o <<= 1) d += __shfl_xor(d, o);
      vals[0] = 2.f - 2.f * d;
    }
    for (int s = 0; s < 3; ++s) {
      const int j = nb[r * 3 + s];
      if (j >= 0) {
        const uint2 cv = reinterpret_cast<const uint2*>(snb + (size_t)j * 256)[lane];
        float e = a0 * bflo(cv.x) + a1 * bfhi(cv.x) + a2 * bflo(cv.y) + a3 * bfhi(cv.y);
#pragma unroll
        for (int o = 1; o < 64; o <<= 1) e += __shfl_xor(e, o);
        vals[1 + s] = 2.f - 2.f * e;
        vals[4 + s] = 1.f;
      }
    }
  }
  __shared__ float red[4][7];
  if (lane == 0)
    for (int q = 0; q < 7; ++q) red[wave][q] = vals[q];
  __syncthreads();
  if (t < 7)
    part[(size_t)blockIdx.x * 8 + t] =
        red[0][t] + red[1][t] + red[2][t] + red[3][t];
}

__global__ __launch_bounds__(64) void finalize_loss(const float* __restrict__ part,
    float* __restrict__ out, int nblocks, int n) {
  const int lane = threadIdx.x;
  float comp[7] = {0.f, 0.f, 0.f, 0.f, 0.f, 0.f, 0.f};
  for (int b = lane; b < nblocks; b += 64) {
#pragma unroll
    for (int q = 0; q < 7; ++q) comp[q] += part[(size_t)b * 8 + q];
  }
#pragma unroll
  for (int q = 0; q < 7; ++q) {
#pragma unroll
    for (int o = 1; o < 64; o <<= 1) comp[q] += __shfl_xor(comp[q], o);
  }
  if (lane == 0) {
    float loss = comp[0] / n;
    for (int s = 0; s < 3; ++s) loss += comp[1 + s] / fmaxf(comp[4 + s], 1.f);
    out[0] = loss * 0.25f;
  }
}

// ---------------- host ----------------
extern "C" void kernel_launch(void* const* d_in, const int* in_sizes, int n_in,
                              void* d_out, int out_size, void* d_ws, size_t ws_size,
                              hipStream_t stream) {
  const float* x   = (const float*)d_in[0];
  const int*   eidx = (const int*)d_in[1];
  const int*   nidx = (const int*)d_in[2];
  const float* W1  = (const float*)d_in[3];
  const float* b1  = (const float*)d_in[4];
  const float* g1  = (const float*)d_in[5];
  const float* bb1 = (const float*)d_in[6];
  const float* pr1 = (const float*)d_in[7];
  const float* W2  = (const float*)d_in[8];
  const float* b2  = (const float*)d_in[9];
  const float* g2  = (const float*)d_in[10];
  const float* bb2 = (const float*)d_in[11];
  const float* pr2 = (const float*)d_in[12];
  const float* pW1 = (const float*)d_in[13];
  const float* pb1 = (const float*)d_in[14];
  const float* pg  = (const float*)d_in[15];
  const float* pbb = (const float*)d_in[16];
  const float* ppr = (const float*)d_in[17];
  const float* pW2 = (const float*)d_in[18];
  const float* pb2 = (const float*)d_in[19];

  const int* row  = eidx;
  const int* col  = eidx + NE;
  const int* nrow = nidx;
  const int* ncol = nidx + NE;

  float* student = (float*)d_out;              // NN x 256
  float* loss    = student + (size_t)NN * 256; // scalar

  char* ws = (char*)d_ws;
  size_t off = 0;
  auto take = [&](size_t bytes) -> void* {
    void* p = ws + off;
    off += (bytes + 255) & ~(size_t)255;
    return p;
  };
  const int LOSS_NB = NN / 4;
  // ---- zero-region (one memset): cnt1,cur1,cnt2,cur2,bns1,bns2,bns3 ----
  const size_t zstart = off;
  int*   cnt1 = (int*)take((size_t)NN * 4);
  int*   cur1 = (int*)take((size_t)NN * 4);
  int*   cnt2 = (int*)take((size_t)NN * 4);
  int*   cur2 = (int*)take((size_t)NN * 4);
  float* bns1 = (float*)take(1024 * 4);  // sums512 | sqs512
  float* bns2 = (float*)take(512 * 4);   // sums256 | sqs256
  float* bns3 = (float*)take(1024 * 4);  // sums512 | sqs512
  const size_t zsize = off - zstart;
  // ---- rest ----
  float* h1    = (float*)take((size_t)NN * 512 * 4);
  float* x2    = (float*)take((size_t)NN * 512 * 4);
  float* h2    = (float*)take((size_t)NN * 256 * 4);
  float* dis   = (float*)take((size_t)NN * 4);
  int*   ptrg  = (int*)take((size_t)(NN + 1) * 4);
  int*   ridx  = (int*)take((size_t)NE * 4);
  int*   ptrn  = (int*)take((size_t)(NN + 1) * 4);
  int*   ncidx = (int*)take((size_t)NE * 4);
  int*   nb    = (int*)take((size_t)NN * 3 * 4);
  float* part  = (float*)take((size_t)LOSS_NB * 8 * 4);
  unsigned short* xb   = (unsigned short*)take((size_t)NN * 512 * 2);
  unsigned short* x2b  = (unsigned short*)take((size_t)NN * 512 * 2);
  unsigned short* stb  = (unsigned short*)take((size_t)NN * 256 * 2);
  unsigned short* phb  = (unsigned short*)take((size_t)NN * 512 * 2);
  unsigned short* h1b  = (unsigned short*)take((size_t)NN * 512 * 2);
  unsigned short* h2b  = (unsigned short*)take((size_t)NN * 256 * 2);
  unsigned short* snb  = (unsigned short*)take((size_t)NN * 256 * 2);
  unsigned short* W1t  = (unsigned short*)take((size_t)W1N * 2);
  unsigned short* W2t  = (unsigned short*)take((size_t)W2N * 2);
  unsigned short* pW1t = (unsigned short*)take((size_t)P1N * 2);
  unsigned short* pW2t = (unsigned short*)take((size_t)P2N * 2);

  float* ph   = h1;  // predictor hidden reuses h1
  float* pred = h2;  // predictor output reuses h2

  const int MB = (NN + GBM - 1) / GBM;  // 79
  const float inv_n = 1.0f / (float)NN;

  // 1) converts (one kernel)  2) zero-region (one memset)
  prep_kernel<<<2048, 256, 0, stream>>>(x, xb, W1, W1t, W2, W2t, pW1, pW1t, pW2, pW2t);
  hipMemsetAsync((char*)d_ws + zstart, 0, zsize, stream);

  // 3-5) both CSRs
  count_both<<<512, 256, 0, stream>>>(col, nrow, cnt1, cnt2);
  scan2_kernel<<<2, 1024, 0, stream>>>(cnt1, ptrg, dis, cnt2, ptrn, NN);
  fill_both<<<512, 256, 0, stream>>>(col, row, ptrg, cur1, ridx,
                                     nrow, ncol, ptrn, cur2, ncidx);

  // ---- encoder layer 1 ----
  { dim3 g(512 / GBN, MB);
    gemm_bf16<true><<<g, 256, 0, stream>>>(xb, W1t, nullptr, dis, nullptr, h1b,
                                           NN, 512, 512); }
  gcn_agg_b<512><<<NN, 64, 0, stream>>>(h1b, dis, ptrg, ridx, b1, x2);
  bn_stats<512><<<128, 256, 0, stream>>>(x2, bns1, bns1 + 512, NN);
  bn_apply_prelu<<<2048, 256, 0, stream>>>(x2, x2b, bns1, bns1 + 512, g1, bb1, pr1,
                                           inv_n, NN * 512 / 4, 511);

  // ---- encoder layer 2 ----
  { dim3 g(256 / GBN, MB);
    gemm_bf16<true><<<g, 256, 0, stream>>>(x2b, W2t, nullptr, dis, nullptr, h2b,
                                           NN, 256, 512); }
  gcn_agg_b<256><<<NN, 64, 0, stream>>>(h2b, dis, ptrg, ridx, b2, student);
  bn_stats<256><<<128, 256, 0, stream>>>(student, bns2, bns2 + 256, NN);
  bn_l2_student<<<NN, 64, 0, stream>>>(student, stb, snb, bns2, bns2 + 256,
                                       g2, bb2, pr2, inv_n);

  // ---- top-3 neighbors (needs only snb) ----
  topk_kernel<<<NN, 64, 0, stream>>>(snb, ptrn, ncidx, nb);

  // ---- predictor ----
  { dim3 g(512 / GBN, MB);
    gemm_bf16<false><<<g, 256, 0, stream>>>(stb, pW1t, pb1, nullptr, ph, nullptr,
                                            NN, 512, 256); }
  bn_stats<512><<<128, 256, 0, stream>>>(ph, bns3, bns3 + 512, NN);
  bn_apply_prelu<<<2048, 256, 0, stream>>>(ph, phb, bns3, bns3 + 512, pg, pbb, ppr,
                                           inv_n, NN * 512 / 4, 511);
  { dim3 g(256 / GBN, MB);
    gemm_bf16<false><<<g, 256, 0, stream>>>(phb, pW2t, pb2, nullptr, pred, nullptr,
                                            NN, 256, 512); }

  // ---- loss (pn computed inline) ----
  loss_terms<<<LOSS_NB, 256, 0, stream>>>(pred, snb, nb, part, NN);
  finalize_loss<<<1, 64, 0, stream>>>(part, loss, LOSS_NB, NN);
}

// Round 8
// 386.202 us; speedup vs baseline: 2.6657x; 1.0262x over previous
//
#include <hip/hip_runtime.h>
#include <math.h>

#define NN 10000
#define NE 320000

typedef __attribute__((ext_vector_type(8))) short bf16x8;
typedef __attribute__((ext_vector_type(4))) float f32x4;

__device__ inline unsigned short f2bf(float f) {
  unsigned u = __float_as_uint(f);
  unsigned r = (u + 0x7fffu + ((u >> 16) & 1u)) >> 16;
  return (unsigned short)r;
}
__device__ inline float bflo(unsigned u) { return __uint_as_float(u << 16); }
__device__ inline float bfhi(unsigned u) { return __uint_as_float(u & 0xffff0000u); }

// ------------- prep: x->bf16 (vec4) + 4 weight transposes, one kernel -------
#define X4 (NN * 512 / 4)
#define W1N (512 * 512)
#define W2N (512 * 256)
#define P1N (256 * 512)
#define P2N (512 * 256)
#define S1 X4
#define S2 (S1 + W1N)
#define S3 (S2 + W2N)
#define S4 (S3 + P1N)
#define PREP_TOT (S4 + P2N)

__global__ void prep_kernel(const float* __restrict__ x, unsigned short* __restrict__ xb,
    const float* __restrict__ W1, unsigned short* __restrict__ W1t,
    const float* __restrict__ W2, unsigned short* __restrict__ W2t,
    const float* __restrict__ pW1, unsigned short* __restrict__ pW1t,
    const float* __restrict__ pW2, unsigned short* __restrict__ pW2t) {
  for (int i = blockIdx.x * blockDim.x + threadIdx.x; i < PREP_TOT;
       i += gridDim.x * blockDim.x) {
    if (i < X4) {
      const float4 v = reinterpret_cast<const float4*>(x)[i];
      ushort4 o;
      o.x = f2bf(v.x); o.y = f2bf(v.y); o.z = f2bf(v.z); o.w = f2bf(v.w);
      reinterpret_cast<ushort4*>(xb)[i] = o;
    } else if (i < S2) {
      const int j = i - S1, n = j >> 9, k = j & 511;
      W1t[j] = f2bf(W1[(size_t)k * 512 + n]);
    } else if (i < S3) {
      const int j = i - S2, n = j >> 9, k = j & 511;
      W2t[j] = f2bf(W2[(size_t)k * 256 + n]);
    } else if (i < S4) {
      const int j = i - S3, n = j >> 8, k = j & 255;
      pW1t[j] = f2bf(pW1[(size_t)k * 512 + n]);
    } else {
      const int j = i - S4, n = j >> 9, k = j & 511;
      pW2t[j] = f2bf(pW2[(size_t)k * 256 + n]);
    }
  }
}

// ---------------- MFMA GEMM: A (MxK bf16 rm) x Bt (NxK bf16) -> C (MxN) -----
#define GBM 128
#define GBN 64
#define GBK 32
#define SAS 40

template <bool BF16OUT>
__global__ __launch_bounds__(256) void gemm_bf16(
    const unsigned short* __restrict__ A, const unsigned short* __restrict__ Bt,
    const float* __restrict__ bias, const float* __restrict__ rowscale,
    float* __restrict__ Cf, unsigned short* __restrict__ Cb,
    int M, int N, int K) {
  __shared__ unsigned short As[GBM * SAS];
  __shared__ unsigned short Bs[GBN * SAS];
  const int bm = blockIdx.y * GBM;
  const int bn = blockIdx.x * GBN;
  const int tid = threadIdx.x;
  const int wave = tid >> 6, lane = tid & 63;
  const int wm = wave & 1, wn = wave >> 1;
  f32x4 acc[4][2] = {};

  const int srow = tid >> 2;
  const int scol = (tid & 3) << 3;

  for (int k0 = 0; k0 < K; k0 += GBK) {
#pragma unroll
    for (int r = 0; r < 2; ++r) {
      const int row = srow + (r << 6);
      const int gr = bm + row;
      uint4 v = make_uint4(0u, 0u, 0u, 0u);
      if (gr < M) v = *reinterpret_cast<const uint4*>(&A[(size_t)gr * K + k0 + scol]);
      *reinterpret_cast<uint4*>(&As[row * SAS + scol]) = v;
    }
    {
      const uint4 v = *reinterpret_cast<const uint4*>(
          &Bt[(size_t)(bn + srow) * K + k0 + scol]);
      *reinterpret_cast<uint4*>(&Bs[srow * SAS + scol]) = v;
    }
    __syncthreads();
    const int kofs = (lane >> 4) << 3;
    const int rl = lane & 15;
    bf16x8 af[4], bfr[2];
#pragma unroll
    for (int m = 0; m < 4; ++m)
      af[m] = *reinterpret_cast<const bf16x8*>(
          &As[((wm << 6) + (m << 4) + rl) * SAS + kofs]);
#pragma unroll
    for (int n = 0; n < 2; ++n)
      bfr[n] = *reinterpret_cast<const bf16x8*>(
          &Bs[((wn << 5) + (n << 4) + rl) * SAS + kofs]);
#pragma unroll
    for (int m = 0; m < 4; ++m)
#pragma unroll
      for (int n = 0; n < 2; ++n)
        acc[m][n] = __builtin_amdgcn_mfma_f32_16x16x32_bf16(af[m], bfr[n], acc[m][n], 0, 0, 0);
    __syncthreads();
  }
  const int crow0 = (lane >> 4) << 2;
  const int ccol = lane & 15;
#pragma unroll
  for (int n = 0; n < 2; ++n) {
    const int col = bn + (wn << 5) + (n << 4) + ccol;
    const float bv = (!BF16OUT && bias) ? bias[col] : 0.f;
#pragma unroll
    for (int m = 0; m < 4; ++m) {
#pragma unroll
      for (int r = 0; r < 4; ++r) {
        const int rowg = bm + (wm << 6) + (m << 4) + crow0 + r;
        if (rowg < M) {
          if (BF16OUT)
            Cb[(size_t)rowg * N + col] = f2bf(acc[m][n][r] * rowscale[rowg]);
          else
            Cf[(size_t)rowg * N + col] = acc[m][n][r] + bv;
        }
      }
    }
  }
}

// ---------------- CSR build (both graphs fused) ----------------
__global__ void count_both(const int* __restrict__ col, const int* __restrict__ nrow,
                           int* __restrict__ cnt1, int* __restrict__ cnt2) {
  for (int e = blockIdx.x * blockDim.x + threadIdx.x; e < NE; e += gridDim.x * blockDim.x) {
    atomicAdd(&cnt1[col[e]], 1);
    atomicAdd(&cnt2[nrow[e]], 1);
  }
}

__global__ __launch_bounds__(1024) void scan2_kernel(
    const int* __restrict__ cnt1, int* __restrict__ ptrg, float* __restrict__ dis,
    const int* __restrict__ cnt2, int* __restrict__ ptrn, int n) {
  const int* cnt = (blockIdx.x == 0) ? cnt1 : cnt2;
  int* ptr = (blockIdx.x == 0) ? ptrg : ptrn;
  __shared__ int s[1024];
  const int t = threadIdx.x;
  const int chunk = (n + 1023) >> 10;
  const int start = t * chunk;
  const int end = min(start + chunk, n);
  int sum = 0;
  for (int i = start; i < end; ++i) sum += cnt[i];
  s[t] = sum;
  __syncthreads();
  for (int off = 1; off < 1024; off <<= 1) {
    int v = 0;
    if (t >= off) v = s[t - off];
    __syncthreads();
    s[t] += v;
    __syncthreads();
  }
  int excl = (t == 0) ? 0 : s[t - 1];
  for (int i = start; i < end; ++i) { ptr[i] = excl; excl += cnt[i]; }
  if (t == 1023) ptr[n] = s[1023];
  if (blockIdx.x == 0)
    for (int i = start; i < end; ++i)
      dis[i] = 1.0f / sqrtf((float)(cnt[i] + 1));
}

__global__ void fill_both(const int* __restrict__ col, const int* __restrict__ row,
                          const int* __restrict__ ptrg, int* __restrict__ cur1,
                          int* __restrict__ ridx,
                          const int* __restrict__ nrow, const int* __restrict__ ncol,
                          const int* __restrict__ ptrn, int* __restrict__ cur2,
                          int* __restrict__ ncidx) {
  for (int e = blockIdx.x * blockDim.x + threadIdx.x; e < NE; e += gridDim.x * blockDim.x) {
    const int k1 = col[e];
    const int p1 = atomicAdd(&cur1[k1], 1);
    ridx[ptrg[k1] + p1] = row[e];
    const int k2 = nrow[e];
    const int p2 = atomicAdd(&cur2[k2], 1);
    ncidx[ptrn[k2] + p2] = ncol[e];
  }
}

// ------- GCN aggregation, 2 nodes/block (one wave each), 2-edge unroll -------
template <int C>
__global__ __launch_bounds__(128) void gcn_agg_b(const unsigned short* __restrict__ hs,
    const float* __restrict__ dis, const int* __restrict__ ptr,
    const int* __restrict__ ridx, const float* __restrict__ bias,
    float* __restrict__ out) {
  constexpr int P = C / 64;
  constexpr int U = P / 2;
  const int j = blockIdx.x * 2 + (threadIdx.x >> 6);
  const int t = threadIdx.x & 63;
  float acc[P];
  {
    const unsigned short* hj = hs + (size_t)j * C + t * P;
    if constexpr (U == 4) {
      const uint4 v = *reinterpret_cast<const uint4*>(hj);
      acc[0] = bflo(v.x); acc[1] = bfhi(v.x);
      acc[2] = bflo(v.y); acc[3] = bfhi(v.y);
      acc[4] = bflo(v.z); acc[5] = bfhi(v.z);
      acc[6] = bflo(v.w); acc[7] = bfhi(v.w);
    } else {
      const uint2 v = *reinterpret_cast<const uint2*>(hj);
      acc[0] = bflo(v.x); acc[1] = bfhi(v.x);
      acc[2] = bflo(v.y); acc[3] = bfhi(v.y);
    }
  }
  const int e0 = ptr[j], e1 = ptr[j + 1];
  int e = e0;
  for (; e + 1 < e1; e += 2) {         // 2 independent gathers in flight
    const int r0 = ridx[e], r1 = ridx[e + 1];
    const unsigned short* h0 = hs + (size_t)r0 * C + t * P;
    const unsigned short* h1 = hs + (size_t)r1 * C + t * P;
    if constexpr (U == 4) {
      const uint4 a = *reinterpret_cast<const uint4*>(h0);
      const uint4 b = *reinterpret_cast<const uint4*>(h1);
      acc[0] += bflo(a.x) + bflo(b.x); acc[1] += bfhi(a.x) + bfhi(b.x);
      acc[2] += bflo(a.y) + bflo(b.y); acc[3] += bfhi(a.y) + bfhi(b.y);
      acc[4] += bflo(a.z) + bflo(b.z); acc[5] += bfhi(a.z) + bfhi(b.z);
      acc[6] += bflo(a.w) + bflo(b.w); acc[7] += bfhi(a.w) + bfhi(b.w);
    } else {
      const uint2 a = *reinterpret_cast<const uint2*>(h0);
      const uint2 b = *reinterpret_cast<const uint2*>(h1);
      acc[0] += bflo(a.x) + bflo(b.x); acc[1] += bfhi(a.x) + bfhi(b.x);
      acc[2] += bflo(a.y) + bflo(b.y); acc[3] += bfhi(a.y) + bfhi(b.y);
    }
  }
  if (e < e1) {
    const int r = ridx[e];
    const unsigned short* hr = hs + (size_t)r * C + t * P;
    if constexpr (U == 4) {
      const uint4 v = *reinterpret_cast<const uint4*>(hr);
      acc[0] += bflo(v.x); acc[1] += bfhi(v.x);
      acc[2] += bflo(v.y); acc[3] += bfhi(v.y);
      acc[4] += bflo(v.z); acc[5] += bfhi(v.z);
      acc[6] += bflo(v.w); acc[7] += bfhi(v.w);
    } else {
      const uint2 v = *reinterpret_cast<const uint2*>(hr);
      acc[0] += bflo(v.x); acc[1] += bfhi(v.x);
      acc[2] += bflo(v.y); acc[3] += bfhi(v.y);
    }
  }
  const float dj = dis[j];
  float* o = out + (size_t)j * C + t * P;
  const float* bs = bias + t * P;
#pragma unroll
  for (int u = 0; u < U; u += 2) {
    float4 w;
    w.x = fmaf(dj, acc[2 * u + 0], bs[2 * u + 0]);
    w.y = fmaf(dj, acc[2 * u + 1], bs[2 * u + 1]);
    w.z = fmaf(dj, acc[2 * u + 2], bs[2 * u + 2]);
    w.w = fmaf(dj, acc[2 * u + 3], bs[2 * u + 3]);
    *reinterpret_cast<float4*>(o + 2 * u) = w;
  }
}

// ---------------- BatchNorm stats (atomic partials; no finalize kernel) ------
template <int C>
__global__ __launch_bounds__(256) void bn_stats(const float* __restrict__ x,
    float* __restrict__ sums, float* __restrict__ sqs, int n) {
  constexpr int P = C / 256;
  float s[P], q[P];
#pragma unroll
  for (int p = 0; p < P; ++p) { s[p] = 0.f; q[p] = 0.f; }
  const int rpb = (n + gridDim.x - 1) / gridDim.x;
  const int r0 = blockIdx.x * rpb;
  const int r1 = min(r0 + rpb, n);
  for (int r = r0; r < r1; ++r) {
#pragma unroll
    for (int p = 0; p < P; ++p) {
      const float v = x[(size_t)r * C + threadIdx.x + (p << 8)];
      s[p] += v;
      q[p] = fmaf(v, v, q[p]);
    }
  }
#pragma unroll
  for (int p = 0; p < P; ++p) {
    atomicAdd(&sums[threadIdx.x + (p << 8)], s[p]);
    atomicAdd(&sqs[threadIdx.x + (p << 8)], q[p]);
  }
}

__device__ inline void bn_coeff(const float* sums, const float* sqs,
                                const float* g, const float* b, int c,
                                float inv_n, float& sc, float& sh) {
  const float m = sums[c] * inv_n;
  const float var = sqs[c] * inv_n - m * m;
  sc = g[c] / sqrtf(var + 1e-5f);
  sh = b[c] - m * sc;
}

// BN(inline-finalize)+PReLU -> bf16 out only
__global__ void bn_apply_prelu(const float* __restrict__ in,
    unsigned short* __restrict__ outb, const float* __restrict__ sums,
    const float* __restrict__ sqs, const float* __restrict__ g,
    const float* __restrict__ b, const float* __restrict__ pa,
    float inv_n, int total4, int cmask) {
  const float a = pa[0];
  for (int i = blockIdx.x * blockDim.x + threadIdx.x; i < total4;
       i += gridDim.x * blockDim.x) {
    float4 v = reinterpret_cast<const float4*>(in)[i];
    const int c0 = (i << 2) & cmask;
    float r[4] = {v.x, v.y, v.z, v.w};
    ushort4 o;
    unsigned short* op = reinterpret_cast<unsigned short*>(&o);
#pragma unroll
    for (int j = 0; j < 4; ++j) {
      float sc, sh;
      bn_coeff(sums, sqs, g, b, c0 + j, inv_n, sc, sh);
      float t = fmaf(r[j], sc, sh);
      t = t > 0.f ? t : a * t;
      op[j] = f2bf(t);
    }
    reinterpret_cast<ushort4*>(outb)[i] = o;
  }
}

// --- fused layer-2 tail: BN(inline)+PReLU -> student(f32)+stb+snb, 2 rows/blk
__global__ __launch_bounds__(128) void bn_l2_student(float* __restrict__ student,
    unsigned short* __restrict__ stb, unsigned short* __restrict__ snb,
    const float* __restrict__ sums, const float* __restrict__ sqs,
    const float* __restrict__ g, const float* __restrict__ b,
    const float* __restrict__ pa, float inv_n) {
  const int r = blockIdx.x * 2 + (threadIdx.x >> 6);
  const int t = threadIdx.x & 63;
  const float a = pa[0];
  const float4 v = reinterpret_cast<const float4*>(student + (size_t)r * 256)[t];
  float w[4] = {v.x, v.y, v.z, v.w};
  const int c0 = t << 2;
#pragma unroll
  for (int j = 0; j < 4; ++j) {
    float sc, sh;
    bn_coeff(sums, sqs, g, b, c0 + j, inv_n, sc, sh);
    float u = fmaf(w[j], sc, sh);
    w[j] = u > 0.f ? u : a * u;
  }
  reinterpret_cast<float4*>(student + (size_t)r * 256)[t] =
      make_float4(w[0], w[1], w[2], w[3]);
  ushort4 ob;
  ob.x = f2bf(w[0]); ob.y = f2bf(w[1]); ob.z = f2bf(w[2]); ob.w = f2bf(w[3]);
  reinterpret_cast<ushort4*>(stb + (size_t)r * 256)[t] = ob;
  float sq = w[0] * w[0] + w[1] * w[1] + w[2] * w[2] + w[3] * w[3];
#pragma unroll
  for (int o = 1; o < 64; o <<= 1) sq += __shfl_xor(sq, o);
  const float inv = 1.0f / sqrtf(sq + 1e-12f);
  ushort4 on;
  on.x = f2bf(w[0] * inv); on.y = f2bf(w[1] * inv);
  on.z = f2bf(w[2] * inv); on.w = f2bf(w[3] * inv);
  reinterpret_cast<ushort4*>(snb + (size_t)r * 256)[t] = on;
}

// ------ per-row edge sims + dedup + top-3; 2 rows/block (one wave each) ------
#define MAXK 256
__global__ __launch_bounds__(128) void topk_kernel(const unsigned short* __restrict__ snb,
    const int* __restrict__ ptr, const int* __restrict__ ncol, int* __restrict__ nb) {
  const int wv = threadIdx.x >> 6, lane = threadIdx.x & 63;
  const int i = blockIdx.x * 2 + wv;
  __shared__ unsigned short sni[2][256];
  __shared__ float vals[2][MAXK];
  __shared__ int   cols[2][MAXK];
  __shared__ float mvals[2][MAXK];
  __shared__ int   mcols[2][MAXK];
  reinterpret_cast<uint2*>(sni[wv])[lane] =
      reinterpret_cast<const uint2*>(snb + (size_t)i * 256)[lane];
  __syncthreads();
  const int e0 = ptr[i];
  const int k  = min(ptr[i + 1] - e0, MAXK);
  for (int e = lane; e < k; e += 64) {
    const int j = ncol[e0 + e];
    const uint4* bj = reinterpret_cast<const uint4*>(snb + (size_t)j * 256);
    const uint4* aj = reinterpret_cast<const uint4*>(sni[wv]);
    float s = 0.f;
#pragma unroll 8
    for (int q = 0; q < 32; ++q) {
      const uint4 b = bj[q];
      const uint4 a = aj[q];
      s = fmaf(bflo(a.x), bflo(b.x), s);
      s = fmaf(bfhi(a.x), bfhi(b.x), s);
      s = fmaf(bflo(a.y), bflo(b.y), s);
      s = fmaf(bfhi(a.y), bfhi(b.y), s);
      s = fmaf(bflo(a.z), bflo(b.z), s);
      s = fmaf(bfhi(a.z), bfhi(b.z), s);
      s = fmaf(bflo(a.w), bflo(b.w), s);
      s = fmaf(bfhi(a.w), bfhi(b.w), s);
    }
    vals[wv][e] = s;
    cols[wv][e] = j;
  }
  __syncthreads();
  for (int e = lane; e < k; e += 64) {
    const int c = cols[wv][e];
    bool first = true;
    float sum = vals[wv][e];
    for (int q = 0; q < k; ++q) {
      if (q == e) continue;
      if (cols[wv][q] == c) {
        if (q < e) { first = false; break; }
        sum += vals[wv][q];
      }
    }
    mvals[wv][e] = sum;
    mcols[wv][e] = first ? c : -1;
  }
  __syncthreads();
  for (int s = 0; s < 3; ++s) {
    unsigned long long best = 0ull;
    for (int e = lane; e < k; e += 64) {
      const int c = mcols[wv][e];
      if (c < 0) continue;
      const float v = mvals[wv][e];
      if (v <= 0.f) continue;
      const unsigned long long key =
          ((unsigned long long)__float_as_uint(v) << 32) |
          (unsigned long long)(0xFFFFFFFFu - (unsigned)c);
      if (key > best) best = key;
    }
#pragma unroll
    for (int off = 1; off < 64; off <<= 1) {
      const unsigned long long o = __shfl_xor(best, off);
      if (o > best) best = o;
    }
    const int wcol = best ? (int)(0xFFFFFFFFu - (unsigned)(best & 0xFFFFFFFFu)) : -1;
    if (lane == 0) nb[i * 3 + s] = wcol;
    if (wcol >= 0)
      for (int e = lane; e < k; e += 64)
        if (mcols[wv][e] == wcol) mcols[wv][e] = -1;
    __syncthreads();
  }
}

// ------ loss terms: inline pn=l2norm(pred), bf16 snb gathers, partials ------
__global__ __launch_bounds__(256) void loss_terms(const float* __restrict__ pred,
    const unsigned short* __restrict__ snb, const int* __restrict__ nb,
    float* __restrict__ part, int n) {
  const int t = threadIdx.x, wave = t >> 6, lane = t & 63;
  const int r = blockIdx.x * 4 + wave;
  float vals[7] = {0.f, 0.f, 0.f, 0.f, 0.f, 0.f, 0.f};
  if (r < n) {
    const float4 p = reinterpret_cast<const float4*>(pred + (size_t)r * 256)[lane];
    float sq = p.x * p.x + p.y * p.y + p.z * p.z + p.w * p.w;
#pragma unroll
    for (int o = 1; o < 64; o <<= 1) sq += __shfl_xor(sq, o);
    const float inv = 1.0f / sqrtf(sq + 1e-12f);
    const float a0 = p.x * inv, a1 = p.y * inv, a2 = p.z * inv, a3 = p.w * inv;
    {
      const uint2 bv = reinterpret_cast<const uint2*>(snb + (size_t)r * 256)[lane];
      float d = a0 * bflo(bv.x) + a1 * bfhi(bv.x) + a2 * bflo(bv.y) + a3 * bfhi(bv.y);
#pragma unroll
      for (int o = 1; o < 64; o <<= 1) d += __shfl_xor(d, o);
      vals[0] = 2.f - 2.f * d;
    }
    for (int s = 0; s < 3; ++s) {
      const int j = nb[r * 3 + s];
      if (j >= 0) {
        const uint2 cv = reinterpret_cast<const uint2*>(snb + (size_t)j * 256)[lane];
        float e = a0 * bflo(cv.x) + a1 * bfhi(cv.x) + a2 * bflo(cv.y) + a3 * bfhi(cv.y);
#pragma unroll
        for (int o = 1; o < 64; o <<= 1) e += __shfl_xor(e, o);
        vals[1 + s] = 2.f - 2.f * e;
        vals[4 + s] = 1.f;
      }
    }
  }
  __shared__ float red[4][7];
  if (lane == 0)
    for (int q = 0; q < 7; ++q) red[wave][q] = vals[q];
  __syncthreads();
  if (t < 7)
    part[(size_t)blockIdx.x * 8 + t] =
        red[0][t] + red[1][t] + red[2][t] + red[3][t];
}

__global__ __launch_bounds__(64) void finalize_loss(const float* __restrict__ part,
    float* __restrict__ out, int nblocks, int n) {
  const int lane = threadIdx.x;
  float comp[7] = {0.f, 0.f, 0.f, 0.f, 0.f, 0.f, 0.f};
  for (int b = lane; b < nblocks; b += 64) {
#pragma unroll
    for (int q = 0; q < 7; ++q) comp[q] += part[(size_t)b * 8 + q];
  }
#pragma unroll
  for (int q = 0; q < 7; ++q) {
#pragma unroll
    for (int o = 1; o < 64; o <<= 1) comp[q] += __shfl_xor(comp[q], o);
  }
  if (lane == 0) {
    float loss = comp[0] / n;
    for (int s = 0; s < 3; ++s) loss += comp[1 + s] / fmaxf(comp[4 + s], 1.f);
    out[0] = loss * 0.25f;
  }
}

// ---------------- host ----------------
extern "C" void kernel_launch(void* const* d_in, const int* in_sizes, int n_in,
                              void* d_out, int out_size, void* d_ws, size_t ws_size,
                              hipStream_t stream) {
  const float* x   = (const float*)d_in[0];
  const int*   eidx = (const int*)d_in[1];
  const int*   nidx = (const int*)d_in[2];
  const float* W1  = (const float*)d_in[3];
  const float* b1  = (const float*)d_in[4];
  const float* g1  = (const float*)d_in[5];
  const float* bb1 = (const float*)d_in[6];
  const float* pr1 = (const float*)d_in[7];
  const float* W2  = (const float*)d_in[8];
  const float* b2  = (const float*)d_in[9];
  const float* g2  = (const float*)d_in[10];
  const float* bb2 = (const float*)d_in[11];
  const float* pr2 = (const float*)d_in[12];
  const float* pW1 = (const float*)d_in[13];
  const float* pb1 = (const float*)d_in[14];
  const float* pg  = (const float*)d_in[15];
  const float* pbb = (const float*)d_in[16];
  const float* ppr = (const float*)d_in[17];
  const float* pW2 = (const float*)d_in[18];
  const float* pb2 = (const float*)d_in[19];

  const int* row  = eidx;
  const int* col  = eidx + NE;
  const int* nrow = nidx;
  const int* ncol = nidx + NE;

  float* student = (float*)d_out;              // NN x 256
  float* loss    = student + (size_t)NN * 256; // scalar

  char* ws = (char*)d_ws;
  size_t off = 0;
  auto take = [&](size_t bytes) -> void* {
    void* p = ws + off;
    off += (bytes + 255) & ~(size_t)255;
    return p;
  };
  const int LOSS_NB = NN / 4;
  // ---- zero-region (one memset) ----
  const size_t zstart = off;
  int*   cnt1 = (int*)take((size_t)NN * 4);
  int*   cur1 = (int*)take((size_t)NN * 4);
  int*   cnt2 = (int*)take((size_t)NN * 4);
  int*   cur2 = (int*)take((size_t)NN * 4);
  float* bns1 = (float*)take(1024 * 4);
  float* bns2 = (float*)take(512 * 4);
  float* bns3 = (float*)take(1024 * 4);
  const size_t zsize = off - zstart;
  // ---- rest ----
  float* h1    = (float*)take((size_t)NN * 512 * 4);
  float* x2    = (float*)take((size_t)NN * 512 * 4);
  float* h2    = (float*)take((size_t)NN * 256 * 4);
  float* dis   = (float*)take((size_t)NN * 4);
  int*   ptrg  = (int*)take((size_t)(NN + 1) * 4);
  int*   ridx  = (int*)take((size_t)NE * 4);
  int*   ptrn  = (int*)take((size_t)(NN + 1) * 4);
  int*   ncidx = (int*)take((size_t)NE * 4);
  int*   nb    = (int*)take((size_t)NN * 3 * 4);
  float* part  = (float*)take((size_t)LOSS_NB * 8 * 4);
  unsigned short* xb   = (unsigned short*)take((size_t)NN * 512 * 2);
  unsigned short* x2b  = (unsigned short*)take((size_t)NN * 512 * 2);
  unsigned short* stb  = (unsigned short*)take((size_t)NN * 256 * 2);
  unsigned short* phb  = (unsigned short*)take((size_t)NN * 512 * 2);
  unsigned short* h1b  = (unsigned short*)take((size_t)NN * 512 * 2);
  unsigned short* h2b  = (unsigned short*)take((size_t)NN * 256 * 2);
  unsigned short* snb  = (unsigned short*)take((size_t)NN * 256 * 2);
  unsigned short* W1t  = (unsigned short*)take((size_t)W1N * 2);
  unsigned short* W2t  = (unsigned short*)take((size_t)W2N * 2);
  unsigned short* pW1t = (unsigned short*)take((size_t)P1N * 2);
  unsigned short* pW2t = (unsigned short*)take((size_t)P2N * 2);

  float* ph   = h1;  // predictor hidden reuses h1
  float* pred = h2;  // predictor output reuses h2

  const int MB = (NN + GBM - 1) / GBM;  // 79
  const float inv_n = 1.0f / (float)NN;

  prep_kernel<<<2048, 256, 0, stream>>>(x, xb, W1, W1t, W2, W2t, pW1, pW1t, pW2, pW2t);
  hipMemsetAsync((char*)d_ws + zstart, 0, zsize, stream);

  count_both<<<512, 256, 0, stream>>>(col, nrow, cnt1, cnt2);
  scan2_kernel<<<2, 1024, 0, stream>>>(cnt1, ptrg, dis, cnt2, ptrn, NN);
  fill_both<<<512, 256, 0, stream>>>(col, row, ptrg, cur1, ridx,
                                     nrow, ncol, ptrn, cur2, ncidx);

  // ---- encoder layer 1 ----
  { dim3 g(512 / GBN, MB);
    gemm_bf16<true><<<g, 256, 0, stream>>>(xb, W1t, nullptr, dis, nullptr, h1b,
                                           NN, 512, 512); }
  gcn_agg_b<512><<<NN / 2, 128, 0, stream>>>(h1b, dis, ptrg, ridx, b1, x2);
  bn_stats<512><<<256, 256, 0, stream>>>(x2, bns1, bns1 + 512, NN);
  bn_apply_prelu<<<2048, 256, 0, stream>>>(x2, x2b, bns1, bns1 + 512, g1, bb1, pr1,
                                           inv_n, NN * 512 / 4, 511);

  // ---- encoder layer 2 ----
  { dim3 g(256 / GBN, MB);
    gemm_bf16<true><<<g, 256, 0, stream>>>(x2b, W2t, nullptr, dis, nullptr, h2b,
                                           NN, 256, 512); }
  gcn_agg_b<256><<<NN / 2, 128, 0, stream>>>(h2b, dis, ptrg, ridx, b2, student);
  bn_stats<256><<<256, 256, 0, stream>>>(student, bns2, bns2 + 256, NN);
  bn_l2_student<<<NN / 2, 128, 0, stream>>>(student, stb, snb, bns2, bns2 + 256,
                                            g2, bb2, pr2, inv_n);

  // ---- top-3 neighbors ----
  topk_kernel<<<NN / 2, 128, 0, stream>>>(snb, ptrn, ncidx, nb);

  // ---- predictor ----
  { dim3 g(512 / GBN, MB);
    gemm_bf16<false><<<g, 256, 0, stream>>>(stb, pW1t, pb1, nullptr, ph, nullptr,
                                            NN, 512, 256); }
  bn_stats<512><<<256, 256, 0, stream>>>(ph, bns3, bns3 + 512, NN);
  bn_apply_prelu<<<2048, 256, 0, stream>>>(ph, phb, bns3, bns3 + 512, pg, pbb, ppr,
                                           inv_n, NN * 512 / 4, 511);
  { dim3 g(256 / GBN, MB);
    gemm_bf16<false><<<g, 256, 0, stream>>>(phb, pW2t, pb2, nullptr, pred, nullptr,
                                            NN, 256, 512); }

  // ---- loss ----
  loss_terms<<<LOSS_NB, 256, 0, stream>>>(pred, snb, nb, part, NN);
  finalize_loss<<<1, 64, 0, stream>>>(part, loss, LOSS_NB, NN);
}

// Round 10
// 377.316 us; speedup vs baseline: 2.7285x; 1.0236x over previous
//
#include <hip/hip_runtime.h>
#include <math.h>

#define NN 10000
#define NE 320000

typedef __attribute__((ext_vector_type(8))) short bf16x8;
typedef __attribute__((ext_vector_type(4))) float f32x4;

__device__ inline unsigned short f2bf(float f) {
  unsigned u = __float_as_uint(f);
  unsigned r = (u + 0x7fffu + ((u >> 16) & 1u)) >> 16;
  return (unsigned short)r;
}
__device__ inline float bflo(unsigned u) { return __uint_as_float(u << 16); }
__device__ inline float bfhi(unsigned u) { return __uint_as_float(u & 0xffff0000u); }

// ------------- prep: x->bf16 (vec4) + 4 weight transposes, one kernel -------
#define X4 (NN * 512 / 4)
#define W1N (512 * 512)
#define W2N (512 * 256)
#define P1N (256 * 512)
#define P2N (512 * 256)
#define S1 X4
#define S2 (S1 + W1N)
#define S3 (S2 + W2N)
#define S4 (S3 + P1N)
#define PREP_TOT (S4 + P2N)

__global__ void prep_kernel(const float* __restrict__ x, unsigned short* __restrict__ xb,
    const float* __restrict__ W1, unsigned short* __restrict__ W1t,
    const float* __restrict__ W2, unsigned short* __restrict__ W2t,
    const float* __restrict__ pW1, unsigned short* __restrict__ pW1t,
    const float* __restrict__ pW2, unsigned short* __restrict__ pW2t) {
  for (int i = blockIdx.x * blockDim.x + threadIdx.x; i < PREP_TOT;
       i += gridDim.x * blockDim.x) {
    if (i < X4) {
      const float4 v = reinterpret_cast<const float4*>(x)[i];
      ushort4 o;
      o.x = f2bf(v.x); o.y = f2bf(v.y); o.z = f2bf(v.z); o.w = f2bf(v.w);
      reinterpret_cast<ushort4*>(xb)[i] = o;
    } else if (i < S2) {
      const int j = i - S1, n = j >> 9, k = j & 511;
      W1t[j] = f2bf(W1[(size_t)k * 512 + n]);
    } else if (i < S3) {
      const int j = i - S2, n = j >> 9, k = j & 511;
      W2t[j] = f2bf(W2[(size_t)k * 256 + n]);
    } else if (i < S4) {
      const int j = i - S3, n = j >> 8, k = j & 255;
      pW1t[j] = f2bf(pW1[(size_t)k * 512 + n]);
    } else {
      const int j = i - S4, n = j >> 9, k = j & 511;
      pW2t[j] = f2bf(pW2[(size_t)k * 256 + n]);
    }
  }
}

// ---------------- MFMA GEMM: A (MxK bf16 rm) x Bt (NxK bf16) -> C (MxN) -----
#define GBM 128
#define GBN 64
#define GBK 32
#define SAS 40

template <bool BF16OUT>
__global__ __launch_bounds__(256) void gemm_bf16(
    const unsigned short* __restrict__ A, const unsigned short* __restrict__ Bt,
    const float* __restrict__ bias, const float* __restrict__ rowscale,
    float* __restrict__ Cf, unsigned short* __restrict__ Cb,
    int M, int N, int K) {
  __shared__ unsigned short As[GBM * SAS];
  __shared__ unsigned short Bs[GBN * SAS];
  const int bm = blockIdx.y * GBM;
  const int bn = blockIdx.x * GBN;
  const int tid = threadIdx.x;
  const int wave = tid >> 6, lane = tid & 63;
  const int wm = wave & 1, wn = wave >> 1;
  f32x4 acc[4][2] = {};

  const int srow = tid >> 2;
  const int scol = (tid & 3) << 3;

  for (int k0 = 0; k0 < K; k0 += GBK) {
#pragma unroll
    for (int r = 0; r < 2; ++r) {
      const int row = srow + (r << 6);
      const int gr = bm + row;
      uint4 v = make_uint4(0u, 0u, 0u, 0u);
      if (gr < M) v = *reinterpret_cast<const uint4*>(&A[(size_t)gr * K + k0 + scol]);
      *reinterpret_cast<uint4*>(&As[row * SAS + scol]) = v;
    }
    {
      const uint4 v = *reinterpret_cast<const uint4*>(
          &Bt[(size_t)(bn + srow) * K + k0 + scol]);
      *reinterpret_cast<uint4*>(&Bs[srow * SAS + scol]) = v;
    }
    __syncthreads();
    const int kofs = (lane >> 4) << 3;
    const int rl = lane & 15;
    bf16x8 af[4], bfr[2];
#pragma unroll
    for (int m = 0; m < 4; ++m)
      af[m] = *reinterpret_cast<const bf16x8*>(
          &As[((wm << 6) + (m << 4) + rl) * SAS + kofs]);
#pragma unroll
    for (int n = 0; n < 2; ++n)
      bfr[n] = *reinterpret_cast<const bf16x8*>(
          &Bs[((wn << 5) + (n << 4) + rl) * SAS + kofs]);
#pragma unroll
    for (int m = 0; m < 4; ++m)
#pragma unroll
      for (int n = 0; n < 2; ++n)
        acc[m][n] = __builtin_amdgcn_mfma_f32_16x16x32_bf16(af[m], bfr[n], acc[m][n], 0, 0, 0);
    __syncthreads();
  }
  const int crow0 = (lane >> 4) << 2;
  const int ccol = lane & 15;
#pragma unroll
  for (int n = 0; n < 2; ++n) {
    const int col = bn + (wn << 5) + (n << 4) + ccol;
    const float bv = (!BF16OUT && bias) ? bias[col] : 0.f;
#pragma unroll
    for (int m = 0; m < 4; ++m) {
#pragma unroll
      for (int r = 0; r < 4; ++r) {
        const int rowg = bm + (wm << 6) + (m << 4) + crow0 + r;
        if (rowg < M) {
          if (BF16OUT)
            Cb[(size_t)rowg * N + col] = f2bf(acc[m][n][r] * rowscale[rowg]);
          else
            Cf[(size_t)rowg * N + col] = acc[m][n][r] + bv;
        }
      }
    }
  }
}

// ---------------- CSR build (both graphs fused) ----------------
__global__ void count_both(const int* __restrict__ col, const int* __restrict__ nrow,
                           int* __restrict__ cnt1, int* __restrict__ cnt2) {
  for (int e = blockIdx.x * blockDim.x + threadIdx.x; e < NE; e += gridDim.x * blockDim.x) {
    atomicAdd(&cnt1[col[e]], 1);
    atomicAdd(&cnt2[nrow[e]], 1);
  }
}

__global__ __launch_bounds__(1024) void scan2_kernel(
    const int* __restrict__ cnt1, int* __restrict__ ptrg, float* __restrict__ dis,
    const int* __restrict__ cnt2, int* __restrict__ ptrn, int n) {
  const int* cnt = (blockIdx.x == 0) ? cnt1 : cnt2;
  int* ptr = (blockIdx.x == 0) ? ptrg : ptrn;
  __shared__ int s[1024];
  const int t = threadIdx.x;
  const int chunk = (n + 1023) >> 10;
  const int start = t * chunk;
  const int end = min(start + chunk, n);
  int sum = 0;
  for (int i = start; i < end; ++i) sum += cnt[i];
  s[t] = sum;
  __syncthreads();
  for (int off = 1; off < 1024; off <<= 1) {
    int v = 0;
    if (t >= off) v = s[t - off];
    __syncthreads();
    s[t] += v;
    __syncthreads();
  }
  int excl = (t == 0) ? 0 : s[t - 1];
  for (int i = start; i < end; ++i) { ptr[i] = excl; excl += cnt[i]; }
  if (t == 1023) ptr[n] = s[1023];
  if (blockIdx.x == 0)
    for (int i = start; i < end; ++i)
      dis[i] = 1.0f / sqrtf((float)(cnt[i] + 1));
}

__global__ void fill_both(const int* __restrict__ col, const int* __restrict__ row,
                          const int* __restrict__ ptrg, int* __restrict__ cur1,
                          int* __restrict__ ridx,
                          const int* __restrict__ nrow, const int* __restrict__ ncol,
                          const int* __restrict__ ptrn, int* __restrict__ cur2,
                          int* __restrict__ ncidx) {
  for (int e = blockIdx.x * blockDim.x + threadIdx.x; e < NE; e += gridDim.x * blockDim.x) {
    const int k1 = col[e];
    const int p1 = atomicAdd(&cur1[k1], 1);
    ridx[ptrg[k1] + p1] = row[e];
    const int k2 = nrow[e];
    const int p2 = atomicAdd(&cur2[k2], 1);
    ncidx[ptrn[k2] + p2] = ncol[e];
  }
}

// ------- GCN aggregation, channel-sliced + XCD-pinned (slice fits in L2) ----
// C=512: 4 slices x 128ch (slice = xcd&3, 2.56MB/slice); C=256: 2 slices.
// blocks = NN*NS/2 ; block handles one (node-pair, slice).
// Same edge-order accumulation as before -> numerics unchanged.
template <int C>
__global__ __launch_bounds__(128) void gcn_slice(const unsigned short* __restrict__ hs,
    const float* __restrict__ dis, const int* __restrict__ ptr,
    const int* __restrict__ ridx, const float* __restrict__ bias,
    float* __restrict__ out) {
  constexpr int NS = C / 128;           // 4 (C=512) or 2 (C=256)
  const int b = blockIdx.x;
  const int x = b & 7;                  // XCD id (round-robin dispatch)
  const int p = b >> 3;
  const int slice = x & (NS - 1);
  const int pair = p * (8 / NS) + (x / NS);
  const int wave = threadIdx.x >> 6;
  const int lane = threadIdx.x & 63;
  const int j = pair * 2 + wave;
  const int cbase = slice * 128 + lane * 2;  // 2 bf16 channels per lane
  const unsigned short* hb = hs + cbase;

  float a0, a1;
  {
    const unsigned v = *reinterpret_cast<const unsigned*>(hb + (size_t)j * C);
    a0 = bflo(v); a1 = bfhi(v);
  }
  const int e0 = ptr[j], e1 = ptr[j + 1];
  int e = e0;
  for (; e + 3 < e1; e += 4) {          // 4 small gathers in flight
    const int r0 = ridx[e], r1 = ridx[e + 1], r2 = ridx[e + 2], r3 = ridx[e + 3];
    const unsigned u0 = *reinterpret_cast<const unsigned*>(hb + (size_t)r0 * C);
    const unsigned u1 = *reinterpret_cast<const unsigned*>(hb + (size_t)r1 * C);
    const unsigned u2 = *reinterpret_cast<const unsigned*>(hb + (size_t)r2 * C);
    const unsigned u3 = *reinterpret_cast<const unsigned*>(hb + (size_t)r3 * C);
    a0 += (bflo(u0) + bflo(u1)) + (bflo(u2) + bflo(u3));
    a1 += (bfhi(u0) + bfhi(u1)) + (bfhi(u2) + bfhi(u3));
  }
  for (; e < e1; ++e) {
    const unsigned u = *reinterpret_cast<const unsigned*>(hb + (size_t)ridx[e] * C);
    a0 += bflo(u);
    a1 += bfhi(u);
  }
  const float dj = dis[j];
  float2 w;
  w.x = fmaf(dj, a0, bias[cbase + 0]);
  w.y = fmaf(dj, a1, bias[cbase + 1]);
  *reinterpret_cast<float2*>(out + (size_t)j * C + cbase) = w;
}

// ---------------- BatchNorm stats (atomic partials; no finalize kernel) ------
template <int C>
__global__ __launch_bounds__(256) void bn_stats(const float* __restrict__ x,
    float* __restrict__ sums, float* __restrict__ sqs, int n) {
  constexpr int P = C / 256;
  float s[P], q[P];
#pragma unroll
  for (int p = 0; p < P; ++p) { s[p] = 0.f; q[p] = 0.f; }
  const int rpb = (n + gridDim.x - 1) / gridDim.x;
  const int r0 = blockIdx.x * rpb;
  const int r1 = min(r0 + rpb, n);
  for (int r = r0; r < r1; ++r) {
#pragma unroll
    for (int p = 0; p < P; ++p) {
      const float v = x[(size_t)r * C + threadIdx.x + (p << 8)];
      s[p] += v;
      q[p] = fmaf(v, v, q[p]);
    }
  }
#pragma unroll
  for (int p = 0; p < P; ++p) {
    atomicAdd(&sums[threadIdx.x + (p << 8)], s[p]);
    atomicAdd(&sqs[threadIdx.x + (p << 8)], q[p]);
  }
}

__device__ inline void bn_coeff(const float* sums, const float* sqs,
                                const float* g, const float* b, int c,
                                float inv_n, float& sc, float& sh) {
  const float m = sums[c] * inv_n;
  const float var = sqs[c] * inv_n - m * m;
  sc = g[c] / sqrtf(var + 1e-5f);
  sh = b[c] - m * sc;
}

// BN(inline-finalize)+PReLU -> bf16 out only
__global__ void bn_apply_prelu(const float* __restrict__ in,
    unsigned short* __restrict__ outb, const float* __restrict__ sums,
    const float* __restrict__ sqs, const float* __restrict__ g,
    const float* __restrict__ b, const float* __restrict__ pa,
    float inv_n, int total4, int cmask) {
  const float a = pa[0];
  for (int i = blockIdx.x * blockDim.x + threadIdx.x; i < total4;
       i += gridDim.x * blockDim.x) {
    float4 v = reinterpret_cast<const float4*>(in)[i];
    const int c0 = (i << 2) & cmask;
    float r[4] = {v.x, v.y, v.z, v.w};
    ushort4 o;
    unsigned short* op = reinterpret_cast<unsigned short*>(&o);
#pragma unroll
    for (int j = 0; j < 4; ++j) {
      float sc, sh;
      bn_coeff(sums, sqs, g, b, c0 + j, inv_n, sc, sh);
      float t = fmaf(r[j], sc, sh);
      t = t > 0.f ? t : a * t;
      op[j] = f2bf(t);
    }
    reinterpret_cast<ushort4*>(outb)[i] = o;
  }
}

// --- fused layer-2 tail: BN(inline)+PReLU -> student(f32)+stb+snb, 2 rows/blk
__global__ __launch_bounds__(128) void bn_l2_student(float* __restrict__ student,
    unsigned short* __restrict__ stb, unsigned short* __restrict__ snb,
    const float* __restrict__ sums, const float* __restrict__ sqs,
    const float* __restrict__ g, const float* __restrict__ b,
    const float* __restrict__ pa, float inv_n) {
  const int r = blockIdx.x * 2 + (threadIdx.x >> 6);
  const int t = threadIdx.x & 63;
  const float a = pa[0];
  const float4 v = reinterpret_cast<const float4*>(student + (size_t)r * 256)[t];
  float w[4] = {v.x, v.y, v.z, v.w};
  const int c0 = t << 2;
#pragma unroll
  for (int j = 0; j < 4; ++j) {
    float sc, sh;
    bn_coeff(sums, sqs, g, b, c0 + j, inv_n, sc, sh);
    float u = fmaf(w[j], sc, sh);
    w[j] = u > 0.f ? u : a * u;
  }
  reinterpret_cast<float4*>(student + (size_t)r * 256)[t] =
      make_float4(w[0], w[1], w[2], w[3]);
  ushort4 ob;
  ob.x = f2bf(w[0]); ob.y = f2bf(w[1]); ob.z = f2bf(w[2]); ob.w = f2bf(w[3]);
  reinterpret_cast<ushort4*>(stb + (size_t)r * 256)[t] = ob;
  float sq = w[0] * w[0] + w[1] * w[1] + w[2] * w[2] + w[3] * w[3];
#pragma unroll
  for (int o = 1; o < 64; o <<= 1) sq += __shfl_xor(sq, o);
  const float inv = 1.0f / sqrtf(sq + 1e-12f);
  ushort4 on;
  on.x = f2bf(w[0] * inv); on.y = f2bf(w[1] * inv);
  on.z = f2bf(w[2] * inv); on.w = f2bf(w[3] * inv);
  reinterpret_cast<ushort4*>(snb + (size_t)r * 256)[t] = on;
}

// ------ per-row edge sims + dedup + top-3; 2 rows/block (one wave each) ------
#define MAXK 256
__global__ __launch_bounds__(128) void topk_kernel(const unsigned short* __restrict__ snb,
    const int* __restrict__ ptr, const int* __restrict__ ncol, int* __restrict__ nb) {
  const int wv = threadIdx.x >> 6, lane = threadIdx.x & 63;
  const int i = blockIdx.x * 2 + wv;
  __shared__ unsigned short sni[2][256];
  __shared__ float vals[2][MAXK];
  __shared__ int   cols[2][MAXK];
  __shared__ float mvals[2][MAXK];
  __shared__ int   mcols[2][MAXK];
  reinterpret_cast<uint2*>(sni[wv])[lane] =
      reinterpret_cast<const uint2*>(snb + (size_t)i * 256)[lane];
  __syncthreads();
  const int e0 = ptr[i];
  const int k  = min(ptr[i + 1] - e0, MAXK);
  for (int e = lane; e < k; e += 64) {
    const int j = ncol[e0 + e];
    const uint4* bj = reinterpret_cast<const uint4*>(snb + (size_t)j * 256);
    const uint4* aj = reinterpret_cast<const uint4*>(sni[wv]);
    float s = 0.f;
#pragma unroll 8
    for (int q = 0; q < 32; ++q) {
      const uint4 b = bj[q];
      const uint4 a = aj[q];
      s = fmaf(bflo(a.x), bflo(b.x), s);
      s = fmaf(bfhi(a.x), bfhi(b.x), s);
      s = fmaf(bflo(a.y), bflo(b.y), s);
      s = fmaf(bfhi(a.y), bfhi(b.y), s);
      s = fmaf(bflo(a.z), bflo(b.z), s);
      s = fmaf(bfhi(a.z), bfhi(b.z), s);
      s = fmaf(bflo(a.w), bflo(b.w), s);
      s = fmaf(bfhi(a.w), bfhi(b.w), s);
    }
    vals[wv][e] = s;
    cols[wv][e] = j;
  }
  __syncthreads();
  for (int e = lane; e < k; e += 64) {
    const int c = cols[wv][e];
    bool first = true;
    float sum = vals[wv][e];
    for (int q = 0; q < k; ++q) {
      if (q == e) continue;
      if (cols[wv][q] == c) {
        if (q < e) { first = false; break; }
        sum += vals[wv][q];
      }
    }
    mvals[wv][e] = sum;
    mcols[wv][e] = first ? c : -1;
  }
  __syncthreads();
  for (int s = 0; s < 3; ++s) {
    unsigned long long best = 0ull;
    for (int e = lane; e < k; e += 64) {
      const int c = mcols[wv][e];
      if (c < 0) continue;
      const float v = mvals[wv][e];
      if (v <= 0.f) continue;
      const unsigned long long key =
          ((unsigned long long)__float_as_uint(v) << 32) |
          (unsigned long long)(0xFFFFFFFFu - (unsigned)c);
      if (key > best) best = key;
    }
#pragma unroll
    for (int off = 1; off < 64; off <<= 1) {
      const unsigned long long o = __shfl_xor(best, off);
      if (o > best) best = o;
    }
    const int wcol = best ? (int)(0xFFFFFFFFu - (unsigned)(best & 0xFFFFFFFFu)) : -1;
    if (lane == 0) nb[i * 3 + s] = wcol;
    if (wcol >= 0)
      for (int e = lane; e < k; e += 64)
        if (mcols[wv][e] == wcol) mcols[wv][e] = -1;
    __syncthreads();
  }
}

// ------ loss terms: inline pn=l2norm(pred), bf16 snb gathers, partials ------
__global__ __launch_bounds__(256) void loss_terms(const float* __restrict__ pred,
    const unsigned short* __restrict__ snb, const int* __restrict__ nb,
    float* __restrict__ part, int n) {
  const int t = threadIdx.x, wave = t >> 6, lane = t & 63;
  const int r = blockIdx.x * 4 + wave;
  float vals[7] = {0.f, 0.f, 0.f, 0.f, 0.f, 0.f, 0.f};
  if (r < n) {
    const float4 p = reinterpret_cast<const float4*>(pred + (size_t)r * 256)[lane];
    float sq = p.x * p.x + p.y * p.y + p.z * p.z + p.w * p.w;
#pragma unroll
    for (int o = 1; o < 64; o <<= 1) sq += __shfl_xor(sq, o);
    const float inv = 1.0f / sqrtf(sq + 1e-12f);
    const float a0 = p.x * inv, a1 = p.y * inv, a2 = p.z * inv, a3 = p.w * inv;
    {
      const uint2 bv = reinterpret_cast<const uint2*>(snb + (size_t)r * 256)[lane];
      float d = a0 * bflo(bv.x) + a1 * bfhi(bv.x) + a2 * bflo(bv.y) + a3 * bfhi(bv.y);
#pragma unroll
      for (int o = 1; o < 64; o <<= 1) d += __shfl_xor(d, o);
      vals[0] = 2.f - 2.f * d;
    }
    for (int s = 0; s < 3; ++s) {
      const int j = nb[r * 3 + s];
      if (j >= 0) {
        const uint2 cv = reinterpret_cast<const uint2*>(snb + (size_t)j * 256)[lane];
        float e = a0 * bflo(cv.x) + a1 * bfhi(cv.x) + a2 * bflo(cv.y) + a3 * bfhi(cv.y);
#pragma unroll
        for (int o = 1; o < 64; o <<= 1) e += __shfl_xor(e, o);
        vals[1 + s] = 2.f - 2.f * e;
        vals[4 + s] = 1.f;
      }
    }
  }
  __shared__ float red[4][7];
  if (lane == 0)
    for (int q = 0; q < 7; ++q) red[wave][q] = vals[q];
  __syncthreads();
  if (t < 7)
    part[(size_t)blockIdx.x * 8 + t] =
        red[0][t] + red[1][t] + red[2][t] + red[3][t];
}

__global__ __launch_bounds__(64) void finalize_loss(const float* __restrict__ part,
    float* __restrict__ out, int nblocks, int n) {
  const int lane = threadIdx.x;
  float comp[7] = {0.f, 0.f, 0.f, 0.f, 0.f, 0.f, 0.f};
  for (int b = lane; b < nblocks; b += 64) {
#pragma unroll
    for (int q = 0; q < 7; ++q) comp[q] += part[(size_t)b * 8 + q];
  }
#pragma unroll
  for (int q = 0; q < 7; ++q) {
#pragma unroll
    for (int o = 1; o < 64; o <<= 1) comp[q] += __shfl_xor(comp[q], o);
  }
  if (lane == 0) {
    float loss = comp[0] / n;
    for (int s = 0; s < 3; ++s) loss += comp[1 + s] / fmaxf(comp[4 + s], 1.f);
    out[0] = loss * 0.25f;
  }
}

// ---------------- host ----------------
extern "C" void kernel_launch(void* const* d_in, const int* in_sizes, int n_in,
                              void* d_out, int out_size, void* d_ws, size_t ws_size,
                              hipStream_t stream) {
  const float* x   = (const float*)d_in[0];
  const int*   eidx = (const int*)d_in[1];
  const int*   nidx = (const int*)d_in[2];
  const float* W1  = (const float*)d_in[3];
  const float* b1  = (const float*)d_in[4];
  const float* g1  = (const float*)d_in[5];
  const float* bb1 = (const float*)d_in[6];
  const float* pr1 = (const float*)d_in[7];
  const float* W2  = (const float*)d_in[8];
  const float* b2  = (const float*)d_in[9];
  const float* g2  = (const float*)d_in[10];
  const float* bb2 = (const float*)d_in[11];
  const float* pr2 = (const float*)d_in[12];
  const float* pW1 = (const float*)d_in[13];
  const float* pb1 = (const float*)d_in[14];
  const float* pg  = (const float*)d_in[15];
  const float* pbb = (const float*)d_in[16];
  const float* ppr = (const float*)d_in[17];
  const float* pW2 = (const float*)d_in[18];
  const float* pb2 = (const float*)d_in[19];

  const int* row  = eidx;
  const int* col  = eidx + NE;
  const int* nrow = nidx;
  const int* ncol = nidx + NE;

  float* student = (float*)d_out;              // NN x 256
  float* loss    = student + (size_t)NN * 256; // scalar

  char* ws = (char*)d_ws;
  size_t off = 0;
  auto take = [&](size_t bytes) -> void* {
    void* p = ws + off;
    off += (bytes + 255) & ~(size_t)255;
    return p;
  };
  const int LOSS_NB = NN / 4;
  // ---- zero-region (one memset) ----
  const size_t zstart = off;
  int*   cnt1 = (int*)take((size_t)NN * 4);
  int*   cur1 = (int*)take((size_t)NN * 4);
  int*   cnt2 = (int*)take((size_t)NN * 4);
  int*   cur2 = (int*)take((size_t)NN * 4);
  float* bns1 = (float*)take(1024 * 4);
  float* bns2 = (float*)take(512 * 4);
  float* bns3 = (float*)take(1024 * 4);
  const size_t zsize = off - zstart;
  // ---- rest ----
  float* h1    = (float*)take((size_t)NN * 512 * 4);
  float* x2    = (float*)take((size_t)NN * 512 * 4);
  float* h2    = (float*)take((size_t)NN * 256 * 4);
  float* dis   = (float*)take((size_t)NN * 4);
  int*   ptrg  = (int*)take((size_t)(NN + 1) * 4);
  int*   ridx  = (int*)take((size_t)NE * 4);
  int*   ptrn  = (int*)take((size_t)(NN + 1) * 4);
  int*   ncidx = (int*)take((size_t)NE * 4);
  int*   nb    = (int*)take((size_t)NN * 3 * 4);
  float* part  = (float*)take((size_t)LOSS_NB * 8 * 4);
  unsigned short* xb   = (unsigned short*)take((size_t)NN * 512 * 2);
  unsigned short* x2b  = (unsigned short*)take((size_t)NN * 512 * 2);
  unsigned short* stb  = (unsigned short*)take((size_t)NN * 256 * 2);
  unsigned short* phb  = (unsigned short*)take((size_t)NN * 512 * 2);
  unsigned short* h1b  = (unsigned short*)take((size_t)NN * 512 * 2);
  unsigned short* h2b  = (unsigned short*)take((size_t)NN * 256 * 2);
  unsigned short* snb  = (unsigned short*)take((size_t)NN * 256 * 2);
  unsigned short* W1t  = (unsigned short*)take((size_t)W1N * 2);
  unsigned short* W2t  = (unsigned short*)take((size_t)W2N * 2);
  unsigned short* pW1t = (unsigned short*)take((size_t)P1N * 2);
  unsigned short* pW2t = (unsigned short*)take((size_t)P2N * 2);

  float* ph   = h1;  // predictor hidden reuses h1
  float* pred = h2;  // predictor output reuses h2

  const int MB = (NN + GBM - 1) / GBM;  // 79
  const float inv_n = 1.0f / (float)NN;

  prep_kernel<<<2048, 256, 0, stream>>>(x, xb, W1, W1t, W2, W2t, pW1, pW1t, pW2, pW2t);
  hipMemsetAsync((char*)d_ws + zstart, 0, zsize, stream);

  count_both<<<512, 256, 0, stream>>>(col, nrow, cnt1, cnt2);
  scan2_kernel<<<2, 1024, 0, stream>>>(cnt1, ptrg, dis, cnt2, ptrn, NN);
  fill_both<<<512, 256, 0, stream>>>(col, row, ptrg, cur1, ridx,
                                     nrow, ncol, ptrn, cur2, ncidx);

  // ---- encoder layer 1 ----
  { dim3 g(512 / GBN, MB);
    gemm_bf16<true><<<g, 256, 0, stream>>>(xb, W1t, nullptr, dis, nullptr, h1b,
                                           NN, 512, 512); }
  // blocks = NN*NS/2 = 10000*4/2 = 20000  (5000 node-pairs x 4 slices)
  gcn_slice<512><<<NN * 4 / 2, 128, 0, stream>>>(h1b, dis, ptrg, ridx, b1, x2);
  bn_stats<512><<<256, 256, 0, stream>>>(x2, bns1, bns1 + 512, NN);
  bn_apply_prelu<<<2048, 256, 0, stream>>>(x2, x2b, bns1, bns1 + 512, g1, bb1, pr1,
                                           inv_n, NN * 512 / 4, 511);

  // ---- encoder layer 2 ----
  { dim3 g(256 / GBN, MB);
    gemm_bf16<true><<<g, 256, 0, stream>>>(x2b, W2t, nullptr, dis, nullptr, h2b,
                                           NN, 256, 512); }
  // blocks = NN*NS/2 = 10000*2/2 = 10000  (5000 node-pairs x 2 slices)
  gcn_slice<256><<<NN * 2 / 2, 128, 0, stream>>>(h2b, dis, ptrg, ridx, b2, student);
  bn_stats<256><<<256, 256, 0, stream>>>(student, bns2, bns2 + 256, NN);
  bn_l2_student<<<NN / 2, 128, 0, stream>>>(student, stb, snb, bns2, bns2 + 256,
                                            g2, bb2, pr2, inv_n);

  // ---- top-3 neighbors ----
  topk_kernel<<<NN / 2, 128, 0, stream>>>(snb, ptrn, ncidx, nb);

  // ---- predictor ----
  { dim3 g(512 / GBN, MB);
    gemm_bf16<false><<<g, 256, 0, stream>>>(stb, pW1t, pb1, nullptr, ph, nullptr,
                                            NN, 512, 256); }
  bn_stats<512><<<256, 256, 0, stream>>>(ph, bns3, bns3 + 512, NN);
  bn_apply_prelu<<<2048, 256, 0, stream>>>(ph, phb, bns3, bns3 + 512, pg, pbb, ppr,
                                           inv_n, NN * 512 / 4, 511);
  { dim3 g(256 / GBN, MB);
    gemm_bf16<false><<<g, 256, 0, stream>>>(phb, pW2t, pb2, nullptr, pred, nullptr,
                                            NN, 256, 512); }

  // ---- loss ----
  loss_terms<<<LOSS_NB, 256, 0, stream>>>(pred, snb, nb, part, NN);
  finalize_loss<<<1, 64, 0, stream>>>(part, loss, LOSS_NB, NN);
}

// Round 11
// 354.676 us; speedup vs baseline: 2.9027x; 1.0638x over previous
//
#include <hip/hip_runtime.h>
#include <math.h>

#define NN 10000
#define NE 320000

typedef __attribute__((ext_vector_type(8))) short bf16x8;
typedef __attribute__((ext_vector_type(4))) float f32x4;

__device__ inline unsigned short f2bf(float f) {
  unsigned u = __float_as_uint(f);
  unsigned r = (u + 0x7fffu + ((u >> 16) & 1u)) >> 16;
  return (unsigned short)r;
}
__device__ inline float bflo(unsigned u) { return __uint_as_float(u << 16); }
__device__ inline float bfhi(unsigned u) { return __uint_as_float(u & 0xffff0000u); }

// ------------- prep: x->bf16 (vec4) + 4 weight transposes, one kernel -------
#define X4 (NN * 512 / 4)
#define W1N (512 * 512)
#define W2N (512 * 256)
#define P1N (256 * 512)
#define P2N (512 * 256)
#define S1 X4
#define S2 (S1 + W1N)
#define S3 (S2 + W2N)
#define S4 (S3 + P1N)
#define PREP_TOT (S4 + P2N)

__global__ void prep_kernel(const float* __restrict__ x, unsigned short* __restrict__ xb,
    const float* __restrict__ W1, unsigned short* __restrict__ W1t,
    const float* __restrict__ W2, unsigned short* __restrict__ W2t,
    const float* __restrict__ pW1, unsigned short* __restrict__ pW1t,
    const float* __restrict__ pW2, unsigned short* __restrict__ pW2t) {
  for (int i = blockIdx.x * blockDim.x + threadIdx.x; i < PREP_TOT;
       i += gridDim.x * blockDim.x) {
    if (i < X4) {
      const float4 v = reinterpret_cast<const float4*>(x)[i];
      ushort4 o;
      o.x = f2bf(v.x); o.y = f2bf(v.y); o.z = f2bf(v.z); o.w = f2bf(v.w);
      reinterpret_cast<ushort4*>(xb)[i] = o;
    } else if (i < S2) {
      const int j = i - S1, n = j >> 9, k = j & 511;
      W1t[j] = f2bf(W1[(size_t)k * 512 + n]);
    } else if (i < S3) {
      const int j = i - S2, n = j >> 9, k = j & 511;
      W2t[j] = f2bf(W2[(size_t)k * 256 + n]);
    } else if (i < S4) {
      const int j = i - S3, n = j >> 8, k = j & 255;
      pW1t[j] = f2bf(pW1[(size_t)k * 512 + n]);
    } else {
      const int j = i - S4, n = j >> 9, k = j & 511;
      pW2t[j] = f2bf(pW2[(size_t)k * 256 + n]);
    }
  }
}

// ---------------- MFMA GEMM: A (MxK bf16 rm) x Bt (NxK bf16) -> C (MxN) -----
#define GBM 128
#define GBN 64
#define GBK 32
#define SAS 40

template <bool BF16OUT>
__global__ __launch_bounds__(256) void gemm_bf16(
    const unsigned short* __restrict__ A, const unsigned short* __restrict__ Bt,
    const float* __restrict__ bias, const float* __restrict__ rowscale,
    float* __restrict__ Cf, unsigned short* __restrict__ Cb,
    int M, int N, int K) {
  __shared__ unsigned short As[GBM * SAS];
  __shared__ unsigned short Bs[GBN * SAS];
  const int bm = blockIdx.y * GBM;
  const int bn = blockIdx.x * GBN;
  const int tid = threadIdx.x;
  const int wave = tid >> 6, lane = tid & 63;
  const int wm = wave & 1, wn = wave >> 1;
  f32x4 acc[4][2] = {};

  const int srow = tid >> 2;
  const int scol = (tid & 3) << 3;

  for (int k0 = 0; k0 < K; k0 += GBK) {
#pragma unroll
    for (int r = 0; r < 2; ++r) {
      const int row = srow + (r << 6);
      const int gr = bm + row;
      uint4 v = make_uint4(0u, 0u, 0u, 0u);
      if (gr < M) v = *reinterpret_cast<const uint4*>(&A[(size_t)gr * K + k0 + scol]);
      *reinterpret_cast<uint4*>(&As[row * SAS + scol]) = v;
    }
    {
      const uint4 v = *reinterpret_cast<const uint4*>(
          &Bt[(size_t)(bn + srow) * K + k0 + scol]);
      *reinterpret_cast<uint4*>(&Bs[srow * SAS + scol]) = v;
    }
    __syncthreads();
    const int kofs = (lane >> 4) << 3;
    const int rl = lane & 15;
    bf16x8 af[4], bfr[2];
#pragma unroll
    for (int m = 0; m < 4; ++m)
      af[m] = *reinterpret_cast<const bf16x8*>(
          &As[((wm << 6) + (m << 4) + rl) * SAS + kofs]);
#pragma unroll
    for (int n = 0; n < 2; ++n)
      bfr[n] = *reinterpret_cast<const bf16x8*>(
          &Bs[((wn << 5) + (n << 4) + rl) * SAS + kofs]);
#pragma unroll
    for (int m = 0; m < 4; ++m)
#pragma unroll
      for (int n = 0; n < 2; ++n)
        acc[m][n] = __builtin_amdgcn_mfma_f32_16x16x32_bf16(af[m], bfr[n], acc[m][n], 0, 0, 0);
    __syncthreads();
  }
  const int crow0 = (lane >> 4) << 2;
  const int ccol = lane & 15;
#pragma unroll
  for (int n = 0; n < 2; ++n) {
    const int col = bn + (wn << 5) + (n << 4) + ccol;
    const float bv = (!BF16OUT && bias) ? bias[col] : 0.f;
#pragma unroll
    for (int m = 0; m < 4; ++m) {
#pragma unroll
      for (int r = 0; r < 4; ++r) {
        const int rowg = bm + (wm << 6) + (m << 4) + crow0 + r;
        if (rowg < M) {
          if (BF16OUT)
            Cb[(size_t)rowg * N + col] = f2bf(acc[m][n][r] * rowscale[rowg]);
          else
            Cf[(size_t)rowg * N + col] = acc[m][n][r] + bv;
        }
      }
    }
  }
}

// ---------------- CSR build (both graphs fused) ----------------
__global__ void count_both(const int* __restrict__ col, const int* __restrict__ nrow,
                           int* __restrict__ cnt1, int* __restrict__ cnt2) {
  for (int e = blockIdx.x * blockDim.x + threadIdx.x; e < NE; e += gridDim.x * blockDim.x) {
    atomicAdd(&cnt1[col[e]], 1);
    atomicAdd(&cnt2[nrow[e]], 1);
  }
}

__global__ __launch_bounds__(1024) void scan2_kernel(
    const int* __restrict__ cnt1, int* __restrict__ ptrg, float* __restrict__ dis,
    const int* __restrict__ cnt2, int* __restrict__ ptrn, int n) {
  const int* cnt = (blockIdx.x == 0) ? cnt1 : cnt2;
  int* ptr = (blockIdx.x == 0) ? ptrg : ptrn;
  __shared__ int s[1024];
  const int t = threadIdx.x;
  const int chunk = (n + 1023) >> 10;
  const int start = t * chunk;
  const int end = min(start + chunk, n);
  int sum = 0;
  for (int i = start; i < end; ++i) sum += cnt[i];
  s[t] = sum;
  __syncthreads();
  for (int off = 1; off < 1024; off <<= 1) {
    int v = 0;
    if (t >= off) v = s[t - off];
    __syncthreads();
    s[t] += v;
    __syncthreads();
  }
  int excl = (t == 0) ? 0 : s[t - 1];
  for (int i = start; i < end; ++i) { ptr[i] = excl; excl += cnt[i]; }
  if (t == 1023) ptr[n] = s[1023];
  if (blockIdx.x == 0)
    for (int i = start; i < end; ++i)
      dis[i] = 1.0f / sqrtf((float)(cnt[i] + 1));
}

__global__ void fill_both(const int* __restrict__ col, const int* __restrict__ row,
                          const int* __restrict__ ptrg, int* __restrict__ cur1,
                          int* __restrict__ ridx,
                          const int* __restrict__ nrow, const int* __restrict__ ncol,
                          const int* __restrict__ ptrn, int* __restrict__ cur2,
                          int* __restrict__ ncidx) {
  for (int e = blockIdx.x * blockDim.x + threadIdx.x; e < NE; e += gridDim.x * blockDim.x) {
    const int k1 = col[e];
    const int p1 = atomicAdd(&cur1[k1], 1);
    ridx[ptrg[k1] + p1] = row[e];
    const int k2 = nrow[e];
    const int p2 = atomicAdd(&cur2[k2], 1);
    ncidx[ptrn[k2] + p2] = ncol[e];
  }
}

// ------- GCN aggregation, channel-sliced + XCD-pinned, 4 edges/wave ---------
// C=512: 4 slices x 128ch; C=256: 2 slices. blocks = NN*NS/2.
// Wave handles one (node, slice). Lane group g=lane>>4 takes edges e0+g+4k;
// each lane loads uint4 (8 ch), 16 lanes cover the 128-ch slice. Group
// partials tree-reduced via shfl_xor(16,32) at the end.
template <int C>
__global__ __launch_bounds__(128) void gcn_slice(const unsigned short* __restrict__ hs,
    const float* __restrict__ dis, const int* __restrict__ ptr,
    const int* __restrict__ ridx, const float* __restrict__ bias,
    float* __restrict__ out) {
  constexpr int NS = C / 128;           // 4 (C=512) or 2 (C=256)
  const int b = blockIdx.x;
  const int x = b & 7;                  // XCD id (round-robin dispatch)
  const int p = b >> 3;
  const int slice = x & (NS - 1);
  const int pair = p * (8 / NS) + (x / NS);
  const int wave = threadIdx.x >> 6;
  const int lane = threadIdx.x & 63;
  const int j = pair * 2 + wave;
  const int g = lane >> 4;              // edge group 0..3
  const int l = lane & 15;
  const int cbase = slice * 128 + l * 8;  // 8 bf16 channels per lane
  const unsigned short* hb = hs + cbase;

  float a[8];
  if (g == 0) {   // self row handled by group 0
    const uint4 v = *reinterpret_cast<const uint4*>(hb + (size_t)j * C);
    a[0] = bflo(v.x); a[1] = bfhi(v.x); a[2] = bflo(v.y); a[3] = bfhi(v.y);
    a[4] = bflo(v.z); a[5] = bfhi(v.z); a[6] = bflo(v.w); a[7] = bfhi(v.w);
  } else {
#pragma unroll
    for (int c = 0; c < 8; ++c) a[c] = 0.f;
  }
  const int e0 = ptr[j], e1 = ptr[j + 1];
  int e = e0 + g;
  for (; e + 4 < e1; e += 8) {          // 2-deep unroll: 8 gathers in flight/wave
    const int r0 = ridx[e], r1 = ridx[e + 4];
    const uint4 v0 = *reinterpret_cast<const uint4*>(hb + (size_t)r0 * C);
    const uint4 v1 = *reinterpret_cast<const uint4*>(hb + (size_t)r1 * C);
    a[0] += bflo(v0.x) + bflo(v1.x); a[1] += bfhi(v0.x) + bfhi(v1.x);
    a[2] += bflo(v0.y) + bflo(v1.y); a[3] += bfhi(v0.y) + bfhi(v1.y);
    a[4] += bflo(v0.z) + bflo(v1.z); a[5] += bfhi(v0.z) + bfhi(v1.z);
    a[6] += bflo(v0.w) + bflo(v1.w); a[7] += bfhi(v0.w) + bfhi(v1.w);
  }
  if (e < e1) {
    const uint4 v = *reinterpret_cast<const uint4*>(hb + (size_t)ridx[e] * C);
    a[0] += bflo(v.x); a[1] += bfhi(v.x); a[2] += bflo(v.y); a[3] += bfhi(v.y);
    a[4] += bflo(v.z); a[5] += bfhi(v.z); a[6] += bflo(v.w); a[7] += bfhi(v.w);
  }
  // reduce the 4 group-partials (lanes l, l+16, l+32, l+48)
#pragma unroll
  for (int c = 0; c < 8; ++c) {
    a[c] += __shfl_xor(a[c], 16);
    a[c] += __shfl_xor(a[c], 32);
  }
  if (g == 0) {
    const float dj = dis[j];
    const float* bs = bias + cbase;
    float4 w0, w1;
    w0.x = fmaf(dj, a[0], bs[0]); w0.y = fmaf(dj, a[1], bs[1]);
    w0.z = fmaf(dj, a[2], bs[2]); w0.w = fmaf(dj, a[3], bs[3]);
    w1.x = fmaf(dj, a[4], bs[4]); w1.y = fmaf(dj, a[5], bs[5]);
    w1.z = fmaf(dj, a[6], bs[6]); w1.w = fmaf(dj, a[7], bs[7]);
    float* o = out + (size_t)j * C + cbase;
    *reinterpret_cast<float4*>(o) = w0;
    *reinterpret_cast<float4*>(o + 4) = w1;
  }
}

// ---------------- BatchNorm stats (atomic partials; no finalize kernel) ------
template <int C>
__global__ __launch_bounds__(256) void bn_stats(const float* __restrict__ x,
    float* __restrict__ sums, float* __restrict__ sqs, int n) {
  constexpr int P = C / 256;
  float s[P], q[P];
#pragma unroll
  for (int p = 0; p < P; ++p) { s[p] = 0.f; q[p] = 0.f; }
  const int rpb = (n + gridDim.x - 1) / gridDim.x;
  const int r0 = blockIdx.x * rpb;
  const int r1 = min(r0 + rpb, n);
  for (int r = r0; r < r1; ++r) {
#pragma unroll
    for (int p = 0; p < P; ++p) {
      const float v = x[(size_t)r * C + threadIdx.x + (p << 8)];
      s[p] += v;
      q[p] = fmaf(v, v, q[p]);
    }
  }
#pragma unroll
  for (int p = 0; p < P; ++p) {
    atomicAdd(&sums[threadIdx.x + (p << 8)], s[p]);
    atomicAdd(&sqs[threadIdx.x + (p << 8)], q[p]);
  }
}

__device__ inline void bn_coeff(const float* sums, const float* sqs,
                                const float* g, const float* b, int c,
                                float inv_n, float& sc, float& sh) {
  const float m = sums[c] * inv_n;
  const float var = sqs[c] * inv_n - m * m;
  sc = g[c] / sqrtf(var + 1e-5f);
  sh = b[c] - m * sc;
}

// BN(inline-finalize)+PReLU -> bf16 out only
__global__ void bn_apply_prelu(const float* __restrict__ in,
    unsigned short* __restrict__ outb, const float* __restrict__ sums,
    const float* __restrict__ sqs, const float* __restrict__ g,
    const float* __restrict__ b, const float* __restrict__ pa,
    float inv_n, int total4, int cmask) {
  const float a = pa[0];
  for (int i = blockIdx.x * blockDim.x + threadIdx.x; i < total4;
       i += gridDim.x * blockDim.x) {
    float4 v = reinterpret_cast<const float4*>(in)[i];
    const int c0 = (i << 2) & cmask;
    float r[4] = {v.x, v.y, v.z, v.w};
    ushort4 o;
    unsigned short* op = reinterpret_cast<unsigned short*>(&o);
#pragma unroll
    for (int j = 0; j < 4; ++j) {
      float sc, sh;
      bn_coeff(sums, sqs, g, b, c0 + j, inv_n, sc, sh);
      float t = fmaf(r[j], sc, sh);
      t = t > 0.f ? t : a * t;
      op[j] = f2bf(t);
    }
    reinterpret_cast<ushort4*>(outb)[i] = o;
  }
}

// --- fused layer-2 tail: BN(inline)+PReLU -> student(f32)+stb+snb, 2 rows/blk
__global__ __launch_bounds__(128) void bn_l2_student(float* __restrict__ student,
    unsigned short* __restrict__ stb, unsigned short* __restrict__ snb,
    const float* __restrict__ sums, const float* __restrict__ sqs,
    const float* __restrict__ g, const float* __restrict__ b,
    const float* __restrict__ pa, float inv_n) {
  const int r = blockIdx.x * 2 + (threadIdx.x >> 6);
  const int t = threadIdx.x & 63;
  const float a = pa[0];
  const float4 v = reinterpret_cast<const float4*>(student + (size_t)r * 256)[t];
  float w[4] = {v.x, v.y, v.z, v.w};
  const int c0 = t << 2;
#pragma unroll
  for (int j = 0; j < 4; ++j) {
    float sc, sh;
    bn_coeff(sums, sqs, g, b, c0 + j, inv_n, sc, sh);
    float u = fmaf(w[j], sc, sh);
    w[j] = u > 0.f ? u : a * u;
  }
  reinterpret_cast<float4*>(student + (size_t)r * 256)[t] =
      make_float4(w[0], w[1], w[2], w[3]);
  ushort4 ob;
  ob.x = f2bf(w[0]); ob.y = f2bf(w[1]); ob.z = f2bf(w[2]); ob.w = f2bf(w[3]);
  reinterpret_cast<ushort4*>(stb + (size_t)r * 256)[t] = ob;
  float sq = w[0] * w[0] + w[1] * w[1] + w[2] * w[2] + w[3] * w[3];
#pragma unroll
  for (int o = 1; o < 64; o <<= 1) sq += __shfl_xor(sq, o);
  const float inv = 1.0f / sqrtf(sq + 1e-12f);
  ushort4 on;
  on.x = f2bf(w[0] * inv); on.y = f2bf(w[1] * inv);
  on.z = f2bf(w[2] * inv); on.w = f2bf(w[3] * inv);
  reinterpret_cast<ushort4*>(snb + (size_t)r * 256)[t] = on;
}

// ------ per-row edge sims + dedup + top-3; 2 rows/block (one wave each) ------
#define MAXK 256
__global__ __launch_bounds__(128) void topk_kernel(const unsigned short* __restrict__ snb,
    const int* __restrict__ ptr, const int* __restrict__ ncol, int* __restrict__ nb) {
  const int wv = threadIdx.x >> 6, lane = threadIdx.x & 63;
  const int i = blockIdx.x * 2 + wv;
  __shared__ unsigned short sni[2][256];
  __shared__ float vals[2][MAXK];
  __shared__ int   cols[2][MAXK];
  __shared__ float mvals[2][MAXK];
  __shared__ int   mcols[2][MAXK];
  reinterpret_cast<uint2*>(sni[wv])[lane] =
      reinterpret_cast<const uint2*>(snb + (size_t)i * 256)[lane];
  __syncthreads();
  const int e0 = ptr[i];
  const int k  = min(ptr[i + 1] - e0, MAXK);
  for (int e = lane; e < k; e += 64) {
    const int j = ncol[e0 + e];
    const uint4* bj = reinterpret_cast<const uint4*>(snb + (size_t)j * 256);
    const uint4* aj = reinterpret_cast<const uint4*>(sni[wv]);
    float s = 0.f;
#pragma unroll 8
    for (int q = 0; q < 32; ++q) {
      const uint4 b = bj[q];
      const uint4 a = aj[q];
      s = fmaf(bflo(a.x), bflo(b.x), s);
      s = fmaf(bfhi(a.x), bfhi(b.x), s);
      s = fmaf(bflo(a.y), bflo(b.y), s);
      s = fmaf(bfhi(a.y), bfhi(b.y), s);
      s = fmaf(bflo(a.z), bflo(b.z), s);
      s = fmaf(bfhi(a.z), bfhi(b.z), s);
      s = fmaf(bflo(a.w), bflo(b.w), s);
      s = fmaf(bfhi(a.w), bfhi(b.w), s);
    }
    vals[wv][e] = s;
    cols[wv][e] = j;
  }
  __syncthreads();
  for (int e = lane; e < k; e += 64) {
    const int c = cols[wv][e];
    bool first = true;
    float sum = vals[wv][e];
    for (int q = 0; q < k; ++q) {
      if (q == e) continue;
      if (cols[wv][q] == c) {
        if (q < e) { first = false; break; }
        sum += vals[wv][q];
      }
    }
    mvals[wv][e] = sum;
    mcols[wv][e] = first ? c : -1;
  }
  __syncthreads();
  for (int s = 0; s < 3; ++s) {
    unsigned long long best = 0ull;
    for (int e = lane; e < k; e += 64) {
      const int c = mcols[wv][e];
      if (c < 0) continue;
      const float v = mvals[wv][e];
      if (v <= 0.f) continue;
      const unsigned long long key =
          ((unsigned long long)__float_as_uint(v) << 32) |
          (unsigned long long)(0xFFFFFFFFu - (unsigned)c);
      if (key > best) best = key;
    }
#pragma unroll
    for (int off = 1; off < 64; off <<= 1) {
      const unsigned long long o = __shfl_xor(best, off);
      if (o > best) best = o;
    }
    const int wcol = best ? (int)(0xFFFFFFFFu - (unsigned)(best & 0xFFFFFFFFu)) : -1;
    if (lane == 0) nb[i * 3 + s] = wcol;
    if (wcol >= 0)
      for (int e = lane; e < k; e += 64)
        if (mcols[wv][e] == wcol) mcols[wv][e] = -1;
    __syncthreads();
  }
}

// ------ loss terms: inline pn=l2norm(pred), bf16 snb gathers, partials ------
__global__ __launch_bounds__(256) void loss_terms(const float* __restrict__ pred,
    const unsigned short* __restrict__ snb, const int* __restrict__ nb,
    float* __restrict__ part, int n) {
  const int t = threadIdx.x, wave = t >> 6, lane = t & 63;
  const int r = blockIdx.x * 4 + wave;
  float vals[7] = {0.f, 0.f, 0.f, 0.f, 0.f, 0.f, 0.f};
  if (r < n) {
    const float4 p = reinterpret_cast<const float4*>(pred + (size_t)r * 256)[lane];
    float sq = p.x * p.x + p.y * p.y + p.z * p.z + p.w * p.w;
#pragma unroll
    for (int o = 1; o < 64; o <<= 1) sq += __shfl_xor(sq, o);
    const float inv = 1.0f / sqrtf(sq + 1e-12f);
    const float a0 = p.x * inv, a1 = p.y * inv, a2 = p.z * inv, a3 = p.w * inv;
    {
      const uint2 bv = reinterpret_cast<const uint2*>(snb + (size_t)r * 256)[lane];
      float d = a0 * bflo(bv.x) + a1 * bfhi(bv.x) + a2 * bflo(bv.y) + a3 * bfhi(bv.y);
#pragma unroll
      for (int o = 1; o < 64; o <<= 1) d += __shfl_xor(d, o);
      vals[0] = 2.f - 2.f * d;
    }
    for (int s = 0; s < 3; ++s) {
      const int j = nb[r * 3 + s];
      if (j >= 0) {
        const uint2 cv = reinterpret_cast<const uint2*>(snb + (size_t)j * 256)[lane];
        float e = a0 * bflo(cv.x) + a1 * bfhi(cv.x) + a2 * bflo(cv.y) + a3 * bfhi(cv.y);
#pragma unroll
        for (int o = 1; o < 64; o <<= 1) e += __shfl_xor(e, o);
        vals[1 + s] = 2.f - 2.f * e;
        vals[4 + s] = 1.f;
      }
    }
  }
  __shared__ float red[4][7];
  if (lane == 0)
    for (int q = 0; q < 7; ++q) red[wave][q] = vals[q];
  __syncthreads();
  if (t < 7)
    part[(size_t)blockIdx.x * 8 + t] =
        red[0][t] + red[1][t] + red[2][t] + red[3][t];
}

__global__ __launch_bounds__(64) void finalize_loss(const float* __restrict__ part,
    float* __restrict__ out, int nblocks, int n) {
  const int lane = threadIdx.x;
  float comp[7] = {0.f, 0.f, 0.f, 0.f, 0.f, 0.f, 0.f};
  for (int b = lane; b < nblocks; b += 64) {
#pragma unroll
    for (int q = 0; q < 7; ++q) comp[q] += part[(size_t)b * 8 + q];
  }
#pragma unroll
  for (int q = 0; q < 7; ++q) {
#pragma unroll
    for (int o = 1; o < 64; o <<= 1) comp[q] += __shfl_xor(comp[q], o);
  }
  if (lane == 0) {
    float loss = comp[0] / n;
    for (int s = 0; s < 3; ++s) loss += comp[1 + s] / fmaxf(comp[4 + s], 1.f);
    out[0] = loss * 0.25f;
  }
}

// ---------------- host ----------------
extern "C" void kernel_launch(void* const* d_in, const int* in_sizes, int n_in,
                              void* d_out, int out_size, void* d_ws, size_t ws_size,
                              hipStream_t stream) {
  const float* x   = (const float*)d_in[0];
  const int*   eidx = (const int*)d_in[1];
  const int*   nidx = (const int*)d_in[2];
  const float* W1  = (const float*)d_in[3];
  const float* b1  = (const float*)d_in[4];
  const float* g1  = (const float*)d_in[5];
  const float* bb1 = (const float*)d_in[6];
  const float* pr1 = (const float*)d_in[7];
  const float* W2  = (const float*)d_in[8];
  const float* b2  = (const float*)d_in[9];
  const float* g2  = (const float*)d_in[10];
  const float* bb2 = (const float*)d_in[11];
  const float* pr2 = (const float*)d_in[12];
  const float* pW1 = (const float*)d_in[13];
  const float* pb1 = (const float*)d_in[14];
  const float* pg  = (const float*)d_in[15];
  const float* pbb = (const float*)d_in[16];
  const float* ppr = (const float*)d_in[17];
  const float* pW2 = (const float*)d_in[18];
  const float* pb2 = (const float*)d_in[19];

  const int* row  = eidx;
  const int* col  = eidx + NE;
  const int* nrow = nidx;
  const int* ncol = nidx + NE;

  float* student = (float*)d_out;              // NN x 256
  float* loss    = student + (size_t)NN * 256; // scalar

  char* ws = (char*)d_ws;
  size_t off = 0;
  auto take = [&](size_t bytes) -> void* {
    void* p = ws + off;
    off += (bytes + 255) & ~(size_t)255;
    return p;
  };
  const int LOSS_NB = NN / 4;
  // ---- zero-region (one memset) ----
  const size_t zstart = off;
  int*   cnt1 = (int*)take((size_t)NN * 4);
  int*   cur1 = (int*)take((size_t)NN * 4);
  int*   cnt2 = (int*)take((size_t)NN * 4);
  int*   cur2 = (int*)take((size_t)NN * 4);
  float* bns1 = (float*)take(1024 * 4);
  float* bns2 = (float*)take(512 * 4);
  float* bns3 = (float*)take(1024 * 4);
  const size_t zsize = off - zstart;
  // ---- rest ----
  float* h1    = (float*)take((size_t)NN * 512 * 4);
  float* x2    = (float*)take((size_t)NN * 512 * 4);
  float* h2    = (float*)take((size_t)NN * 256 * 4);
  float* dis   = (float*)take((size_t)NN * 4);
  int*   ptrg  = (int*)take((size_t)(NN + 1) * 4);
  int*   ridx  = (int*)take((size_t)NE * 4);
  int*   ptrn  = (int*)take((size_t)(NN + 1) * 4);
  int*   ncidx = (int*)take((size_t)NE * 4);
  int*   nb    = (int*)take((size_t)NN * 3 * 4);
  float* part  = (float*)take((size_t)LOSS_NB * 8 * 4);
  unsigned short* xb   = (unsigned short*)take((size_t)NN * 512 * 2);
  unsigned short* x2b  = (unsigned short*)take((size_t)NN * 512 * 2);
  unsigned short* stb  = (unsigned short*)take((size_t)NN * 256 * 2);
  unsigned short* phb  = (unsigned short*)take((size_t)NN * 512 * 2);
  unsigned short* h1b  = (unsigned short*)take((size_t)NN * 512 * 2);
  unsigned short* h2b  = (unsigned short*)take((size_t)NN * 256 * 2);
  unsigned short* snb  = (unsigned short*)take((size_t)NN * 256 * 2);
  unsigned short* W1t  = (unsigned short*)take((size_t)W1N * 2);
  unsigned short* W2t  = (unsigned short*)take((size_t)W2N * 2);
  unsigned short* pW1t = (unsigned short*)take((size_t)P1N * 2);
  unsigned short* pW2t = (unsigned short*)take((size_t)P2N * 2);

  float* ph   = h1;  // predictor hidden reuses h1
  float* pred = h2;  // predictor output reuses h2

  const int MB = (NN + GBM - 1) / GBM;  // 79
  const float inv_n = 1.0f / (float)NN;

  prep_kernel<<<2048, 256, 0, stream>>>(x, xb, W1, W1t, W2, W2t, pW1, pW1t, pW2, pW2t);
  hipMemsetAsync((char*)d_ws + zstart, 0, zsize, stream);

  count_both<<<512, 256, 0, stream>>>(col, nrow, cnt1, cnt2);
  scan2_kernel<<<2, 1024, 0, stream>>>(cnt1, ptrg, dis, cnt2, ptrn, NN);
  fill_both<<<512, 256, 0, stream>>>(col, row, ptrg, cur1, ridx,
                                     nrow, ncol, ptrn, cur2, ncidx);

  // ---- encoder layer 1 ----
  { dim3 g(512 / GBN, MB);
    gemm_bf16<true><<<g, 256, 0, stream>>>(xb, W1t, nullptr, dis, nullptr, h1b,
                                           NN, 512, 512); }
  gcn_slice<512><<<NN * 4 / 2, 128, 0, stream>>>(h1b, dis, ptrg, ridx, b1, x2);
  bn_stats<512><<<256, 256, 0, stream>>>(x2, bns1, bns1 + 512, NN);
  bn_apply_prelu<<<2048, 256, 0, stream>>>(x2, x2b, bns1, bns1 + 512, g1, bb1, pr1,
                                           inv_n, NN * 512 / 4, 511);

  // ---- encoder layer 2 ----
  { dim3 g(256 / GBN, MB);
    gemm_bf16<true><<<g, 256, 0, stream>>>(x2b, W2t, nullptr, dis, nullptr, h2b,
                                           NN, 256, 512); }
  gcn_slice<256><<<NN * 2 / 2, 128, 0, stream>>>(h2b, dis, ptrg, ridx, b2, student);
  bn_stats<256><<<256, 256, 0, stream>>>(student, bns2, bns2 + 256, NN);
  bn_l2_student<<<NN / 2, 128, 0, stream>>>(student, stb, snb, bns2, bns2 + 256,
                                            g2, bb2, pr2, inv_n);

  // ---- top-3 neighbors ----
  topk_kernel<<<NN / 2, 128, 0, stream>>>(snb, ptrn, ncidx, nb);

  // ---- predictor ----
  { dim3 g(512 / GBN, MB);
    gemm_bf16<false><<<g, 256, 0, stream>>>(stb, pW1t, pb1, nullptr, ph, nullptr,
                                            NN, 512, 256); }
  bn_stats<512><<<256, 256, 0, stream>>>(ph, bns3, bns3 + 512, NN);
  bn_apply_prelu<<<2048, 256, 0, stream>>>(ph, phb, bns3, bns3 + 512, pg, pbb, ppr,
                                           inv_n, NN * 512 / 4, 511);
  { dim3 g(256 / GBN, MB);
    gemm_bf16<false><<<g, 256, 0, stream>>>(phb, pW2t, pb2, nullptr, pred, nullptr,
                                            NN, 256, 512); }

  // ---- loss ----
  loss_terms<<<LOSS_NB, 256, 0, stream>>>(pred, snb, nb, part, NN);
  finalize_loss<<<1, 64, 0, stream>>>(part, loss, LOSS_NB, NN);
}